// Round 6
// baseline (540.143 us; speedup 1.0000x reference)
//
#include <hip/hip_runtime.h>

#define NR 4096

typedef __attribute__((ext_vector_type(8))) short bf16x8;
typedef __attribute__((ext_vector_type(4))) float f32x4;

struct P3 { const float* p[3]; };
struct V3 { const void* p[3]; };
struct O3 { float* p[3]; };
struct I3 { int v[3]; };
struct P6 { const float* p[6]; };
struct U6 { unsigned short* p[6]; };
struct I6 { int v[6]; };

__device__ __forceinline__ unsigned short f2bf(float f) {
    union { float f; unsigned u; } v; v.f = f;
    unsigned r = v.u + 0x7fffu + ((v.u >> 16) & 1u);
    return (unsigned short)(r >> 16);
}

// ---------------------------------------------------------------------------
// C[M,64] = A[M,K] @ B[K,64], z-merged, NO LDS / NO BARRIERS.
// Each wave owns a 16-row x 64-col output strip and loads MFMA fragments
// DIRECTLY from global:
//   A (f32, HBM): lane l -> row l&15, k (l>>4)*8 (+ks*32), 2x f32x4.
//       Raw f32 kept in regs; bf16 conversion DEFERRED one iteration so the
//       vmcnt wait lands ~1.7 iters after issue (R5 converted inline, making
//       every "prefetch" synchronous — the round's diagnosed bug).
//   B (bf16, pre-transposed B^T[n][k], L2-resident): lane l -> col j*16+(l&15),
//       k (l>>4)*8, one bf16x8 per (ks, j) — no conversion needed.
// Banks rotate by parity with literal indices (no dynamic reg indexing).
// DUAL folds w0*A1+w1*A2+b during conversion.  CT writes C^T (for fe^T).
// Split-K partials to Cpart (deterministic).
// ---------------------------------------------------------------------------
template<bool DUAL, bool CT>
__global__ __launch_bounds__(256, 2) void gemm_direct(
    P3 A1a, P3 A2a, V3 Ba, float* __restrict__ Cpart,
    P3 wca, P3 bca, I3 Kz, I3 Kpz, I3 ktz, I3 tpsz, const int KScap)
{
    const int z = blockIdx.z;
    const int K = Kz.v[z], Kp = Kpz.v[z], ktiles = ktz.v[z], tps = tpsz.v[z];
    const int mt = blockIdx.x, sp = blockIdx.y;
    const int kt0 = sp * tps;
    int kt1 = kt0 + tps; if (kt1 > ktiles) kt1 = ktiles;
    if (kt0 >= kt1) return;
    const int niter = kt1 - kt0;

    const int t = threadIdx.x;
    const int l = t & 63, w = t >> 6;
    const int lr = l & 15, lk = l >> 4;
    const int arow = mt * 64 + w * 16 + lr;

    const float* __restrict__ A1 = A1a.p[z] + (size_t)arow * K + lk * 8;
    const float* __restrict__ A2 = (DUAL ? A2a.p[z] : A1a.p[z]) + (size_t)arow * K + lk * 8;
    const unsigned short* __restrict__ Bt = (const unsigned short*)Ba.p[z];

    float w0 = 0.f, w1 = 0.f, bb = 0.f;
    if (DUAL) { w0 = wca.p[z][0]; w1 = wca.p[z][1]; bb = bca.p[z][0]; }

    const unsigned short* Bp[4];
    #pragma unroll
    for (int j = 0; j < 4; ++j)
        Bp[j] = Bt + (size_t)(j * 16 + lr) * Kp + lk * 8;

    f32x4 acc[4];
    #pragma unroll
    for (int j = 0; j < 4; ++j)
        #pragma unroll
        for (int r = 0; r < 4; ++r) acc[j][r] = 0.f;

    // register banks (outer index always a literal via duplicated loop bodies)
    f32x4 a1r[2][2][2];            // [bank][ks][half]
    f32x4 a2r[2][2][2];            // dual only
    bf16x8 bfr[2][2][4];           // [bank][ks][j]
    bf16x8 cva[2][2];              // [bank][ks]

    auto issueA = [&](int kt, f32x4 (&r1)[2][2], f32x4 (&r2)[2][2]) {
        const int kb = kt * 64 + lk * 8;
        #pragma unroll
        for (int ks = 0; ks < 2; ++ks) {
            const int kkk = kb + ks * 32;
            const float* p1 = A1 + kt * 64 + ks * 32;
            const float* p2 = A2 + kt * 64 + ks * 32;
            if (kkk + 7 < K) {
                r1[ks][0] = *(const f32x4*)p1;
                r1[ks][1] = *(const f32x4*)(p1 + 4);
                if (DUAL) {
                    r2[ks][0] = *(const f32x4*)p2;
                    r2[ks][1] = *(const f32x4*)(p2 + 4);
                }
            } else {
                #pragma unroll
                for (int h = 0; h < 2; ++h)
                    #pragma unroll
                    for (int e = 0; e < 4; ++e) {
                        const int ki = kkk + h * 4 + e;
                        r1[ks][h][e] = (ki < K) ? p1[h * 4 + e] : 0.f;
                        if (DUAL) r2[ks][h][e] = (ki < K) ? p2[h * 4 + e] : 0.f;
                    }
            }
        }
    };
    auto issueB = [&](int kt, bf16x8 (&rb)[2][4]) {
        #pragma unroll
        for (int ks = 0; ks < 2; ++ks)
            #pragma unroll
            for (int j = 0; j < 4; ++j)
                rb[ks][j] = *(const bf16x8*)(Bp[j] + kt * 64 + ks * 32);
    };
    auto convA = [&](const f32x4 (&r1)[2][2], const f32x4 (&r2)[2][2],
                     bf16x8 (&cv)[2]) {
        #pragma unroll
        for (int ks = 0; ks < 2; ++ks) {
            bf16x8 o;
            #pragma unroll
            for (int h = 0; h < 2; ++h)
                #pragma unroll
                for (int e = 0; e < 4; ++e) {
                    const float v = DUAL ? (w0 * r1[ks][h][e] + w1 * r2[ks][h][e] + bb)
                                         : r1[ks][h][e];
                    o[h * 4 + e] = (short)f2bf(v);
                }
            cv[ks] = o;
        }
    };
    auto domfma = [&](const bf16x8 (&cv)[2], const bf16x8 (&rb)[2][4]) {
        #pragma unroll
        for (int ks = 0; ks < 2; ++ks)
            #pragma unroll
            for (int j = 0; j < 4; ++j)
                acc[j] = __builtin_amdgcn_mfma_f32_16x16x32_bf16(cv[ks], rb[ks][j], acc[j], 0, 0, 0);
    };

    // prologue: tiles kt0, kt0+1 in flight; conv(kt0) ready
    issueA(kt0, a1r[0], a2r[0]);
    issueB(kt0, bfr[0]);
    if (niter > 1) { issueA(kt0 + 1, a1r[1], a2r[1]); issueB(kt0 + 1, bfr[1]); }
    convA(a1r[0], a2r[0], cva[0]);

    for (int i = 0; i < niter; ++i) {
        if ((i & 1) == 0) {
            if (i + 2 < niter) issueA(kt0 + i + 2, a1r[0], a2r[0]);
            domfma(cva[0], bfr[0]);
            if (i + 2 < niter) issueB(kt0 + i + 2, bfr[0]);
            if (i + 1 < niter) convA(a1r[1], a2r[1], cva[1]);
        } else {
            if (i + 2 < niter) issueA(kt0 + i + 2, a1r[1], a2r[1]);
            domfma(cva[1], bfr[1]);
            if (i + 2 < niter) issueB(kt0 + i + 2, bfr[1]);
            if (i + 1 < niter) convA(a1r[0], a2r[0], cva[0]);
        }
    }

    float* Cp = Cpart + (size_t)(z * KScap + sp) * (NR * 64);
    if (CT) {
        #pragma unroll
        for (int j = 0; j < 4; ++j) {
            const int col = j * 16 + lr;
            const int row0 = mt * 64 + w * 16 + lk * 4;
            *(f32x4*)&Cp[(size_t)col * NR + row0] = acc[j];
        }
    } else {
        #pragma unroll
        for (int j = 0; j < 4; ++j)
            #pragma unroll
            for (int r = 0; r < 4; ++r) {
                const int row = mt * 64 + w * 16 + lk * 4 + r;
                const int col = j * 16 + lr;
                Cp[(size_t)row * 64 + col] = acc[j][r];
            }
    }
}

// sum per-z split partials -> bf16 (layout-agnostic), z-merged
__global__ __launch_bounds__(256) void reduce_many(
    const float* __restrict__ Cpart, unsigned short* __restrict__ out,
    I3 nsp, const int KScap)
{
    const int z = blockIdx.y;
    const int idx = (blockIdx.x * 256 + threadIdx.x) * 4;
    const float* base = Cpart + (size_t)z * KScap * (NR * 64);
    const int n = nsp.v[z];
    f32x4 s; s[0] = s[1] = s[2] = s[3] = 0.f;
    for (int sp = 0; sp < n; ++sp)
        s += *(const f32x4*)(base + (size_t)sp * (NR * 64) + idx);
    unsigned short* o = out + (size_t)z * (NR * 64);
    #pragma unroll
    for (int e = 0; e < 4; ++e) o[idx + e] = f2bf(s[e]);
}

// split-reduce fused with CED: gc = sum(partials);
// emb = gc + alpha * (relu(LN(gc)@W1 + b1)@W2 + b2).  One wave per row.
__global__ __launch_bounds__(256) void reduce_ced(
    const float* __restrict__ Cpart, P3 ga, P3 bea, P3 W1a, P3 b1a,
    P3 W2a, P3 b2a, P3 ala, float* __restrict__ emb_out,
    I3 nsp, const int KScap)
{
    __shared__ float ln_s[4][64];
    __shared__ float h_s[4][32];
    const int z = blockIdx.y;
    const int w = threadIdx.x >> 6, l = threadIdx.x & 63;
    const int row = blockIdx.x * 4 + w;
    const float* base = Cpart + (size_t)z * KScap * (NR * 64);
    const int n = nsp.v[z];
    float x = 0.f;
    for (int sp = 0; sp < n; ++sp)
        x += base[(size_t)sp * (NR * 64) + (size_t)row * 64 + l];

    float s = x, s2 = x * x;
    #pragma unroll
    for (int off = 32; off >= 1; off >>= 1) {
        s  += __shfl_xor(s, off);
        s2 += __shfl_xor(s2, off);
    }
    const float mu  = s * (1.f / 64.f);
    const float var = s2 * (1.f / 64.f) - mu * mu;
    const float ln = (x - mu) * rsqrtf(var + 1e-5f) * ga.p[z][l] + bea.p[z][l];
    ln_s[w][l] = ln;
    __syncthreads();
    if (l < 32) {
        const float* W1 = W1a.p[z];
        float h = b1a.p[z][l];
        #pragma unroll 8
        for (int k = 0; k < 64; ++k) h += ln_s[w][k] * W1[k * 32 + l];
        h_s[w][l] = fmaxf(h, 0.f);
    }
    __syncthreads();
    const float* W2 = W2a.p[z];
    float e = b2a.p[z][l];
    #pragma unroll 8
    for (int j = 0; j < 32; ++j) e += h_s[w][j] * W2[j * 64 + l];
    emb_out[(size_t)z * (NR * 64) + (size_t)row * 64 + l] = x + ala.p[z][0] * e;
}

// fusion MLP: comb = (cat @ Wfc1 + b1) @ Wfc2 + b2; emits f32 + combT bf16
__global__ __launch_bounds__(256) void fusion_kernel(
    const float* __restrict__ emb_base, const float* __restrict__ Wfc1,
    const float* __restrict__ bfc1, const float* __restrict__ Wfc2,
    const float* __restrict__ bfc2, float* __restrict__ comb,
    unsigned short* __restrict__ combT)
{
    __shared__ float cat_s[4][192];
    __shared__ float h_s[4][64];
    const int w = threadIdx.x >> 6, l = threadIdx.x & 63;
    const int row = blockIdx.x * 4 + w;
    cat_s[w][l]       = emb_base[(size_t)row * 64 + l];
    cat_s[w][64 + l]  = emb_base[(size_t)(NR * 64) + (size_t)row * 64 + l];
    cat_s[w][128 + l] = emb_base[(size_t)(2 * NR * 64) + (size_t)row * 64 + l];
    __syncthreads();
    float h = bfc1[l];
    #pragma unroll 8
    for (int k = 0; k < 192; ++k) h += cat_s[w][k] * Wfc1[k * 64 + l];
    h_s[w][l] = h;
    __syncthreads();
    float c = bfc2[l];
    #pragma unroll 8
    for (int j = 0; j < 64; ++j) c += h_s[w][j] * Wfc2[j * 64 + l];
    comb[(size_t)row * 64 + l] = c;
    combT[(size_t)l * NR + row] = f2bf(c);      // B^T for step-4
}

// generic f32 [R][C] -> bf16 [Cp][Rp] transpose with zero-pad (weights prep)
__global__ __launch_bounds__(256) void prep_t(P6 src, U6 dst, I6 Rv6, I6 Cv6,
                                              I6 Rp6, I6 Cp6)
{
    const int z = blockIdx.y;
    const int Rp = Rp6.v[z], Cp = Cp6.v[z];
    const int rtiles = Rp >> 6, ctiles = Cp >> 6;
    const int tid = blockIdx.x;
    if (tid >= rtiles * ctiles) return;
    const int ci = tid / rtiles, ri = tid % rtiles;
    __shared__ float ld[64][65];
    const int t = threadIdx.x;
    const float* s = src.p[z];
    const int Rv = Rv6.v[z], Cv = Cv6.v[z];
    {
        const int rr = t >> 2;
        const int gr = ri * 64 + rr;
        #pragma unroll
        for (int q = 0; q < 4; ++q) {
            const int cc = (t & 3) * 16 + q * 4;
            const int gc = ci * 64 + cc;
            f32x4 x;
            if (gr < Rv && gc + 3 < Cv) {
                x = *(const f32x4*)(s + (size_t)gr * Cv + gc);
            } else {
                #pragma unroll
                for (int e = 0; e < 4; ++e)
                    x[e] = (gr < Rv && gc + e < Cv) ? s[(size_t)gr * Cv + gc + e] : 0.f;
            }
            #pragma unroll
            for (int e = 0; e < 4; ++e) ld[rr][cc + e] = x[e];
        }
    }
    __syncthreads();
    {
        unsigned short* d = dst.p[z];
        const int cl = t >> 2;
        const int r4 = (t & 3) * 16;
        unsigned short vv[16] __attribute__((aligned(16)));
        #pragma unroll
        for (int e = 0; e < 16; ++e) vv[e] = f2bf(ld[r4 + e][cl]);
        const size_t bpos = (size_t)(ci * 64 + cl) * Rp + ri * 64 + r4;
        *(bf16x8*)&d[bpos]     = *(bf16x8*)&vv[0];
        *(bf16x8*)&d[bpos + 8] = *(bf16x8*)&vv[8];
    }
}

// rec[M,Dz] = Tb[M,64](bf16) @ WdecT_z^T ; B staged from WdecT[Dp][64] bf16.
__global__ __launch_bounds__(256) void gemm_rec(
    const unsigned short* __restrict__ Tbase, V3 WdTa, O3 outa, I3 Dz)
{
    const int z = blockIdx.z;
    const int Nw = Dz.v[z];
    const int mt = blockIdx.x, nt = blockIdx.y;
    if (nt * 64 >= Nw) return;                  // uniform early-exit
    __shared__ unsigned short As[64 * 64];
    __shared__ unsigned short Bs[64 * 64];
    const int t = threadIdx.x;
    const unsigned short* Tb = Tbase + (size_t)z * (NR * 64);
    const unsigned short* Wt = (const unsigned short*)WdTa.p[z];
    float* C = outa.p[z];

    const int sr = t >> 3, sc = t & 7;
    const int l = t & 63, w = t >> 6;
    const int wm = (w >> 1) << 5, wn = (w & 1) << 5;
    const int lr = l & 15, lk = l >> 4;
    const int aw0 = sr * 64 + ((sc ^ (sr & 7)) << 3);

    #pragma unroll
    for (int j = 0; j < 2; ++j) {
        const int m = j * 32 + sr;
        *(bf16x8*)&As[aw0 + j * 2048] = *(const bf16x8*)&Tb[(size_t)(mt * 64 + m) * 64 + sc * 8];
        *(bf16x8*)&Bs[aw0 + j * 2048] = *(const bf16x8*)&Wt[(size_t)(nt * 64 + m) * 64 + sc * 8];
    }
    __syncthreads();

    f32x4 acc[2][2];
    #pragma unroll
    for (int i = 0; i < 2; ++i)
        #pragma unroll
        for (int j = 0; j < 2; ++j)
            #pragma unroll
            for (int r = 0; r < 4; ++r) acc[i][j][r] = 0.f;

    #pragma unroll
    for (int ks = 0; ks < 2; ++ks) {
        bf16x8 af[2], bfv[2];
        #pragma unroll
        for (int i = 0; i < 2; ++i) {
            const int row = wm + (i << 4) + lr;
            af[i]  = *(const bf16x8*)&As[row * 64 + ((((ks << 2) + lk) ^ (row & 7)) << 3)];
            const int col = wn + (i << 4) + lr;
            bfv[i] = *(const bf16x8*)&Bs[col * 64 + ((((ks << 2) + lk) ^ (col & 7)) << 3)];
        }
        #pragma unroll
        for (int i = 0; i < 2; ++i)
            #pragma unroll
            for (int j = 0; j < 2; ++j)
                acc[i][j] = __builtin_amdgcn_mfma_f32_16x16x32_bf16(af[i], bfv[j], acc[i][j], 0, 0, 0);
    }

    #pragma unroll
    for (int i = 0; i < 2; ++i)
        #pragma unroll
        for (int j = 0; j < 2; ++j)
            #pragma unroll
            for (int r = 0; r < 4; ++r) {
                const int row = mt * 64 + wm + (i << 4) + (lk << 2) + r;
                const int col = nt * 64 + wn + (j << 4) + lr;
                if (col < Nw) C[(size_t)row * Nw + col] = acc[i][j][r];
            }
}

extern "C" void kernel_launch(void* const* d_in, const int* in_sizes, int n_in,
                              void* d_out, int out_size, void* d_ws, size_t ws_size,
                              hipStream_t stream)
{
    const int Din[3] = {3000, 1000, 500};
    const int DinP[3] = {3008, 1024, 512};
    const float* feat[3]   = {(const float*)d_in[0], (const float*)d_in[1], (const float*)d_in[2]};
    const float* adj_sp[3] = {(const float*)d_in[3], (const float*)d_in[5], (const float*)d_in[7]};
    const float* adj_ft[3] = {(const float*)d_in[4], (const float*)d_in[6], (const float*)d_in[8]};
    const int base[3] = {9, 20, 31};
    const float *wconv[3], *bconv[3], *Wenc[3], *g[3], *be[3], *W1[3], *b1[3],
                *W2[3], *b2[3], *alpha[3], *Wdec[3];
    for (int i = 0; i < 3; ++i) {
        wconv[i] = (const float*)d_in[base[i] + 0];
        bconv[i] = (const float*)d_in[base[i] + 1];
        Wenc[i]  = (const float*)d_in[base[i] + 2];
        g[i]     = (const float*)d_in[base[i] + 3];
        be[i]    = (const float*)d_in[base[i] + 4];
        W1[i]    = (const float*)d_in[base[i] + 5];
        b1[i]    = (const float*)d_in[base[i] + 6];
        W2[i]    = (const float*)d_in[base[i] + 7];
        b2[i]    = (const float*)d_in[base[i] + 8];
        alpha[i] = (const float*)d_in[base[i] + 9];
        Wdec[i]  = (const float*)d_in[base[i] + 10];
    }
    const float* Wfc1 = (const float*)d_in[42];
    const float* bfc1 = (const float*)d_in[43];
    const float* Wfc2 = (const float*)d_in[44];
    const float* bfc2 = (const float*)d_in[45];

    // workspace: febT[3] | combT | Tb[3] (bf16), WencT[3], WdecT[3], Cpart
    char* wsb = (char*)d_ws;
    const size_t SZ_BF = (size_t)NR * 64 * 2;   // 512 KB
    const size_t SZ_F  = (size_t)NR * 64 * 4;   // 1 MB
    unsigned short* febT  = (unsigned short*)wsb;                    // 3x
    unsigned short* combT = (unsigned short*)(wsb + 3 * SZ_BF);
    unsigned short* Tb    = (unsigned short*)(wsb + 4 * SZ_BF);      // 3x
    size_t off = 7 * SZ_BF;
    unsigned short* WencT[3]; unsigned short* WdecT[3];
    for (int i = 0; i < 3; ++i) { WencT[i] = (unsigned short*)(wsb + off); off += (size_t)DinP[i] * 64 * 2; }
    for (int i = 0; i < 3; ++i) { WdecT[i] = (unsigned short*)(wsb + off); off += (size_t)DinP[i] * 64 * 2; }
    float* Cpart = (float*)(wsb + ((off + 255) & ~(size_t)255));

    int KScap = (int)((ws_size - ((off + 255) & ~(size_t)255)) / (3 * SZ_F));
    if (KScap > 8) KScap = 8;
    if (KScap < 1) KScap = 1;

    float* out = (float*)d_out;
    float* emb_out  = out;
    float* comb_out = out + 3 * (size_t)NR * 64;
    O3 rec_out;
    rec_out.p[0] = out + 4 * (size_t)NR * 64;
    rec_out.p[1] = rec_out.p[0] + (size_t)NR * Din[0];
    rec_out.p[2] = rec_out.p[1] + (size_t)NR * Din[1];

    auto split_plan = [&](const int* kts, I3& kt, I3& tps, I3& nsp, int& maxnsp) {
        maxnsp = 0;
        for (int i = 0; i < 3; ++i) {
            const int k = kts[i];
            const int t = (k + KScap - 1) / KScap;
            kt.v[i] = k; tps.v[i] = t;
            nsp.v[i] = (k + t - 1) / t;
            if (nsp.v[i] > maxnsp) maxnsp = nsp.v[i];
        }
    };

    P3 featA, adjspA, adjftA, wcA, bcA, gA, beA, W1A, b1A, W2A, b2A, alA;
    for (int i = 0; i < 3; ++i) {
        featA.p[i] = feat[i]; adjspA.p[i] = adj_sp[i]; adjftA.p[i] = adj_ft[i];
        wcA.p[i] = wconv[i];  bcA.p[i] = bconv[i];
        gA.p[i] = g[i]; beA.p[i] = be[i]; W1A.p[i] = W1[i]; b1A.p[i] = b1[i];
        W2A.p[i] = W2[i]; b2A.p[i] = b2[i]; alA.p[i] = alpha[i];
    }
    V3 BencV, BfeV, BcombV, WdTV;
    for (int i = 0; i < 3; ++i) {
        BencV.p[i]  = WencT[i];
        BfeV.p[i]   = febT + (size_t)i * NR * 64;
        BcombV.p[i] = combT;
        WdTV.p[i]   = WdecT[i];
    }
    I3 Kfeat = {Din[0], Din[1], Din[2]};
    I3 KpF   = {DinP[0], DinP[1], DinP[2]};
    I3 Kadj  = {NR, NR, NR};
    I3 Dz    = {Din[0], Din[1], Din[2]};

    const int ktF_[3] = {DinP[0] / 64, DinP[1] / 64, DinP[2] / 64};
    const int ktA_[3] = {64, 64, 64};
    I3 ktF, tpsF, nspF; int mF; split_plan(ktF_, ktF, tpsF, nspF, mF);
    I3 ktA, tpsA, nspA; int mA; split_plan(ktA_, ktA, tpsA, nspA, mA);

    // 0) weight prep: WencT [64][DinP], WdecT [DinP][64] (bf16, zero-padded)
    {
        P6 s6; U6 d6; I6 R6, C6, Rp6, Cp6;
        int maxtiles = 1;
        for (int i = 0; i < 3; ++i) {
            s6.p[i] = Wenc[i]; d6.p[i] = WencT[i];
            R6.v[i] = Din[i]; C6.v[i] = 64; Rp6.v[i] = DinP[i]; Cp6.v[i] = 64;
            s6.p[3 + i] = Wdec[i]; d6.p[3 + i] = WdecT[i];
            R6.v[3 + i] = 64; C6.v[3 + i] = Din[i]; Rp6.v[3 + i] = 64; Cp6.v[3 + i] = DinP[i];
            const int tls = DinP[i] / 64;
            if (tls > maxtiles) maxtiles = tls;
        }
        prep_t<<<dim3(maxtiles, 6), 256, 0, stream>>>(s6, d6, R6, C6, Rp6, Cp6);
    }

    // 1) fe_i = feat_i @ W_enc_i  -> transposed partials -> febT [64][NR]
    gemm_direct<false, true><<<dim3(64, mF, 3), 256, 0, stream>>>(
        featA, featA, BencV, Cpart, wcA, bcA, Kfeat, KpF, ktF, tpsF, KScap);
    reduce_many<<<dim3(256, 3), 256, 0, stream>>>(Cpart, febT, nspF, KScap);

    // 2) gc_i = (w0*adj_sp + w1*adj_ft + b) @ fe_i ; fused CED -> emb_i
    gemm_direct<true, false><<<dim3(64, mA, 3), 256, 0, stream>>>(
        adjspA, adjftA, BfeV, Cpart, wcA, bcA, Kadj, Kadj, ktA, tpsA, KScap);
    reduce_ced<<<dim3(NR / 4, 3), 256, 0, stream>>>(
        Cpart, gA, beA, W1A, b1A, W2A, b2A, alA, emb_out, nspA, KScap);

    // 3) fusion MLP -> comb (f32 out) + combT (bf16 B^T scratch)
    fusion_kernel<<<NR / 4, 256, 0, stream>>>(emb_out, Wfc1, bfc1, Wfc2, bfc2,
                                              comb_out, combT);

    // 4) T_i = adj_sp_i @ comb -> Tb [NR][64] bf16
    gemm_direct<false, false><<<dim3(64, mA, 3), 256, 0, stream>>>(
        adjspA, adjspA, BcombV, Cpart, wcA, bcA, Kadj, Kadj, ktA, tpsA, KScap);
    reduce_many<<<dim3(256, 3), 256, 0, stream>>>(Cpart, Tb, nspA, KScap);

    // 5) rec_i = T_i @ W_dec_i
    const int NTmax = DinP[0] / 64;
    gemm_rec<<<dim3(64, NTmax, 3), 256, 0, stream>>>(Tb, WdTV, rec_out, Dz);
}

// Round 7
// 439.563 us; speedup vs baseline: 1.2288x; 1.2288x over previous
//
#include <hip/hip_runtime.h>

#define NR 4096

typedef __attribute__((ext_vector_type(8))) short bf16x8;
typedef __attribute__((ext_vector_type(4))) float f32x4;

struct P3 { const float* p[3]; };
struct V3 { const void* p[3]; };
struct O3 { float* p[3]; };
struct I3 { int v[3]; };
struct P6 { const float* p[6]; };
struct U6 { unsigned short* p[6]; };
struct I6 { int v[6]; };

__device__ __forceinline__ unsigned short f2bf(float f) {
    union { float f; unsigned u; } v; v.f = f;
    unsigned r = v.u + 0x7fffu + ((v.u >> 16) & 1u);
    return (unsigned short)(r >> 16);
}

// ---------------------------------------------------------------------------
// C[M,64] = A[M,K] @ B[K,64], z-merged, NO LDS / NO BARRIERS, K-step 32.
// Wave owns 16x64 strip; fragments loaded directly from global in MFMA
// layout (lane l: A row l&15, k (l>>4)*8; B col j*16+(l&15), same k).
// R6 retro: structure was right (FETCH == ideal) but 2x-K banks demanded
// ~170 VGPR vs 128 allocated -> per-iteration scratch spill (WRITE_SIZE
// 756 MB).  K-step 32 halves every bank: ~100 VGPR, fits under the
// __launch_bounds__(256,4) cap of 128 -> no spill possible.
// Banks are named variables (no dynamic indexing); parity loop bodies.
// Waits: conv(bank) waits its A tile (leaves A(i+1),B(i),B(i+1) in flight);
// mfma waits B(i) (leaves A(i+1),B(i+1),A(i+2) in flight).  No vmcnt(0).
// B is pre-transposed bf16 B^T[64][Kp], Kp padded to 64 -> no B guard.
// DUAL folds w0*A1+w1*A2+b at conversion.  CT writes C^T.
// ---------------------------------------------------------------------------
template<bool DUAL, bool CT>
__global__ __launch_bounds__(256, 4) void gemm_direct(
    P3 A1a, P3 A2a, V3 Ba, float* __restrict__ Cpart,
    P3 wca, P3 bca, I3 Kz, I3 Kpz, I3 ktz, I3 tpsz, const int KScap)
{
    const int z = blockIdx.z;
    const int K = Kz.v[z], Kp = Kpz.v[z], ktiles = ktz.v[z], tps = tpsz.v[z];
    const int mt = blockIdx.x, sp = blockIdx.y;
    const int kt0 = sp * tps;
    int kt1 = kt0 + tps; if (kt1 > ktiles) kt1 = ktiles;
    if (kt0 >= kt1) return;
    const int niter = kt1 - kt0;

    const int t = threadIdx.x;
    const int l = t & 63, w = t >> 6;
    const int lr = l & 15, lk = l >> 4;
    const int arow = mt * 64 + w * 16 + lr;

    const float* __restrict__ A1 = A1a.p[z] + (size_t)arow * K + lk * 8;
    const float* __restrict__ A2 = (DUAL ? A2a.p[z] : A1a.p[z]) + (size_t)arow * K + lk * 8;
    const unsigned short* __restrict__ Bt = (const unsigned short*)Ba.p[z];

    float w0 = 0.f, w1 = 0.f, bb = 0.f;
    if (DUAL) { w0 = wca.p[z][0]; w1 = wca.p[z][1]; bb = bca.p[z][0]; }

    const unsigned short* Bp0 = Bt + (size_t)(lr     ) * Kp + lk * 8;
    const unsigned short* Bp1 = Bt + (size_t)(lr + 16) * Kp + lk * 8;
    const unsigned short* Bp2 = Bt + (size_t)(lr + 32) * Kp + lk * 8;
    const unsigned short* Bp3 = Bt + (size_t)(lr + 48) * Kp + lk * 8;

    f32x4 acc0, acc1, acc2, acc3;
    #pragma unroll
    for (int r = 0; r < 4; ++r) { acc0[r] = 0.f; acc1[r] = 0.f; acc2[r] = 0.f; acc3[r] = 0.f; }

    // register banks — all named, indices literal
    f32x4 xA0, xA1, yA0, yA1;      // bank A: A1 raw (x), A2 raw (y)
    f32x4 xB0, xB1, yB0, yB1;      // bank B
    bf16x8 bA0, bA1, bA2, bA3;     // bank A: B fragments
    bf16x8 bB0, bB1, bB2, bB3;     // bank B

    auto issueA = [&](int kt, f32x4& x0, f32x4& x1, f32x4& y0, f32x4& y1) {
        const int kk = kt * 32 + lk * 8;
        const float* p1 = A1 + kt * 32;
        const float* p2 = A2 + kt * 32;
        if (kk + 7 < K) {
            x0 = *(const f32x4*)p1;
            x1 = *(const f32x4*)(p1 + 4);
            if (DUAL) { y0 = *(const f32x4*)p2; y1 = *(const f32x4*)(p2 + 4); }
        } else {
            #pragma unroll
            for (int e = 0; e < 4; ++e) {
                x0[e] = (kk + e < K) ? p1[e] : 0.f;
                x1[e] = (kk + 4 + e < K) ? p1[4 + e] : 0.f;
                if (DUAL) {
                    y0[e] = (kk + e < K) ? p2[e] : 0.f;
                    y1[e] = (kk + 4 + e < K) ? p2[4 + e] : 0.f;
                }
            }
        }
    };
    auto issueB = [&](int kt, bf16x8& r0, bf16x8& r1, bf16x8& r2, bf16x8& r3) {
        r0 = *(const bf16x8*)(Bp0 + kt * 32);
        r1 = *(const bf16x8*)(Bp1 + kt * 32);
        r2 = *(const bf16x8*)(Bp2 + kt * 32);
        r3 = *(const bf16x8*)(Bp3 + kt * 32);
    };
    auto convA = [&](const f32x4& x0, const f32x4& x1,
                     const f32x4& y0, const f32x4& y1) -> bf16x8 {
        bf16x8 o;
        #pragma unroll
        for (int e = 0; e < 4; ++e) {
            const float v0 = DUAL ? (w0 * x0[e] + w1 * y0[e] + bb) : x0[e];
            const float v1 = DUAL ? (w0 * x1[e] + w1 * y1[e] + bb) : x1[e];
            o[e]     = (short)f2bf(v0);
            o[4 + e] = (short)f2bf(v1);
        }
        return o;
    };
    auto domfma = [&](bf16x8 cv, bf16x8 r0, bf16x8 r1, bf16x8 r2, bf16x8 r3) {
        acc0 = __builtin_amdgcn_mfma_f32_16x16x32_bf16(cv, r0, acc0, 0, 0, 0);
        acc1 = __builtin_amdgcn_mfma_f32_16x16x32_bf16(cv, r1, acc1, 0, 0, 0);
        acc2 = __builtin_amdgcn_mfma_f32_16x16x32_bf16(cv, r2, acc2, 0, 0, 0);
        acc3 = __builtin_amdgcn_mfma_f32_16x16x32_bf16(cv, r3, acc3, 0, 0, 0);
    };

    // prologue: tiles kt0 (bank A) and kt0+1 (bank B) in flight
    issueA(kt0, xA0, xA1, yA0, yA1);
    issueB(kt0, bA0, bA1, bA2, bA3);
    if (niter > 1) {
        issueA(kt0 + 1, xB0, xB1, yB0, yB1);
        issueB(kt0 + 1, bB0, bB1, bB2, bB3);
    }

    for (int i = 0; i < niter; ++i) {
        if ((i & 1) == 0) {
            const bf16x8 cv = convA(xA0, xA1, yA0, yA1);        // waits A(i)
            if (i + 2 < niter) issueA(kt0 + i + 2, xA0, xA1, yA0, yA1);
            domfma(cv, bA0, bA1, bA2, bA3);                     // waits B(i)
            if (i + 2 < niter) issueB(kt0 + i + 2, bA0, bA1, bA2, bA3);
        } else {
            const bf16x8 cv = convA(xB0, xB1, yB0, yB1);
            if (i + 2 < niter) issueA(kt0 + i + 2, xB0, xB1, yB0, yB1);
            domfma(cv, bB0, bB1, bB2, bB3);
            if (i + 2 < niter) issueB(kt0 + i + 2, bB0, bB1, bB2, bB3);
        }
    }

    float* Cp = Cpart + (size_t)(z * KScap + sp) * (NR * 64);
    if (CT) {
        const int row0 = mt * 64 + w * 16 + lk * 4;
        *(f32x4*)&Cp[(size_t)(lr     ) * NR + row0] = acc0;
        *(f32x4*)&Cp[(size_t)(lr + 16) * NR + row0] = acc1;
        *(f32x4*)&Cp[(size_t)(lr + 32) * NR + row0] = acc2;
        *(f32x4*)&Cp[(size_t)(lr + 48) * NR + row0] = acc3;
    } else {
        #pragma unroll
        for (int r = 0; r < 4; ++r) {
            const int row = mt * 64 + w * 16 + lk * 4 + r;
            Cp[(size_t)row * 64 + lr     ] = acc0[r];
            Cp[(size_t)row * 64 + lr + 16] = acc1[r];
            Cp[(size_t)row * 64 + lr + 32] = acc2[r];
            Cp[(size_t)row * 64 + lr + 48] = acc3[r];
        }
    }
}

// sum per-z split partials -> bf16 (layout-agnostic), z-merged
__global__ __launch_bounds__(256) void reduce_many(
    const float* __restrict__ Cpart, unsigned short* __restrict__ out,
    I3 nsp, const int KScap)
{
    const int z = blockIdx.y;
    const int idx = (blockIdx.x * 256 + threadIdx.x) * 4;
    const float* base = Cpart + (size_t)z * KScap * (NR * 64);
    const int n = nsp.v[z];
    f32x4 s; s[0] = s[1] = s[2] = s[3] = 0.f;
    for (int sp = 0; sp < n; ++sp)
        s += *(const f32x4*)(base + (size_t)sp * (NR * 64) + idx);
    unsigned short* o = out + (size_t)z * (NR * 64);
    #pragma unroll
    for (int e = 0; e < 4; ++e) o[idx + e] = f2bf(s[e]);
}

// split-reduce fused with CED: gc = sum(partials);
// emb = gc + alpha * (relu(LN(gc)@W1 + b1)@W2 + b2).  One wave per row.
__global__ __launch_bounds__(256) void reduce_ced(
    const float* __restrict__ Cpart, P3 ga, P3 bea, P3 W1a, P3 b1a,
    P3 W2a, P3 b2a, P3 ala, float* __restrict__ emb_out,
    I3 nsp, const int KScap)
{
    __shared__ float ln_s[4][64];
    __shared__ float h_s[4][32];
    const int z = blockIdx.y;
    const int w = threadIdx.x >> 6, l = threadIdx.x & 63;
    const int row = blockIdx.x * 4 + w;
    const float* base = Cpart + (size_t)z * KScap * (NR * 64);
    const int n = nsp.v[z];
    float x = 0.f;
    for (int sp = 0; sp < n; ++sp)
        x += base[(size_t)sp * (NR * 64) + (size_t)row * 64 + l];

    float s = x, s2 = x * x;
    #pragma unroll
    for (int off = 32; off >= 1; off >>= 1) {
        s  += __shfl_xor(s, off);
        s2 += __shfl_xor(s2, off);
    }
    const float mu  = s * (1.f / 64.f);
    const float var = s2 * (1.f / 64.f) - mu * mu;
    const float ln = (x - mu) * rsqrtf(var + 1e-5f) * ga.p[z][l] + bea.p[z][l];
    ln_s[w][l] = ln;
    __syncthreads();
    if (l < 32) {
        const float* W1 = W1a.p[z];
        float h = b1a.p[z][l];
        #pragma unroll 8
        for (int k = 0; k < 64; ++k) h += ln_s[w][k] * W1[k * 32 + l];
        h_s[w][l] = fmaxf(h, 0.f);
    }
    __syncthreads();
    const float* W2 = W2a.p[z];
    float e = b2a.p[z][l];
    #pragma unroll 8
    for (int j = 0; j < 32; ++j) e += h_s[w][j] * W2[j * 64 + l];
    emb_out[(size_t)z * (NR * 64) + (size_t)row * 64 + l] = x + ala.p[z][0] * e;
}

// fusion MLP: comb = (cat @ Wfc1 + b1) @ Wfc2 + b2; emits f32 + combT bf16
__global__ __launch_bounds__(256) void fusion_kernel(
    const float* __restrict__ emb_base, const float* __restrict__ Wfc1,
    const float* __restrict__ bfc1, const float* __restrict__ Wfc2,
    const float* __restrict__ bfc2, float* __restrict__ comb,
    unsigned short* __restrict__ combT)
{
    __shared__ float cat_s[4][192];
    __shared__ float h_s[4][64];
    const int w = threadIdx.x >> 6, l = threadIdx.x & 63;
    const int row = blockIdx.x * 4 + w;
    cat_s[w][l]       = emb_base[(size_t)row * 64 + l];
    cat_s[w][64 + l]  = emb_base[(size_t)(NR * 64) + (size_t)row * 64 + l];
    cat_s[w][128 + l] = emb_base[(size_t)(2 * NR * 64) + (size_t)row * 64 + l];
    __syncthreads();
    float h = bfc1[l];
    #pragma unroll 8
    for (int k = 0; k < 192; ++k) h += cat_s[w][k] * Wfc1[k * 64 + l];
    h_s[w][l] = h;
    __syncthreads();
    float c = bfc2[l];
    #pragma unroll 8
    for (int j = 0; j < 64; ++j) c += h_s[w][j] * Wfc2[j * 64 + l];
    comb[(size_t)row * 64 + l] = c;
    combT[(size_t)l * NR + row] = f2bf(c);      // B^T for step-4
}

// generic f32 [R][C] -> bf16 [Cp][Rp] transpose with zero-pad (weights prep)
__global__ __launch_bounds__(256) void prep_t(P6 src, U6 dst, I6 Rv6, I6 Cv6,
                                              I6 Rp6, I6 Cp6)
{
    const int z = blockIdx.y;
    const int Rp = Rp6.v[z], Cp = Cp6.v[z];
    const int rtiles = Rp >> 6, ctiles = Cp >> 6;
    const int tid = blockIdx.x;
    if (tid >= rtiles * ctiles) return;
    const int ci = tid / rtiles, ri = tid % rtiles;
    __shared__ float ld[64][65];
    const int t = threadIdx.x;
    const float* s = src.p[z];
    const int Rv = Rv6.v[z], Cv = Cv6.v[z];
    {
        const int rr = t >> 2;
        const int gr = ri * 64 + rr;
        #pragma unroll
        for (int q = 0; q < 4; ++q) {
            const int cc = (t & 3) * 16 + q * 4;
            const int gc = ci * 64 + cc;
            f32x4 x;
            if (gr < Rv && gc + 3 < Cv) {
                x = *(const f32x4*)(s + (size_t)gr * Cv + gc);
            } else {
                #pragma unroll
                for (int e = 0; e < 4; ++e)
                    x[e] = (gr < Rv && gc + e < Cv) ? s[(size_t)gr * Cv + gc + e] : 0.f;
            }
            #pragma unroll
            for (int e = 0; e < 4; ++e) ld[rr][cc + e] = x[e];
        }
    }
    __syncthreads();
    {
        unsigned short* d = dst.p[z];
        const int cl = t >> 2;
        const int r4 = (t & 3) * 16;
        unsigned short vv[16] __attribute__((aligned(16)));
        #pragma unroll
        for (int e = 0; e < 16; ++e) vv[e] = f2bf(ld[r4 + e][cl]);
        const size_t bpos = (size_t)(ci * 64 + cl) * Rp + ri * 64 + r4;
        *(bf16x8*)&d[bpos]     = *(bf16x8*)&vv[0];
        *(bf16x8*)&d[bpos + 8] = *(bf16x8*)&vv[8];
    }
}

// rec[M,Dz] = Tb[M,64](bf16) @ WdecT_z^T ; B staged from WdecT[Dp][64] bf16.
__global__ __launch_bounds__(256) void gemm_rec(
    const unsigned short* __restrict__ Tbase, V3 WdTa, O3 outa, I3 Dz)
{
    const int z = blockIdx.z;
    const int Nw = Dz.v[z];
    const int mt = blockIdx.x, nt = blockIdx.y;
    if (nt * 64 >= Nw) return;                  // uniform early-exit
    __shared__ unsigned short As[64 * 64];
    __shared__ unsigned short Bs[64 * 64];
    const int t = threadIdx.x;
    const unsigned short* Tb = Tbase + (size_t)z * (NR * 64);
    const unsigned short* Wt = (const unsigned short*)WdTa.p[z];
    float* C = outa.p[z];

    const int sr = t >> 3, sc = t & 7;
    const int l = t & 63, w = t >> 6;
    const int wm = (w >> 1) << 5, wn = (w & 1) << 5;
    const int lr = l & 15, lk = l >> 4;
    const int aw0 = sr * 64 + ((sc ^ (sr & 7)) << 3);

    #pragma unroll
    for (int j = 0; j < 2; ++j) {
        const int m = j * 32 + sr;
        *(bf16x8*)&As[aw0 + j * 2048] = *(const bf16x8*)&Tb[(size_t)(mt * 64 + m) * 64 + sc * 8];
        *(bf16x8*)&Bs[aw0 + j * 2048] = *(const bf16x8*)&Wt[(size_t)(nt * 64 + m) * 64 + sc * 8];
    }
    __syncthreads();

    f32x4 acc[2][2];
    #pragma unroll
    for (int i = 0; i < 2; ++i)
        #pragma unroll
        for (int j = 0; j < 2; ++j)
            #pragma unroll
            for (int r = 0; r < 4; ++r) acc[i][j][r] = 0.f;

    #pragma unroll
    for (int ks = 0; ks < 2; ++ks) {
        bf16x8 af[2], bfv[2];
        #pragma unroll
        for (int i = 0; i < 2; ++i) {
            const int row = wm + (i << 4) + lr;
            af[i]  = *(const bf16x8*)&As[row * 64 + ((((ks << 2) + lk) ^ (row & 7)) << 3)];
            const int col = wn + (i << 4) + lr;
            bfv[i] = *(const bf16x8*)&Bs[col * 64 + ((((ks << 2) + lk) ^ (col & 7)) << 3)];
        }
        #pragma unroll
        for (int i = 0; i < 2; ++i)
            #pragma unroll
            for (int j = 0; j < 2; ++j)
                acc[i][j] = __builtin_amdgcn_mfma_f32_16x16x32_bf16(af[i], bfv[j], acc[i][j], 0, 0, 0);
    }

    #pragma unroll
    for (int i = 0; i < 2; ++i)
        #pragma unroll
        for (int j = 0; j < 2; ++j)
            #pragma unroll
            for (int r = 0; r < 4; ++r) {
                const int row = mt * 64 + wm + (i << 4) + (lk << 2) + r;
                const int col = nt * 64 + wn + (j << 4) + lr;
                if (col < Nw) C[(size_t)row * Nw + col] = acc[i][j][r];
            }
}

extern "C" void kernel_launch(void* const* d_in, const int* in_sizes, int n_in,
                              void* d_out, int out_size, void* d_ws, size_t ws_size,
                              hipStream_t stream)
{
    const int Din[3] = {3000, 1000, 500};
    const int DinP[3] = {3008, 1024, 512};
    const float* feat[3]   = {(const float*)d_in[0], (const float*)d_in[1], (const float*)d_in[2]};
    const float* adj_sp[3] = {(const float*)d_in[3], (const float*)d_in[5], (const float*)d_in[7]};
    const float* adj_ft[3] = {(const float*)d_in[4], (const float*)d_in[6], (const float*)d_in[8]};
    const int base[3] = {9, 20, 31};
    const float *wconv[3], *bconv[3], *Wenc[3], *g[3], *be[3], *W1[3], *b1[3],
                *W2[3], *b2[3], *alpha[3], *Wdec[3];
    for (int i = 0; i < 3; ++i) {
        wconv[i] = (const float*)d_in[base[i] + 0];
        bconv[i] = (const float*)d_in[base[i] + 1];
        Wenc[i]  = (const float*)d_in[base[i] + 2];
        g[i]     = (const float*)d_in[base[i] + 3];
        be[i]    = (const float*)d_in[base[i] + 4];
        W1[i]    = (const float*)d_in[base[i] + 5];
        b1[i]    = (const float*)d_in[base[i] + 6];
        W2[i]    = (const float*)d_in[base[i] + 7];
        b2[i]    = (const float*)d_in[base[i] + 8];
        alpha[i] = (const float*)d_in[base[i] + 9];
        Wdec[i]  = (const float*)d_in[base[i] + 10];
    }
    const float* Wfc1 = (const float*)d_in[42];
    const float* bfc1 = (const float*)d_in[43];
    const float* Wfc2 = (const float*)d_in[44];
    const float* bfc2 = (const float*)d_in[45];

    // workspace: febT[3] | combT | Tb[3] (bf16), WencT[3], WdecT[3], Cpart
    char* wsb = (char*)d_ws;
    const size_t SZ_BF = (size_t)NR * 64 * 2;   // 512 KB
    const size_t SZ_F  = (size_t)NR * 64 * 4;   // 1 MB
    unsigned short* febT  = (unsigned short*)wsb;                    // 3x
    unsigned short* combT = (unsigned short*)(wsb + 3 * SZ_BF);
    unsigned short* Tb    = (unsigned short*)(wsb + 4 * SZ_BF);      // 3x
    size_t off = 7 * SZ_BF;
    unsigned short* WencT[3]; unsigned short* WdecT[3];
    for (int i = 0; i < 3; ++i) { WencT[i] = (unsigned short*)(wsb + off); off += (size_t)DinP[i] * 64 * 2; }
    for (int i = 0; i < 3; ++i) { WdecT[i] = (unsigned short*)(wsb + off); off += (size_t)DinP[i] * 64 * 2; }
    float* Cpart = (float*)(wsb + ((off + 255) & ~(size_t)255));

    int KScap = (int)((ws_size - ((off + 255) & ~(size_t)255)) / (3 * SZ_F));
    if (KScap > 8) KScap = 8;
    if (KScap < 1) KScap = 1;

    float* out = (float*)d_out;
    float* emb_out  = out;
    float* comb_out = out + 3 * (size_t)NR * 64;
    O3 rec_out;
    rec_out.p[0] = out + 4 * (size_t)NR * 64;
    rec_out.p[1] = rec_out.p[0] + (size_t)NR * Din[0];
    rec_out.p[2] = rec_out.p[1] + (size_t)NR * Din[1];

    auto split_plan = [&](const int* kts, I3& kt, I3& tps, I3& nsp, int& maxnsp) {
        maxnsp = 0;
        for (int i = 0; i < 3; ++i) {
            const int k = kts[i];
            const int t = (k + KScap - 1) / KScap;
            kt.v[i] = k; tps.v[i] = t;
            nsp.v[i] = (k + t - 1) / t;
            if (nsp.v[i] > maxnsp) maxnsp = nsp.v[i];
        }
    };

    P3 featA, adjspA, adjftA, wcA, bcA, gA, beA, W1A, b1A, W2A, b2A, alA;
    for (int i = 0; i < 3; ++i) {
        featA.p[i] = feat[i]; adjspA.p[i] = adj_sp[i]; adjftA.p[i] = adj_ft[i];
        wcA.p[i] = wconv[i];  bcA.p[i] = bconv[i];
        gA.p[i] = g[i]; beA.p[i] = be[i]; W1A.p[i] = W1[i]; b1A.p[i] = b1[i];
        W2A.p[i] = W2[i]; b2A.p[i] = b2[i]; alA.p[i] = alpha[i];
    }
    V3 BencV, BfeV, BcombV, WdTV;
    for (int i = 0; i < 3; ++i) {
        BencV.p[i]  = WencT[i];
        BfeV.p[i]   = febT + (size_t)i * NR * 64;
        BcombV.p[i] = combT;
        WdTV.p[i]   = WdecT[i];
    }
    I3 Kfeat = {Din[0], Din[1], Din[2]};
    I3 KpF   = {DinP[0], DinP[1], DinP[2]};
    I3 Kadj  = {NR, NR, NR};
    I3 Dz    = {Din[0], Din[1], Din[2]};

    // K-step 32 tiles
    const int ktF_[3] = {DinP[0] / 32, DinP[1] / 32, DinP[2] / 32};
    const int ktA_[3] = {NR / 32, NR / 32, NR / 32};
    I3 ktF, tpsF, nspF; int mF; split_plan(ktF_, ktF, tpsF, nspF, mF);
    I3 ktA, tpsA, nspA; int mA; split_plan(ktA_, ktA, tpsA, nspA, mA);

    // 0) weight prep: WencT [64][DinP], WdecT [DinP][64] (bf16, zero-padded)
    {
        P6 s6; U6 d6; I6 R6, C6, Rp6, Cp6;
        int maxtiles = 1;
        for (int i = 0; i < 3; ++i) {
            s6.p[i] = Wenc[i]; d6.p[i] = WencT[i];
            R6.v[i] = Din[i]; C6.v[i] = 64; Rp6.v[i] = DinP[i]; Cp6.v[i] = 64;
            s6.p[3 + i] = Wdec[i]; d6.p[3 + i] = WdecT[i];
            R6.v[3 + i] = 64; C6.v[3 + i] = Din[i]; Rp6.v[3 + i] = 64; Cp6.v[3 + i] = DinP[i];
            const int tls = DinP[i] / 64;
            if (tls > maxtiles) maxtiles = tls;
        }
        prep_t<<<dim3(maxtiles, 6), 256, 0, stream>>>(s6, d6, R6, C6, Rp6, Cp6);
    }

    // 1) fe_i = feat_i @ W_enc_i  -> transposed partials -> febT [64][NR]
    gemm_direct<false, true><<<dim3(64, mF, 3), 256, 0, stream>>>(
        featA, featA, BencV, Cpart, wcA, bcA, Kfeat, KpF, ktF, tpsF, KScap);
    reduce_many<<<dim3(256, 3), 256, 0, stream>>>(Cpart, febT, nspF, KScap);

    // 2) gc_i = (w0*adj_sp + w1*adj_ft + b) @ fe_i ; fused CED -> emb_i
    gemm_direct<true, false><<<dim3(64, mA, 3), 256, 0, stream>>>(
        adjspA, adjftA, BfeV, Cpart, wcA, bcA, Kadj, Kadj, ktA, tpsA, KScap);
    reduce_ced<<<dim3(NR / 4, 3), 256, 0, stream>>>(
        Cpart, gA, beA, W1A, b1A, W2A, b2A, alA, emb_out, nspA, KScap);

    // 3) fusion MLP -> comb (f32 out) + combT (bf16 B^T scratch)
    fusion_kernel<<<NR / 4, 256, 0, stream>>>(emb_out, Wfc1, bfc1, Wfc2, bfc2,
                                              comb_out, combT);

    // 4) T_i = adj_sp_i @ comb -> Tb [NR][64] bf16
    gemm_direct<false, false><<<dim3(64, mA, 3), 256, 0, stream>>>(
        adjspA, adjspA, BcombV, Cpart, wcA, bcA, Kadj, Kadj, ktA, tpsA, KScap);
    reduce_many<<<dim3(256, 3), 256, 0, stream>>>(Cpart, Tb, nspA, KScap);

    // 5) rec_i = T_i @ W_dec_i
    const int NTmax = DinP[0] / 64;
    gemm_rec<<<dim3(64, NTmax, 3), 256, 0, stream>>>(Tb, WdTV, rec_out, Dz);
}

// Round 8
// 401.027 us; speedup vs baseline: 1.3469x; 1.0961x over previous
//
#include <hip/hip_runtime.h>

#define NR 4096

typedef __attribute__((ext_vector_type(8))) short bf16x8;
typedef __attribute__((ext_vector_type(4))) float f32x4;

struct P3 { const float* p[3]; };
struct V3 { const void* p[3]; };
struct O3 { float* p[3]; };
struct I3 { int v[3]; };
struct P6 { const float* p[6]; };
struct V6 { const void* p[6]; };
struct U6 { unsigned short* p[6]; };
struct I6 { int v[6]; };

__device__ __forceinline__ unsigned short f2bf(float f) {
    union { float f; unsigned u; } v; v.f = f;
    unsigned r = v.u + 0x7fffu + ((v.u >> 16) & 1u);
    return (unsigned short)(r >> 16);
}
__device__ __forceinline__ float bf2f(unsigned short b) {
    union { unsigned u; float f; } v; v.u = ((unsigned)b) << 16;
    return v.f;
}

// ---------------------------------------------------------------------------
// C[M,64] = A[M,K] @ B[K,64], SINGLE f32 A stream, no LDS / no barriers,
// K-step 32, depth-2 parity register banks.
// R6/R7 retro: structure right (FETCH == ideal) but register demand blew the
// arch-VGPR cap (cap = 256/waves_per_EU; MFMA acc takes a separate AGPR
// block) -> scratch spill (WRITE_SIZE 291-756 MB).  Fix is ALGEBRAIC:
// the dual fusion is linear, so w0*A1+w1*A2+b is computed AFTER the matmuls
// (reduce_ced: w0*S1 + w1*S2 + b*colsum(B)).  Single stream needs only
// ~90 arch VGPRs -> fits the 128 cap of __launch_bounds__(256,2) (R6 data).
// Lane l: A row l&15 (f32, convert deferred one iter), B col j*16+(l&15)
// from pre-transposed bf16 B^T[64][Kp] (L2-resident).  CT writes C^T.
// Split-K partials -> Cpart slot (z*KScap+sp), deterministic.
// ---------------------------------------------------------------------------
template<bool CT>
__global__ __launch_bounds__(256, 2) void gemm_single(
    P6 Aa, V6 Ba, float* __restrict__ Cpart,
    I6 Kz, I6 Kpz, I6 ktz, I6 tpsz, const int KScap)
{
    const int z = blockIdx.z;
    const int K = Kz.v[z], Kp = Kpz.v[z], ktiles = ktz.v[z], tps = tpsz.v[z];
    const int mt = blockIdx.x, sp = blockIdx.y;
    const int kt0 = sp * tps;
    int kt1 = kt0 + tps; if (kt1 > ktiles) kt1 = ktiles;
    if (kt0 >= kt1) return;
    const int niter = kt1 - kt0;

    const int t = threadIdx.x;
    const int l = t & 63, w = t >> 6;
    const int lr = l & 15, lk = l >> 4;
    const int arow = mt * 64 + w * 16 + lr;

    const float* __restrict__ A = Aa.p[z] + (size_t)arow * K + lk * 8;
    const unsigned short* __restrict__ Bt = (const unsigned short*)Ba.p[z];
    const unsigned short* Bp0 = Bt + (size_t)(lr     ) * Kp + lk * 8;
    const unsigned short* Bp1 = Bt + (size_t)(lr + 16) * Kp + lk * 8;
    const unsigned short* Bp2 = Bt + (size_t)(lr + 32) * Kp + lk * 8;
    const unsigned short* Bp3 = Bt + (size_t)(lr + 48) * Kp + lk * 8;

    f32x4 acc0, acc1, acc2, acc3;
    #pragma unroll
    for (int r = 0; r < 4; ++r) { acc0[r] = 0.f; acc1[r] = 0.f; acc2[r] = 0.f; acc3[r] = 0.f; }

    // parity register banks — all named, literal indices only
    f32x4 xA0, xA1, xB0, xB1;
    bf16x8 bA0, bA1, bA2, bA3, bB0, bB1, bB2, bB3;

    auto issueA = [&](int kt, f32x4& x0, f32x4& x1) {
        const int kk = kt * 32 + lk * 8;
        const float* p = A + kt * 32;
        if (kk + 7 < K) {
            x0 = *(const f32x4*)p;
            x1 = *(const f32x4*)(p + 4);
        } else {
            #pragma unroll
            for (int e = 0; e < 4; ++e) {
                x0[e] = (kk + e < K) ? p[e] : 0.f;
                x1[e] = (kk + 4 + e < K) ? p[4 + e] : 0.f;
            }
        }
    };
    auto issueB = [&](int kt, bf16x8& r0, bf16x8& r1, bf16x8& r2, bf16x8& r3) {
        r0 = *(const bf16x8*)(Bp0 + kt * 32);
        r1 = *(const bf16x8*)(Bp1 + kt * 32);
        r2 = *(const bf16x8*)(Bp2 + kt * 32);
        r3 = *(const bf16x8*)(Bp3 + kt * 32);
    };
    auto convA = [&](const f32x4& x0, const f32x4& x1) -> bf16x8 {
        bf16x8 o;
        #pragma unroll
        for (int e = 0; e < 4; ++e) {
            o[e]     = (short)f2bf(x0[e]);
            o[4 + e] = (short)f2bf(x1[e]);
        }
        return o;
    };
    auto domfma = [&](bf16x8 cv, bf16x8 r0, bf16x8 r1, bf16x8 r2, bf16x8 r3) {
        acc0 = __builtin_amdgcn_mfma_f32_16x16x32_bf16(cv, r0, acc0, 0, 0, 0);
        acc1 = __builtin_amdgcn_mfma_f32_16x16x32_bf16(cv, r1, acc1, 0, 0, 0);
        acc2 = __builtin_amdgcn_mfma_f32_16x16x32_bf16(cv, r2, acc2, 0, 0, 0);
        acc3 = __builtin_amdgcn_mfma_f32_16x16x32_bf16(cv, r3, acc3, 0, 0, 0);
    };

    // prologue: tiles kt0 (bank A) and kt0+1 (bank B) in flight
    issueA(kt0, xA0, xA1);
    issueB(kt0, bA0, bA1, bA2, bA3);
    if (niter > 1) {
        issueA(kt0 + 1, xB0, xB1);
        issueB(kt0 + 1, bB0, bB1, bB2, bB3);
    }

    for (int i = 0; i < niter; ++i) {
        if ((i & 1) == 0) {                   // uniform branch
            const bf16x8 cv = convA(xA0, xA1);          // waits A(i) only
            if (i + 2 < niter) issueA(kt0 + i + 2, xA0, xA1);
            domfma(cv, bA0, bA1, bA2, bA3);             // waits B(i)
            if (i + 2 < niter) issueB(kt0 + i + 2, bA0, bA1, bA2, bA3);
        } else {
            const bf16x8 cv = convA(xB0, xB1);
            if (i + 2 < niter) issueA(kt0 + i + 2, xB0, xB1);
            domfma(cv, bB0, bB1, bB2, bB3);
            if (i + 2 < niter) issueB(kt0 + i + 2, bB0, bB1, bB2, bB3);
        }
    }

    float* Cp = Cpart + (size_t)(z * KScap + sp) * (NR * 64);
    if (CT) {
        const int row0 = mt * 64 + w * 16 + lk * 4;
        *(f32x4*)&Cp[(size_t)(lr     ) * NR + row0] = acc0;
        *(f32x4*)&Cp[(size_t)(lr + 16) * NR + row0] = acc1;
        *(f32x4*)&Cp[(size_t)(lr + 32) * NR + row0] = acc2;
        *(f32x4*)&Cp[(size_t)(lr + 48) * NR + row0] = acc3;
    } else {
        #pragma unroll
        for (int r = 0; r < 4; ++r) {
            const int row = mt * 64 + w * 16 + lk * 4 + r;
            Cp[(size_t)row * 64 + lr     ] = acc0[r];
            Cp[(size_t)row * 64 + lr + 16] = acc1[r];
            Cp[(size_t)row * 64 + lr + 32] = acc2[r];
            Cp[(size_t)row * 64 + lr + 48] = acc3[r];
        }
    }
}

// sum per-z split partials -> bf16 (layout-agnostic), z-merged
__global__ __launch_bounds__(256) void reduce_many(
    const float* __restrict__ Cpart, unsigned short* __restrict__ out,
    I3 nsp, const int KScap)
{
    const int z = blockIdx.y;
    const int idx = (blockIdx.x * 256 + threadIdx.x) * 4;
    const float* base = Cpart + (size_t)z * KScap * (NR * 64);
    const int n = nsp.v[z];
    f32x4 s; s[0] = s[1] = s[2] = s[3] = 0.f;
    for (int sp = 0; sp < n; ++sp)
        s += *(const f32x4*)(base + (size_t)sp * (NR * 64) + idx);
    unsigned short* o = out + (size_t)z * (NR * 64);
    #pragma unroll
    for (int e = 0; e < 4; ++e) o[idx + e] = f2bf(s[e]);
}

// column sums of fe (from febT [64][NR]): csum[z][c] = sum_r fe[r][c]
__global__ __launch_bounds__(256) void colsum_kernel(
    const unsigned short* __restrict__ febT, float* __restrict__ csum)
{
    const int z = blockIdx.x;
    const int t = threadIdx.x, w = t >> 6, l = t & 63;
    for (int row = w; row < 64; row += 4) {
        const unsigned short* src = febT + ((size_t)z * 64 + row) * NR;
        float s = 0.f;
        for (int i = l * 8; i < NR; i += 512) {
            const bf16x8 v = *(const bf16x8*)(src + i);
            #pragma unroll
            for (int e = 0; e < 8; ++e) s += bf2f((unsigned short)v[e]);
        }
        #pragma unroll
        for (int off = 32; off >= 1; off >>= 1) s += __shfl_xor(s, off);
        if (l == 0) csum[z * 64 + row] = s;
    }
}

// combine split partials of the two adjacency GEMMs with conv weights +
// bias*colsum, then fused CED:
// gc = w0*S1 + w1*S2 + b*csum;  emb = gc + alpha*(relu(LN(gc)@W1+b1)@W2+b2)
__global__ __launch_bounds__(256) void reduce_ced(
    const float* __restrict__ Cpart, P3 wca, P3 bca,
    const float* __restrict__ csum, P3 ga, P3 bea, P3 W1a, P3 b1a,
    P3 W2a, P3 b2a, P3 ala, float* __restrict__ emb_out,
    I6 nsp, const int KScap)
{
    __shared__ float ln_s[4][64];
    __shared__ float h_s[4][32];
    const int z = blockIdx.y;
    const int w = threadIdx.x >> 6, l = threadIdx.x & 63;
    const int row = blockIdx.x * 4 + w;
    const float* b1p = Cpart + (size_t)z * KScap * (NR * 64);
    const float* b2p = Cpart + (size_t)(3 + z) * KScap * (NR * 64);
    const int n1 = nsp.v[z], n2 = nsp.v[3 + z];
    float s1 = 0.f, s2 = 0.f;
    for (int sp = 0; sp < n1; ++sp)
        s1 += b1p[(size_t)sp * (NR * 64) + (size_t)row * 64 + l];
    for (int sp = 0; sp < n2; ++sp)
        s2 += b2p[(size_t)sp * (NR * 64) + (size_t)row * 64 + l];
    const float w0 = wca.p[z][0], w1 = wca.p[z][1], bb = bca.p[z][0];
    const float x = w0 * s1 + w1 * s2 + bb * csum[z * 64 + l];

    float s = x, s2v = x * x;
    #pragma unroll
    for (int off = 32; off >= 1; off >>= 1) {
        s   += __shfl_xor(s, off);
        s2v += __shfl_xor(s2v, off);
    }
    const float mu  = s * (1.f / 64.f);
    const float var = s2v * (1.f / 64.f) - mu * mu;
    const float ln = (x - mu) * rsqrtf(var + 1e-5f) * ga.p[z][l] + bea.p[z][l];
    ln_s[w][l] = ln;
    __syncthreads();
    if (l < 32) {
        const float* W1 = W1a.p[z];
        float h = b1a.p[z][l];
        #pragma unroll 8
        for (int k = 0; k < 64; ++k) h += ln_s[w][k] * W1[k * 32 + l];
        h_s[w][l] = fmaxf(h, 0.f);
    }
    __syncthreads();
    const float* W2 = W2a.p[z];
    float e = b2a.p[z][l];
    #pragma unroll 8
    for (int j = 0; j < 32; ++j) e += h_s[w][j] * W2[j * 64 + l];
    emb_out[(size_t)z * (NR * 64) + (size_t)row * 64 + l] = x + ala.p[z][0] * e;
}

// fusion MLP: comb = (cat @ Wfc1 + b1) @ Wfc2 + b2; emits f32 + combT bf16
__global__ __launch_bounds__(256) void fusion_kernel(
    const float* __restrict__ emb_base, const float* __restrict__ Wfc1,
    const float* __restrict__ bfc1, const float* __restrict__ Wfc2,
    const float* __restrict__ bfc2, float* __restrict__ comb,
    unsigned short* __restrict__ combT)
{
    __shared__ float cat_s[4][192];
    __shared__ float h_s[4][64];
    const int w = threadIdx.x >> 6, l = threadIdx.x & 63;
    const int row = blockIdx.x * 4 + w;
    cat_s[w][l]       = emb_base[(size_t)row * 64 + l];
    cat_s[w][64 + l]  = emb_base[(size_t)(NR * 64) + (size_t)row * 64 + l];
    cat_s[w][128 + l] = emb_base[(size_t)(2 * NR * 64) + (size_t)row * 64 + l];
    __syncthreads();
    float h = bfc1[l];
    #pragma unroll 8
    for (int k = 0; k < 192; ++k) h += cat_s[w][k] * Wfc1[k * 64 + l];
    h_s[w][l] = h;
    __syncthreads();
    float c = bfc2[l];
    #pragma unroll 8
    for (int j = 0; j < 64; ++j) c += h_s[w][j] * Wfc2[j * 64 + l];
    comb[(size_t)row * 64 + l] = c;
    combT[(size_t)l * NR + row] = f2bf(c);      // B^T for step-4
}

// generic f32 [R][C] -> bf16 [Cp][Rp] transpose with zero-pad (weights prep)
__global__ __launch_bounds__(256) void prep_t(P6 src, U6 dst, I6 Rv6, I6 Cv6,
                                              I6 Rp6, I6 Cp6)
{
    const int z = blockIdx.y;
    const int Rp = Rp6.v[z], Cp = Cp6.v[z];
    const int rtiles = Rp >> 6, ctiles = Cp >> 6;
    const int tid = blockIdx.x;
    if (tid >= rtiles * ctiles) return;
    const int ci = tid / rtiles, ri = tid % rtiles;
    __shared__ float ld[64][65];
    const int t = threadIdx.x;
    const float* s = src.p[z];
    const int Rv = Rv6.v[z], Cv = Cv6.v[z];
    {
        const int rr = t >> 2;
        const int gr = ri * 64 + rr;
        #pragma unroll
        for (int q = 0; q < 4; ++q) {
            const int cc = (t & 3) * 16 + q * 4;
            const int gc = ci * 64 + cc;
            f32x4 x;
            if (gr < Rv && gc + 3 < Cv) {
                x = *(const f32x4*)(s + (size_t)gr * Cv + gc);
            } else {
                #pragma unroll
                for (int e = 0; e < 4; ++e)
                    x[e] = (gr < Rv && gc + e < Cv) ? s[(size_t)gr * Cv + gc + e] : 0.f;
            }
            #pragma unroll
            for (int e = 0; e < 4; ++e) ld[rr][cc + e] = x[e];
        }
    }
    __syncthreads();
    {
        unsigned short* d = dst.p[z];
        const int cl = t >> 2;
        const int r4 = (t & 3) * 16;
        unsigned short vv[16] __attribute__((aligned(16)));
        #pragma unroll
        for (int e = 0; e < 16; ++e) vv[e] = f2bf(ld[r4 + e][cl]);
        const size_t bpos = (size_t)(ci * 64 + cl) * Rp + ri * 64 + r4;
        *(bf16x8*)&d[bpos]     = *(bf16x8*)&vv[0];
        *(bf16x8*)&d[bpos + 8] = *(bf16x8*)&vv[8];
    }
}

// rec[M,Dz] = Tb[M,64](bf16) @ WdecT_z^T ; B staged from WdecT[Dp][64] bf16.
__global__ __launch_bounds__(256) void gemm_rec(
    const unsigned short* __restrict__ Tbase, V3 WdTa, O3 outa, I3 Dz)
{
    const int z = blockIdx.z;
    const int Nw = Dz.v[z];
    const int mt = blockIdx.x, nt = blockIdx.y;
    if (nt * 64 >= Nw) return;                  // uniform early-exit
    __shared__ unsigned short As[64 * 64];
    __shared__ unsigned short Bs[64 * 64];
    const int t = threadIdx.x;
    const unsigned short* Tb = Tbase + (size_t)z * (NR * 64);
    const unsigned short* Wt = (const unsigned short*)WdTa.p[z];
    float* C = outa.p[z];

    const int sr = t >> 3, sc = t & 7;
    const int l = t & 63, w = t >> 6;
    const int wm = (w >> 1) << 5, wn = (w & 1) << 5;
    const int lr = l & 15, lk = l >> 4;
    const int aw0 = sr * 64 + ((sc ^ (sr & 7)) << 3);

    #pragma unroll
    for (int j = 0; j < 2; ++j) {
        const int m = j * 32 + sr;
        *(bf16x8*)&As[aw0 + j * 2048] = *(const bf16x8*)&Tb[(size_t)(mt * 64 + m) * 64 + sc * 8];
        *(bf16x8*)&Bs[aw0 + j * 2048] = *(const bf16x8*)&Wt[(size_t)(nt * 64 + m) * 64 + sc * 8];
    }
    __syncthreads();

    f32x4 acc[2][2];
    #pragma unroll
    for (int i = 0; i < 2; ++i)
        #pragma unroll
        for (int j = 0; j < 2; ++j)
            #pragma unroll
            for (int r = 0; r < 4; ++r) acc[i][j][r] = 0.f;

    #pragma unroll
    for (int ks = 0; ks < 2; ++ks) {
        bf16x8 af[2], bfv[2];
        #pragma unroll
        for (int i = 0; i < 2; ++i) {
            const int row = wm + (i << 4) + lr;
            af[i]  = *(const bf16x8*)&As[row * 64 + ((((ks << 2) + lk) ^ (row & 7)) << 3)];
            const int col = wn + (i << 4) + lr;
            bfv[i] = *(const bf16x8*)&Bs[col * 64 + ((((ks << 2) + lk) ^ (col & 7)) << 3)];
        }
        #pragma unroll
        for (int i = 0; i < 2; ++i)
            #pragma unroll
            for (int j = 0; j < 2; ++j)
                acc[i][j] = __builtin_amdgcn_mfma_f32_16x16x32_bf16(af[i], bfv[j], acc[i][j], 0, 0, 0);
    }

    #pragma unroll
    for (int i = 0; i < 2; ++i)
        #pragma unroll
        for (int j = 0; j < 2; ++j)
            #pragma unroll
            for (int r = 0; r < 4; ++r) {
                const int row = mt * 64 + wm + (i << 4) + (lk << 2) + r;
                const int col = nt * 64 + wn + (j << 4) + lr;
                if (col < Nw) C[(size_t)row * Nw + col] = acc[i][j][r];
            }
}

extern "C" void kernel_launch(void* const* d_in, const int* in_sizes, int n_in,
                              void* d_out, int out_size, void* d_ws, size_t ws_size,
                              hipStream_t stream)
{
    const int Din[3] = {3000, 1000, 500};
    const int DinP[3] = {3008, 1024, 512};
    const float* feat[3]   = {(const float*)d_in[0], (const float*)d_in[1], (const float*)d_in[2]};
    const float* adj_sp[3] = {(const float*)d_in[3], (const float*)d_in[5], (const float*)d_in[7]};
    const float* adj_ft[3] = {(const float*)d_in[4], (const float*)d_in[6], (const float*)d_in[8]};
    const int base[3] = {9, 20, 31};
    const float *wconv[3], *bconv[3], *Wenc[3], *g[3], *be[3], *W1[3], *b1[3],
                *W2[3], *b2[3], *alpha[3], *Wdec[3];
    for (int i = 0; i < 3; ++i) {
        wconv[i] = (const float*)d_in[base[i] + 0];
        bconv[i] = (const float*)d_in[base[i] + 1];
        Wenc[i]  = (const float*)d_in[base[i] + 2];
        g[i]     = (const float*)d_in[base[i] + 3];
        be[i]    = (const float*)d_in[base[i] + 4];
        W1[i]    = (const float*)d_in[base[i] + 5];
        b1[i]    = (const float*)d_in[base[i] + 6];
        W2[i]    = (const float*)d_in[base[i] + 7];
        b2[i]    = (const float*)d_in[base[i] + 8];
        alpha[i] = (const float*)d_in[base[i] + 9];
        Wdec[i]  = (const float*)d_in[base[i] + 10];
    }
    const float* Wfc1 = (const float*)d_in[42];
    const float* bfc1 = (const float*)d_in[43];
    const float* Wfc2 = (const float*)d_in[44];
    const float* bfc2 = (const float*)d_in[45];

    // workspace: febT[3] | combT | Tb[3] (bf16), WencT[3], WdecT[3], csum, Cpart
    char* wsb = (char*)d_ws;
    const size_t SZ_BF = (size_t)NR * 64 * 2;   // 512 KB
    const size_t SZ_F  = (size_t)NR * 64 * 4;   // 1 MB
    unsigned short* febT  = (unsigned short*)wsb;                    // 3x
    unsigned short* combT = (unsigned short*)(wsb + 3 * SZ_BF);
    unsigned short* Tb    = (unsigned short*)(wsb + 4 * SZ_BF);      // 3x
    size_t off = 7 * SZ_BF;
    unsigned short* WencT[3]; unsigned short* WdecT[3];
    for (int i = 0; i < 3; ++i) { WencT[i] = (unsigned short*)(wsb + off); off += (size_t)DinP[i] * 64 * 2; }
    for (int i = 0; i < 3; ++i) { WdecT[i] = (unsigned short*)(wsb + off); off += (size_t)DinP[i] * 64 * 2; }
    float* csum = (float*)(wsb + ((off + 255) & ~(size_t)255));
    off = ((off + 255) & ~(size_t)255) + 3 * 64 * sizeof(float);
    float* Cpart = (float*)(wsb + ((off + 255) & ~(size_t)255));
    const size_t cpart_off = ((off + 255) & ~(size_t)255);

    // 6 partial slots groups (step-2 uses all 6; steps 1/4 use first 3)
    int KScap = (int)((ws_size - cpart_off) / (6 * SZ_F));
    if (KScap > 6) KScap = 6;
    if (KScap < 1) KScap = 1;

    float* out = (float*)d_out;
    float* emb_out  = out;
    float* comb_out = out + 3 * (size_t)NR * 64;
    O3 rec_out;
    rec_out.p[0] = out + 4 * (size_t)NR * 64;
    rec_out.p[1] = rec_out.p[0] + (size_t)NR * Din[0];
    rec_out.p[2] = rec_out.p[1] + (size_t)NR * Din[1];

    auto plan = [&](const int* kts, int cnt, I6& kt, I6& tps, I6& nsp, int& maxnsp) {
        maxnsp = 1;
        for (int i = 0; i < 6; ++i) {
            const int k = kts[(i < cnt) ? i : (cnt - 1)];
            const int tp = (k + KScap - 1) / KScap;
            kt.v[i] = k; tps.v[i] = tp;
            nsp.v[i] = (k + tp - 1) / tp;
            if (i < cnt && nsp.v[i] > maxnsp) maxnsp = nsp.v[i];
        }
    };

    P3 wcA, bcA, gA, beA, W1A, b1A, W2A, b2A, alA;
    for (int i = 0; i < 3; ++i) {
        wcA.p[i] = wconv[i]; bcA.p[i] = bconv[i];
        gA.p[i] = g[i]; beA.p[i] = be[i]; W1A.p[i] = W1[i]; b1A.p[i] = b1[i];
        W2A.p[i] = W2[i]; b2A.p[i] = b2[i]; alA.p[i] = alpha[i];
    }

    // step-1 operands (3 slices)
    P6 A1; V6 B1;
    for (int i = 0; i < 3; ++i) { A1.p[i] = feat[i]; A1.p[3 + i] = feat[i];
                                  B1.p[i] = WencT[i]; B1.p[3 + i] = WencT[i]; }
    // step-2 operands (6 slices: adj_sp x3 then adj_ft x3; B = febT[z%3])
    P6 A2; V6 B2;
    for (int i = 0; i < 3; ++i) {
        A2.p[i]     = adj_sp[i];
        A2.p[3 + i] = adj_ft[i];
        B2.p[i]     = febT + (size_t)i * NR * 64;
        B2.p[3 + i] = febT + (size_t)i * NR * 64;
    }
    // step-4 operands (3 slices: adj_sp; B = combT)
    P6 A4; V6 B4;
    for (int i = 0; i < 3; ++i) { A4.p[i] = adj_sp[i]; A4.p[3 + i] = adj_sp[i];
                                  B4.p[i] = combT;     B4.p[3 + i] = combT; }

    I6 K1 = {Din[0], Din[1], Din[2], Din[0], Din[1], Din[2]};
    I6 Kp1 = {DinP[0], DinP[1], DinP[2], DinP[0], DinP[1], DinP[2]};
    I6 Kadj; for (int i = 0; i < 6; ++i) Kadj.v[i] = NR;

    const int kt1_[3] = {DinP[0] / 32, DinP[1] / 32, DinP[2] / 32};  // 94,32,16
    const int ktA_[1] = {NR / 32};                                    // 128
    I6 ktF, tpsF, nspF; int mF; plan(kt1_, 3, ktF, tpsF, nspF, mF);
    I6 ktA, tpsA, nspA; int mA; plan(ktA_, 1, ktA, tpsA, nspA, mA);

    I3 nspF3 = {nspF.v[0], nspF.v[1], nspF.v[2]};
    I3 nspA3 = {nspA.v[0], nspA.v[1], nspA.v[2]};

    // 0) weight prep: WencT [64][DinP], WdecT [DinP][64] (bf16, zero-padded)
    {
        P6 s6; U6 d6; I6 R6, C6, Rp6, Cp6;
        int maxtiles = 1;
        for (int i = 0; i < 3; ++i) {
            s6.p[i] = Wenc[i]; d6.p[i] = WencT[i];
            R6.v[i] = Din[i]; C6.v[i] = 64; Rp6.v[i] = DinP[i]; Cp6.v[i] = 64;
            s6.p[3 + i] = Wdec[i]; d6.p[3 + i] = WdecT[i];
            R6.v[3 + i] = 64; C6.v[3 + i] = Din[i]; Rp6.v[3 + i] = 64; Cp6.v[3 + i] = DinP[i];
            const int tls = DinP[i] / 64;
            if (tls > maxtiles) maxtiles = tls;
        }
        prep_t<<<dim3(maxtiles, 6), 256, 0, stream>>>(s6, d6, R6, C6, Rp6, Cp6);
    }

    // 1) fe_i = feat_i @ W_enc_i  -> transposed partials -> febT [64][NR]
    gemm_single<true><<<dim3(64, mF, 3), 256, 0, stream>>>(
        A1, B1, Cpart, K1, Kp1, ktF, tpsF, KScap);
    reduce_many<<<dim3(256, 3), 256, 0, stream>>>(Cpart, febT, nspF3, KScap);

    // 1b) csum_z[c] = sum_r fe_z[r][c]  (for the conv bias term)
    colsum_kernel<<<3, 256, 0, stream>>>(febT, csum);

    // 2) S1_z = adj_sp_z @ fe_z, S2_z = adj_ft_z @ fe_z  (6 slices, 1 launch);
    //    reduce_ced: gc = w0*S1 + w1*S2 + b*csum, fused CED -> emb
    gemm_single<false><<<dim3(64, mA, 6), 256, 0, stream>>>(
        A2, B2, Cpart, Kadj, Kadj, ktA, tpsA, KScap);
    reduce_ced<<<dim3(NR / 4, 3), 256, 0, stream>>>(
        Cpart, wcA, bcA, csum, gA, beA, W1A, b1A, W2A, b2A, alA,
        emb_out, nspA, KScap);

    // 3) fusion MLP -> comb (f32 out) + combT (bf16 B^T scratch)
    fusion_kernel<<<NR / 4, 256, 0, stream>>>(emb_out, Wfc1, bfc1, Wfc2, bfc2,
                                              comb_out, combT);

    // 4) T_i = adj_sp_i @ comb -> Tb [NR][64] bf16
    gemm_single<false><<<dim3(64, mA, 3), 256, 0, stream>>>(
        A4, B4, Cpart, Kadj, Kadj, ktA, tpsA, KScap);
    reduce_many<<<dim3(256, 3), 256, 0, stream>>>(Cpart, Tb, nspA3, KScap);

    // 5) rec_i = T_i @ W_dec_i
    V3 WdTV; I3 Dz3 = {Din[0], Din[1], Din[2]};
    for (int i = 0; i < 3; ++i) WdTV.p[i] = WdecT[i];
    const int NTmax = DinP[0] / 64;
    gemm_rec<<<dim3(64, NTmax, 3), 256, 0, stream>>>(Tb, WdTV, rec_out, Dz3);
}

// Round 9
// 303.863 us; speedup vs baseline: 1.7776x; 1.3198x over previous
//
#include <hip/hip_runtime.h>

#define NR 4096

typedef __attribute__((ext_vector_type(8))) short bf16x8;
typedef __attribute__((ext_vector_type(4))) float f32x4;
typedef __attribute__((ext_vector_type(4))) unsigned short u16x4;

struct P3 { const float* p[3]; };
struct V3 { const void* p[3]; };
struct O3 { float* p[3]; };
struct I3 { int v[3]; };
struct P6 { const float* p[6]; };
struct V6 { const void* p[6]; };
struct U6 { unsigned short* p[6]; };
struct I6 { int v[6]; };

__device__ __forceinline__ unsigned short f2bf(float f) {
    union { float f; unsigned u; } v; v.f = f;
    unsigned r = v.u + 0x7fffu + ((v.u >> 16) & 1u);
    return (unsigned short)(r >> 16);
}
__device__ __forceinline__ float bf2f(unsigned short b) {
    union { unsigned u; float f; } v; v.u = ((unsigned)b) << 16;
    return v.f;
}

// ---------------------------------------------------------------------------
// C[M,64] = A[M,K] @ B[K,64], BK=256, DRAM-BURST staging.
// R8 retro: registers clean but HBM stuck at 1.3 TB/s with byte-invariant
// durations -> the 16x128B-segment load pattern thrashes DRAM row buffers.
// Fix: each A-load wave-instruction reads 1 KB CONTIGUOUS within one row
// (lane l -> bytes l*16 of the row's 1 KB chunk); 16 instrs/thread cover the
// 64x256 f32 tile, all in flight at once (16 KB/wave).
// LDS As[64][256] bf16 (32 KB), chunk-swizzled: 16B chunk c of row r at
// byte r*512 + ((c ^ (r&7))<<4)  -> MFMA b128 reads 2-way (free), staging
// writes <=2-way.  B fragments direct from global (pre-transposed bf16
// B^T[64][Kp], L2-resident; R8-proven path).  4 waves 2x2; 8 ks/stage.
// Split-K partials -> Cpart slot (z*KScap+sp).  CT writes C^T.
// ---------------------------------------------------------------------------
template<bool CT>
__global__ __launch_bounds__(256, 2) void gemm_stream(
    P6 Aa, V6 Ba, float* __restrict__ Cpart,
    I6 Kz, I6 Kpz, I6 ktz, I6 tpsz, const int KScap)
{
    const int z = blockIdx.z;
    const int K = Kz.v[z], Kp = Kpz.v[z], ktiles = ktz.v[z], tps = tpsz.v[z];
    const int mt = blockIdx.x, sp = blockIdx.y;
    const int kt0 = sp * tps;
    int kt1 = kt0 + tps; if (kt1 > ktiles) kt1 = ktiles;
    if (kt0 >= kt1) return;                     // uniform early-exit

    __shared__ unsigned short As[64 * 256];     // 32 KB

    const int t = threadIdx.x;
    const int l = t & 63, w = t >> 6;
    const int lr = l & 15, lk = l >> 4;
    const int wm = (w >> 1) << 5, wn = (w & 1) << 5;

    const float* __restrict__ A = Aa.p[z];
    const unsigned short* __restrict__ Bt = (const unsigned short*)Ba.p[z];

    const unsigned short* BpA = Bt + (size_t)(wn + lr) * Kp + lk * 8;
    const unsigned short* BpB = Bt + (size_t)(wn + 16 + lr) * Kp + lk * 8;

    f32x4 acc00, acc01, acc10, acc11;
    #pragma unroll
    for (int r = 0; r < 4; ++r) { acc00[r] = 0.f; acc01[r] = 0.f; acc10[r] = 0.f; acc11[r] = 0.f; }

    // staging: round j covers row j*4+w (j<8) or 32+j*4+w; lane l -> k l*4
    const float* Sbase = A + ((size_t)(mt * 64 + w)) * K + l * 4;

    for (int kt = kt0; kt < kt1; ++kt) {
        const int kk = kt * 256 + l * 4;        // global k of this lane
        f32x4 v[16];
        #pragma unroll
        for (int j = 0; j < 16; ++j) {          // 16 x 1KB-contiguous loads
            const float* p = Sbase + (size_t)(j * 4) * K + kt * 256;
            if (kk + 3 < K) {
                v[j] = *(const f32x4*)p;
            } else {
                #pragma unroll
                for (int e = 0; e < 4; ++e) v[j][e] = (kk + e < K) ? p[e] : 0.f;
            }
        }
        #pragma unroll
        for (int j = 0; j < 16; ++j) {
            const int row = j * 4 + w;
            u16x4 o;
            #pragma unroll
            for (int e = 0; e < 4; ++e) o[e] = f2bf(v[j][e]);
            *(u16x4*)((char*)As + row * 512 +
                      ((((l >> 1) ^ (row & 7))) << 4) + ((l & 1) << 3)) = o;
        }
        __syncthreads();

        const int rowA0 = wm + lr, rowA1 = wm + 16 + lr;
        const char* pa0 = (const char*)As + rowA0 * 512;
        const char* pa1 = (const char*)As + rowA1 * 512;
        const int sw0 = rowA0 & 7, sw1 = rowA1 & 7;
        #pragma unroll
        for (int ks = 0; ks < 8; ++ks) {
            const int c = ks * 4 + lk;
            const bf16x8 a0 = *(const bf16x8*)(pa0 + ((c ^ sw0) << 4));
            const bf16x8 a1 = *(const bf16x8*)(pa1 + ((c ^ sw1) << 4));
            const bf16x8 b0 = *(const bf16x8*)(BpA + kt * 256 + ks * 32);
            const bf16x8 b1 = *(const bf16x8*)(BpB + kt * 256 + ks * 32);
            acc00 = __builtin_amdgcn_mfma_f32_16x16x32_bf16(a0, b0, acc00, 0, 0, 0);
            acc01 = __builtin_amdgcn_mfma_f32_16x16x32_bf16(a0, b1, acc01, 0, 0, 0);
            acc10 = __builtin_amdgcn_mfma_f32_16x16x32_bf16(a1, b0, acc10, 0, 0, 0);
            acc11 = __builtin_amdgcn_mfma_f32_16x16x32_bf16(a1, b1, acc11, 0, 0, 0);
        }
        __syncthreads();
    }

    float* Cp = Cpart + (size_t)(z * KScap + sp) * (NR * 64);
    if (CT) {
        const int r0 = mt * 64 + wm + lk * 4;
        *(f32x4*)&Cp[(size_t)(wn + lr     ) * NR + r0     ] = acc00;
        *(f32x4*)&Cp[(size_t)(wn + 16 + lr) * NR + r0     ] = acc01;
        *(f32x4*)&Cp[(size_t)(wn + lr     ) * NR + r0 + 16] = acc10;
        *(f32x4*)&Cp[(size_t)(wn + 16 + lr) * NR + r0 + 16] = acc11;
    } else {
        #pragma unroll
        for (int r = 0; r < 4; ++r) {
            const int row = mt * 64 + wm + lk * 4 + r;
            Cp[(size_t)row * 64 + wn + lr     ] = acc00[r];
            Cp[(size_t)row * 64 + wn + 16 + lr] = acc01[r];
            Cp[(size_t)(row + 16) * 64 + wn + lr     ] = acc10[r];
            Cp[(size_t)(row + 16) * 64 + wn + 16 + lr] = acc11[r];
        }
    }
}

// sum per-z split partials -> bf16 (layout-agnostic), z-merged
__global__ __launch_bounds__(256) void reduce_many(
    const float* __restrict__ Cpart, unsigned short* __restrict__ out,
    I3 nsp, const int KScap)
{
    const int z = blockIdx.y;
    const int idx = (blockIdx.x * 256 + threadIdx.x) * 4;
    const float* base = Cpart + (size_t)z * KScap * (NR * 64);
    const int n = nsp.v[z];
    f32x4 s; s[0] = s[1] = s[2] = s[3] = 0.f;
    for (int sp = 0; sp < n; ++sp)
        s += *(const f32x4*)(base + (size_t)sp * (NR * 64) + idx);
    unsigned short* o = out + (size_t)z * (NR * 64);
    #pragma unroll
    for (int e = 0; e < 4; ++e) o[idx + e] = f2bf(s[e]);
}

// column sums of fe (from febT [64][NR]): csum[z][c] = sum_r fe[r][c]
__global__ __launch_bounds__(256) void colsum_kernel(
    const unsigned short* __restrict__ febT, float* __restrict__ csum)
{
    const int z = blockIdx.x;
    const int t = threadIdx.x, w = t >> 6, l = t & 63;
    for (int row = w; row < 64; row += 4) {
        const unsigned short* src = febT + ((size_t)z * 64 + row) * NR;
        float s = 0.f;
        for (int i = l * 8; i < NR; i += 512) {
            const bf16x8 v = *(const bf16x8*)(src + i);
            #pragma unroll
            for (int e = 0; e < 8; ++e) s += bf2f((unsigned short)v[e]);
        }
        #pragma unroll
        for (int off = 32; off >= 1; off >>= 1) s += __shfl_xor(s, off);
        if (l == 0) csum[z * 64 + row] = s;
    }
}

// gc = w0*S1 + w1*S2 + b*csum; emb = gc + alpha*(relu(LN(gc)@W1+b1)@W2+b2)
__global__ __launch_bounds__(256) void reduce_ced(
    const float* __restrict__ Cpart, P3 wca, P3 bca,
    const float* __restrict__ csum, P3 ga, P3 bea, P3 W1a, P3 b1a,
    P3 W2a, P3 b2a, P3 ala, float* __restrict__ emb_out,
    I6 nsp, const int KScap)
{
    __shared__ float ln_s[4][64];
    __shared__ float h_s[4][32];
    const int z = blockIdx.y;
    const int w = threadIdx.x >> 6, l = threadIdx.x & 63;
    const int row = blockIdx.x * 4 + w;
    const float* b1p = Cpart + (size_t)z * KScap * (NR * 64);
    const float* b2p = Cpart + (size_t)(3 + z) * KScap * (NR * 64);
    const int n1 = nsp.v[z], n2 = nsp.v[3 + z];
    float s1 = 0.f, s2 = 0.f;
    for (int sp = 0; sp < n1; ++sp)
        s1 += b1p[(size_t)sp * (NR * 64) + (size_t)row * 64 + l];
    for (int sp = 0; sp < n2; ++sp)
        s2 += b2p[(size_t)sp * (NR * 64) + (size_t)row * 64 + l];
    const float w0 = wca.p[z][0], w1 = wca.p[z][1], bb = bca.p[z][0];
    const float x = w0 * s1 + w1 * s2 + bb * csum[z * 64 + l];

    float s = x, s2v = x * x;
    #pragma unroll
    for (int off = 32; off >= 1; off >>= 1) {
        s   += __shfl_xor(s, off);
        s2v += __shfl_xor(s2v, off);
    }
    const float mu  = s * (1.f / 64.f);
    const float var = s2v * (1.f / 64.f) - mu * mu;
    const float ln = (x - mu) * rsqrtf(var + 1e-5f) * ga.p[z][l] + bea.p[z][l];
    ln_s[w][l] = ln;
    __syncthreads();
    if (l < 32) {
        const float* W1 = W1a.p[z];
        float h = b1a.p[z][l];
        #pragma unroll 8
        for (int k = 0; k < 64; ++k) h += ln_s[w][k] * W1[k * 32 + l];
        h_s[w][l] = fmaxf(h, 0.f);
    }
    __syncthreads();
    const float* W2 = W2a.p[z];
    float e = b2a.p[z][l];
    #pragma unroll 8
    for (int j = 0; j < 32; ++j) e += h_s[w][j] * W2[j * 64 + l];
    emb_out[(size_t)z * (NR * 64) + (size_t)row * 64 + l] = x + ala.p[z][0] * e;
}

// fusion MLP: comb = (cat @ Wfc1 + b1) @ Wfc2 + b2; emits f32 + combT bf16
__global__ __launch_bounds__(256) void fusion_kernel(
    const float* __restrict__ emb_base, const float* __restrict__ Wfc1,
    const float* __restrict__ bfc1, const float* __restrict__ Wfc2,
    const float* __restrict__ bfc2, float* __restrict__ comb,
    unsigned short* __restrict__ combT)
{
    __shared__ float cat_s[4][192];
    __shared__ float h_s[4][64];
    const int w = threadIdx.x >> 6, l = threadIdx.x & 63;
    const int row = blockIdx.x * 4 + w;
    cat_s[w][l]       = emb_base[(size_t)row * 64 + l];
    cat_s[w][64 + l]  = emb_base[(size_t)(NR * 64) + (size_t)row * 64 + l];
    cat_s[w][128 + l] = emb_base[(size_t)(2 * NR * 64) + (size_t)row * 64 + l];
    __syncthreads();
    float h = bfc1[l];
    #pragma unroll 8
    for (int k = 0; k < 192; ++k) h += cat_s[w][k] * Wfc1[k * 64 + l];
    h_s[w][l] = h;
    __syncthreads();
    float c = bfc2[l];
    #pragma unroll 8
    for (int j = 0; j < 64; ++j) c += h_s[w][j] * Wfc2[j * 64 + l];
    comb[(size_t)row * 64 + l] = c;
    combT[(size_t)l * NR + row] = f2bf(c);      // B^T for step-4
}

// generic f32 [R][C] -> bf16 [Cp][Rp] transpose with zero-pad (weights prep)
__global__ __launch_bounds__(256) void prep_t(P6 src, U6 dst, I6 Rv6, I6 Cv6,
                                              I6 Rp6, I6 Cp6)
{
    const int z = blockIdx.y;
    const int Rp = Rp6.v[z], Cp = Cp6.v[z];
    const int rtiles = Rp >> 6, ctiles = Cp >> 6;
    const int tid = blockIdx.x;
    if (tid >= rtiles * ctiles) return;
    const int ci = tid / rtiles, ri = tid % rtiles;
    __shared__ float ld[64][65];
    const int t = threadIdx.x;
    const float* s = src.p[z];
    const int Rv = Rv6.v[z], Cv = Cv6.v[z];
    {
        const int rr = t >> 2;
        const int gr = ri * 64 + rr;
        #pragma unroll
        for (int q = 0; q < 4; ++q) {
            const int cc = (t & 3) * 16 + q * 4;
            const int gc = ci * 64 + cc;
            f32x4 x;
            if (gr < Rv && gc + 3 < Cv) {
                x = *(const f32x4*)(s + (size_t)gr * Cv + gc);
            } else {
                #pragma unroll
                for (int e = 0; e < 4; ++e)
                    x[e] = (gr < Rv && gc + e < Cv) ? s[(size_t)gr * Cv + gc + e] : 0.f;
            }
            #pragma unroll
            for (int e = 0; e < 4; ++e) ld[rr][cc + e] = x[e];
        }
    }
    __syncthreads();
    {
        unsigned short* d = dst.p[z];
        const int cl = t >> 2;
        const int r4 = (t & 3) * 16;
        unsigned short vv[16] __attribute__((aligned(16)));
        #pragma unroll
        for (int e = 0; e < 16; ++e) vv[e] = f2bf(ld[r4 + e][cl]);
        const size_t bpos = (size_t)(ci * 64 + cl) * Rp + ri * 64 + r4;
        *(bf16x8*)&d[bpos]     = *(bf16x8*)&vv[0];
        *(bf16x8*)&d[bpos + 8] = *(bf16x8*)&vv[8];
    }
}

// rec[M,Dz] = Tb[M,64](bf16) @ WdecT_z^T ; B staged from WdecT[Dp][64] bf16.
__global__ __launch_bounds__(256) void gemm_rec(
    const unsigned short* __restrict__ Tbase, V3 WdTa, O3 outa, I3 Dz)
{
    const int z = blockIdx.z;
    const int Nw = Dz.v[z];
    const int mt = blockIdx.x, nt = blockIdx.y;
    if (nt * 64 >= Nw) return;                  // uniform early-exit
    __shared__ unsigned short As[64 * 64];
    __shared__ unsigned short Bs[64 * 64];
    const int t = threadIdx.x;
    const unsigned short* Tb = Tbase + (size_t)z * (NR * 64);
    const unsigned short* Wt = (const unsigned short*)WdTa.p[z];
    float* C = outa.p[z];

    const int sr = t >> 3, sc = t & 7;
    const int l = t & 63, w = t >> 6;
    const int wm = (w >> 1) << 5, wn = (w & 1) << 5;
    const int lr = l & 15, lk = l >> 4;
    const int aw0 = sr * 64 + ((sc ^ (sr & 7)) << 3);

    #pragma unroll
    for (int j = 0; j < 2; ++j) {
        const int m = j * 32 + sr;
        *(bf16x8*)&As[aw0 + j * 2048] = *(const bf16x8*)&Tb[(size_t)(mt * 64 + m) * 64 + sc * 8];
        *(bf16x8*)&Bs[aw0 + j * 2048] = *(const bf16x8*)&Wt[(size_t)(nt * 64 + m) * 64 + sc * 8];
    }
    __syncthreads();

    f32x4 acc[2][2];
    #pragma unroll
    for (int i = 0; i < 2; ++i)
        #pragma unroll
        for (int j = 0; j < 2; ++j)
            #pragma unroll
            for (int r = 0; r < 4; ++r) acc[i][j][r] = 0.f;

    #pragma unroll
    for (int ks = 0; ks < 2; ++ks) {
        bf16x8 af[2], bfv[2];
        #pragma unroll
        for (int i = 0; i < 2; ++i) {
            const int row = wm + (i << 4) + lr;
            af[i]  = *(const bf16x8*)&As[row * 64 + ((((ks << 2) + lk) ^ (row & 7)) << 3)];
            const int col = wn + (i << 4) + lr;
            bfv[i] = *(const bf16x8*)&Bs[col * 64 + ((((ks << 2) + lk) ^ (col & 7)) << 3)];
        }
        #pragma unroll
        for (int i = 0; i < 2; ++i)
            #pragma unroll
            for (int j = 0; j < 2; ++j)
                acc[i][j] = __builtin_amdgcn_mfma_f32_16x16x32_bf16(af[i], bfv[j], acc[i][j], 0, 0, 0);
    }

    #pragma unroll
    for (int i = 0; i < 2; ++i)
        #pragma unroll
        for (int j = 0; j < 2; ++j)
            #pragma unroll
            for (int r = 0; r < 4; ++r) {
                const int row = mt * 64 + wm + (i << 4) + (lk << 2) + r;
                const int col = nt * 64 + wn + (j << 4) + lr;
                if (col < Nw) C[(size_t)row * Nw + col] = acc[i][j][r];
            }
}

extern "C" void kernel_launch(void* const* d_in, const int* in_sizes, int n_in,
                              void* d_out, int out_size, void* d_ws, size_t ws_size,
                              hipStream_t stream)
{
    const int Din[3] = {3000, 1000, 500};
    const int DinP[3] = {3072, 1024, 512};      // padded to 256-multiples (BK)
    const float* feat[3]   = {(const float*)d_in[0], (const float*)d_in[1], (const float*)d_in[2]};
    const float* adj_sp[3] = {(const float*)d_in[3], (const float*)d_in[5], (const float*)d_in[7]};
    const float* adj_ft[3] = {(const float*)d_in[4], (const float*)d_in[6], (const float*)d_in[8]};
    const int base[3] = {9, 20, 31};
    const float *wconv[3], *bconv[3], *Wenc[3], *g[3], *be[3], *W1[3], *b1[3],
                *W2[3], *b2[3], *alpha[3], *Wdec[3];
    for (int i = 0; i < 3; ++i) {
        wconv[i] = (const float*)d_in[base[i] + 0];
        bconv[i] = (const float*)d_in[base[i] + 1];
        Wenc[i]  = (const float*)d_in[base[i] + 2];
        g[i]     = (const float*)d_in[base[i] + 3];
        be[i]    = (const float*)d_in[base[i] + 4];
        W1[i]    = (const float*)d_in[base[i] + 5];
        b1[i]    = (const float*)d_in[base[i] + 6];
        W2[i]    = (const float*)d_in[base[i] + 7];
        b2[i]    = (const float*)d_in[base[i] + 8];
        alpha[i] = (const float*)d_in[base[i] + 9];
        Wdec[i]  = (const float*)d_in[base[i] + 10];
    }
    const float* Wfc1 = (const float*)d_in[42];
    const float* bfc1 = (const float*)d_in[43];
    const float* Wfc2 = (const float*)d_in[44];
    const float* bfc2 = (const float*)d_in[45];

    // workspace: febT[3] | combT | Tb[3] (bf16), WencT[3], WdecT[3], csum, Cpart
    char* wsb = (char*)d_ws;
    const size_t SZ_BF = (size_t)NR * 64 * 2;   // 512 KB
    const size_t SZ_F  = (size_t)NR * 64 * 4;   // 1 MB
    unsigned short* febT  = (unsigned short*)wsb;                    // 3x
    unsigned short* combT = (unsigned short*)(wsb + 3 * SZ_BF);
    unsigned short* Tb    = (unsigned short*)(wsb + 4 * SZ_BF);      // 3x
    size_t off = 7 * SZ_BF;
    unsigned short* WencT[3]; unsigned short* WdecT[3];
    for (int i = 0; i < 3; ++i) { WencT[i] = (unsigned short*)(wsb + off); off += (size_t)DinP[i] * 64 * 2; }
    for (int i = 0; i < 3; ++i) { WdecT[i] = (unsigned short*)(wsb + off); off += (size_t)DinP[i] * 64 * 2; }
    float* csum = (float*)(wsb + ((off + 255) & ~(size_t)255));
    off = ((off + 255) & ~(size_t)255) + 3 * 64 * sizeof(float);
    const size_t cpart_off = ((off + 255) & ~(size_t)255);
    float* Cpart = (float*)(wsb + cpart_off);

    int KScap = (int)((ws_size - cpart_off) / (6 * SZ_F));
    if (KScap > 4) KScap = 4;
    if (KScap < 1) KScap = 1;

    float* out = (float*)d_out;
    float* emb_out  = out;
    float* comb_out = out + 3 * (size_t)NR * 64;
    O3 rec_out;
    rec_out.p[0] = out + 4 * (size_t)NR * 64;
    rec_out.p[1] = rec_out.p[0] + (size_t)NR * Din[0];
    rec_out.p[2] = rec_out.p[1] + (size_t)NR * Din[1];

    auto plan = [&](const int* kts, int cnt, I6& kt, I6& tps, I6& nsp, int& maxnsp) {
        maxnsp = 1;
        for (int i = 0; i < 6; ++i) {
            const int k = kts[(i < cnt) ? i : (cnt - 1)];
            const int tp = (k + KScap - 1) / KScap;
            kt.v[i] = k; tps.v[i] = tp;
            nsp.v[i] = (k + tp - 1) / tp;
            if (i < cnt && nsp.v[i] > maxnsp) maxnsp = nsp.v[i];
        }
    };

    P3 wcA, bcA, gA, beA, W1A, b1A, W2A, b2A, alA;
    for (int i = 0; i < 3; ++i) {
        wcA.p[i] = wconv[i]; bcA.p[i] = bconv[i];
        gA.p[i] = g[i]; beA.p[i] = be[i]; W1A.p[i] = W1[i]; b1A.p[i] = b1[i];
        W2A.p[i] = W2[i]; b2A.p[i] = b2[i]; alA.p[i] = alpha[i];
    }

    // step-1 (3 slices): feat @ WencT
    P6 A1; V6 B1;
    for (int i = 0; i < 3; ++i) { A1.p[i] = feat[i]; A1.p[3 + i] = feat[i];
                                  B1.p[i] = WencT[i]; B1.p[3 + i] = WencT[i]; }
    // step-2 (6 slices): adj_sp x3 then adj_ft x3; B = febT[z%3]
    P6 A2; V6 B2;
    for (int i = 0; i < 3; ++i) {
        A2.p[i]     = adj_sp[i];
        A2.p[3 + i] = adj_ft[i];
        B2.p[i]     = febT + (size_t)i * NR * 64;
        B2.p[3 + i] = febT + (size_t)i * NR * 64;
    }
    // step-4 (3 slices): adj_sp; B = combT
    P6 A4; V6 B4;
    for (int i = 0; i < 3; ++i) { A4.p[i] = adj_sp[i]; A4.p[3 + i] = adj_sp[i];
                                  B4.p[i] = combT;     B4.p[3 + i] = combT; }

    I6 K1 = {Din[0], Din[1], Din[2], Din[0], Din[1], Din[2]};
    I6 Kp1 = {DinP[0], DinP[1], DinP[2], DinP[0], DinP[1], DinP[2]};
    I6 Kadj; for (int i = 0; i < 6; ++i) Kadj.v[i] = NR;

    // BK=256 tiles
    const int kt1_[3] = {DinP[0] / 256, DinP[1] / 256, DinP[2] / 256};  // 12,4,2
    const int ktA_[1] = {NR / 256};                                      // 16
    I6 ktF, tpsF, nspF; int mF; plan(kt1_, 3, ktF, tpsF, nspF, mF);
    I6 ktA, tpsA, nspA; int mA; plan(ktA_, 1, ktA, tpsA, nspA, mA);

    I3 nspF3 = {nspF.v[0], nspF.v[1], nspF.v[2]};
    I3 nspA3 = {nspA.v[0], nspA.v[1], nspA.v[2]};

    // 0) weight prep: WencT [64][DinP], WdecT [DinP][64] (bf16, zero-padded)
    {
        P6 s6; U6 d6; I6 R6, C6, Rp6, Cp6;
        int maxtiles = 1;
        for (int i = 0; i < 3; ++i) {
            s6.p[i] = Wenc[i]; d6.p[i] = WencT[i];
            R6.v[i] = Din[i]; C6.v[i] = 64; Rp6.v[i] = DinP[i]; Cp6.v[i] = 64;
            s6.p[3 + i] = Wdec[i]; d6.p[3 + i] = WdecT[i];
            R6.v[3 + i] = 64; C6.v[3 + i] = Din[i]; Rp6.v[3 + i] = 64; Cp6.v[3 + i] = DinP[i];
            const int tls = DinP[i] / 64;
            if (tls > maxtiles) maxtiles = tls;
        }
        prep_t<<<dim3(maxtiles, 6), 256, 0, stream>>>(s6, d6, R6, C6, Rp6, Cp6);
    }

    // 1) fe_i = feat_i @ W_enc_i  -> transposed partials -> febT [64][NR]
    gemm_stream<true><<<dim3(64, mF, 3), 256, 0, stream>>>(
        A1, B1, Cpart, K1, Kp1, ktF, tpsF, KScap);
    reduce_many<<<dim3(256, 3), 256, 0, stream>>>(Cpart, febT, nspF3, KScap);

    // 1b) csum_z[c] = sum_r fe_z[r][c]  (conv bias term)
    colsum_kernel<<<3, 256, 0, stream>>>(febT, csum);

    // 2) S1_z = adj_sp_z @ fe_z, S2_z = adj_ft_z @ fe_z  (6 slices);
    //    reduce_ced: gc = w0*S1 + w1*S2 + b*csum, fused CED -> emb
    gemm_stream<false><<<dim3(64, mA, 6), 256, 0, stream>>>(
        A2, B2, Cpart, Kadj, Kadj, ktA, tpsA, KScap);
    reduce_ced<<<dim3(NR / 4, 3), 256, 0, stream>>>(
        Cpart, wcA, bcA, csum, gA, beA, W1A, b1A, W2A, b2A, alA,
        emb_out, nspA, KScap);

    // 3) fusion MLP -> comb (f32 out) + combT (bf16 B^T scratch)
    fusion_kernel<<<NR / 4, 256, 0, stream>>>(emb_out, Wfc1, bfc1, Wfc2, bfc2,
                                              comb_out, combT);

    // 4) T_i = adj_sp_i @ comb -> Tb [NR][64] bf16
    gemm_stream<false><<<dim3(64, mA, 3), 256, 0, stream>>>(
        A4, B4, Cpart, Kadj, Kadj, ktA, tpsA, KScap);
    reduce_many<<<dim3(256, 3), 256, 0, stream>>>(Cpart, Tb, nspA3, KScap);

    // 5) rec_i = T_i @ W_dec_i
    V3 WdTV; I3 Dz3 = {Din[0], Din[1], Din[2]};
    for (int i = 0; i < 3; ++i) WdTV.p[i] = WdecT[i];
    const int NTmax = DinP[0] / 64;
    gemm_rec<<<dim3(64, NTmax, 3), 256, 0, stream>>>(Tb, WdTV, rec_out, Dz3);
}

// Round 10
// 302.260 us; speedup vs baseline: 1.7870x; 1.0053x over previous
//
#include <hip/hip_runtime.h>

#define NR 4096

typedef __attribute__((ext_vector_type(8))) short bf16x8;
typedef __attribute__((ext_vector_type(4))) float f32x4;
typedef __attribute__((ext_vector_type(4))) unsigned short u16x4;

struct P3 { const float* p[3]; };
struct V3 { const void* p[3]; };
struct O3 { float* p[3]; };
struct I3 { int v[3]; };
struct P6 { const float* p[6]; };
struct V6 { const void* p[6]; };
struct U6 { unsigned short* p[6]; };
struct I6 { int v[6]; };

__device__ __forceinline__ unsigned short f2bf(float f) {
    union { float f; unsigned u; } v; v.f = f;
    unsigned r = v.u + 0x7fffu + ((v.u >> 16) & 1u);
    return (unsigned short)(r >> 16);
}
__device__ __forceinline__ float bf2f(unsigned short b) {
    union { unsigned u; float f; } v; v.u = ((unsigned)b) << 16;
    return v.f;
}

// ---------------------------------------------------------------------------
// C[M,64] = A[M,K] @ B[K,64], BK=128, residency-maximized.
// R9 diagnostic: step-2 (1536 blocks) delivered 2x the throughput of step-4
// (768 blocks) at identical wall time -> still LATENCY-bound; concurrency is
// the lever.  This round: LDS 32->16 KB (8 blocks/CU resident, the 32-wave
// cap), KS up to 8 (grid 2x), VGPR ~60 so occupancy is LDS-limited only.
// Staging: 8 wave-instrs, each 1 KB = 2 rows (512 B contiguous per
// half-wave); convert f32->bf16 in-register; LDS As[64][128] bf16 (16 KB),
// 16B chunk c of row r at byte r*256 + ((c ^ (r&15))<<4) -> fragment reads
// 2-way (free), staging writes ~4-way (tiny fraction of cycles).
// B fragments direct from global (pre-transposed bf16 B^T[64][Kp], L2-hot).
// 4 waves 2x2; 4 ks-steps per tile.  Split-K partials -> Cpart slot
// (z*KScap+sp), deterministic.  CT writes C^T.
// ---------------------------------------------------------------------------
template<bool CT>
__global__ __launch_bounds__(256, 2) void gemm_stream(
    P6 Aa, V6 Ba, float* __restrict__ Cpart,
    I6 Kz, I6 Kpz, I6 ktz, I6 tpsz, const int KScap)
{
    const int z = blockIdx.z;
    const int K = Kz.v[z], Kp = Kpz.v[z], ktiles = ktz.v[z], tps = tpsz.v[z];
    const int mt = blockIdx.x, sp = blockIdx.y;
    const int kt0 = sp * tps;
    int kt1 = kt0 + tps; if (kt1 > ktiles) kt1 = ktiles;
    if (kt0 >= kt1) return;                     // uniform early-exit

    __shared__ unsigned short As[64 * 128];     // 16 KB

    const int t = threadIdx.x;
    const int l = t & 63, w = t >> 6;
    const int lr = l & 15, lk = l >> 4;
    const int wm = (w >> 1) << 5, wn = (w & 1) << 5;

    const float* __restrict__ A = Aa.p[z];
    const unsigned short* __restrict__ Bt = (const unsigned short*)Ba.p[z];

    const unsigned short* BpA = Bt + (size_t)(wn + lr) * Kp + lk * 8;
    const unsigned short* BpB = Bt + (size_t)(wn + 16 + lr) * Kp + lk * 8;

    f32x4 acc00, acc01, acc10, acc11;
    #pragma unroll
    for (int r = 0; r < 4; ++r) { acc00[r] = 0.f; acc01[r] = 0.f; acc10[r] = 0.f; acc11[r] = 0.f; }

    // staging: wave w covers rows [w*16, w*16+16); instr j -> rows w*16+2j
    // and w*16+2j+1; lane l -> row +(l>>5), col floats (l&31)*4
    const int srow0 = w * 16 + (l >> 5);        // + 2j at use
    const int scol  = (l & 31) * 4;
    const float* Sbase = A + (size_t)(mt * 64 + srow0) * K + scol;

    // LDS write address for this lane (row varies with j)
    const int wc  = (l & 31) >> 1;              // 16B chunk within row
    const int whb = (l & 1) << 3;               // 8B half of the chunk

    for (int kt = kt0; kt < kt1; ++kt) {
        const int kk = kt * 128 + scol;         // global k of this lane
        f32x4 v[8];
        #pragma unroll
        for (int j = 0; j < 8; ++j) {           // 8 x 1KB wave-loads
            const float* p = Sbase + (size_t)(2 * j) * K + kt * 128;
            if (kk + 3 < K) {
                v[j] = *(const f32x4*)p;
            } else {
                #pragma unroll
                for (int e = 0; e < 4; ++e) v[j][e] = (kk + e < K) ? p[e] : 0.f;
            }
        }
        #pragma unroll
        for (int j = 0; j < 8; ++j) {
            const int row = w * 16 + 2 * j + (l >> 5);
            u16x4 o;
            #pragma unroll
            for (int e = 0; e < 4; ++e) o[e] = f2bf(v[j][e]);
            *(u16x4*)((char*)As + row * 256 + ((wc ^ (row & 15)) << 4) + whb) = o;
        }
        __syncthreads();

        const int rowA0 = wm + lr, rowA1 = wm + 16 + lr;
        const char* pa0 = (const char*)As + rowA0 * 256;
        const char* pa1 = (const char*)As + rowA1 * 256;
        const int sw0 = rowA0 & 15, sw1 = rowA1 & 15;
        #pragma unroll
        for (int ks = 0; ks < 4; ++ks) {
            const int c = ks * 4 + lk;
            const bf16x8 a0 = *(const bf16x8*)(pa0 + ((c ^ sw0) << 4));
            const bf16x8 a1 = *(const bf16x8*)(pa1 + ((c ^ sw1) << 4));
            const bf16x8 b0 = *(const bf16x8*)(BpA + kt * 128 + ks * 32);
            const bf16x8 b1 = *(const bf16x8*)(BpB + kt * 128 + ks * 32);
            acc00 = __builtin_amdgcn_mfma_f32_16x16x32_bf16(a0, b0, acc00, 0, 0, 0);
            acc01 = __builtin_amdgcn_mfma_f32_16x16x32_bf16(a0, b1, acc01, 0, 0, 0);
            acc10 = __builtin_amdgcn_mfma_f32_16x16x32_bf16(a1, b0, acc10, 0, 0, 0);
            acc11 = __builtin_amdgcn_mfma_f32_16x16x32_bf16(a1, b1, acc11, 0, 0, 0);
        }
        __syncthreads();
    }

    float* Cp = Cpart + (size_t)(z * KScap + sp) * (NR * 64);
    if (CT) {
        const int r0 = mt * 64 + wm + lk * 4;
        *(f32x4*)&Cp[(size_t)(wn + lr     ) * NR + r0     ] = acc00;
        *(f32x4*)&Cp[(size_t)(wn + 16 + lr) * NR + r0     ] = acc01;
        *(f32x4*)&Cp[(size_t)(wn + lr     ) * NR + r0 + 16] = acc10;
        *(f32x4*)&Cp[(size_t)(wn + 16 + lr) * NR + r0 + 16] = acc11;
    } else {
        #pragma unroll
        for (int r = 0; r < 4; ++r) {
            const int row = mt * 64 + wm + lk * 4 + r;
            Cp[(size_t)row * 64 + wn + lr     ] = acc00[r];
            Cp[(size_t)row * 64 + wn + 16 + lr] = acc01[r];
            Cp[(size_t)(row + 16) * 64 + wn + lr     ] = acc10[r];
            Cp[(size_t)(row + 16) * 64 + wn + 16 + lr] = acc11[r];
        }
    }
}

// sum per-z split partials -> bf16 (layout-agnostic), z-merged
__global__ __launch_bounds__(256) void reduce_many(
    const float* __restrict__ Cpart, unsigned short* __restrict__ out,
    I3 nsp, const int KScap)
{
    const int z = blockIdx.y;
    const int idx = (blockIdx.x * 256 + threadIdx.x) * 4;
    const float* base = Cpart + (size_t)z * KScap * (NR * 64);
    const int n = nsp.v[z];
    f32x4 s; s[0] = s[1] = s[2] = s[3] = 0.f;
    for (int sp = 0; sp < n; ++sp)
        s += *(const f32x4*)(base + (size_t)sp * (NR * 64) + idx);
    unsigned short* o = out + (size_t)z * (NR * 64);
    #pragma unroll
    for (int e = 0; e < 4; ++e) o[idx + e] = f2bf(s[e]);
}

// column sums of fe (from febT [64][NR]): csum[z][c] = sum_r fe[r][c]
__global__ __launch_bounds__(256) void colsum_kernel(
    const unsigned short* __restrict__ febT, float* __restrict__ csum)
{
    const int z = blockIdx.x;
    const int t = threadIdx.x, w = t >> 6, l = t & 63;
    for (int row = w; row < 64; row += 4) {
        const unsigned short* src = febT + ((size_t)z * 64 + row) * NR;
        float s = 0.f;
        for (int i = l * 8; i < NR; i += 512) {
            const bf16x8 v = *(const bf16x8*)(src + i);
            #pragma unroll
            for (int e = 0; e < 8; ++e) s += bf2f((unsigned short)v[e]);
        }
        #pragma unroll
        for (int off = 32; off >= 1; off >>= 1) s += __shfl_xor(s, off);
        if (l == 0) csum[z * 64 + row] = s;
    }
}

// gc = w0*S1 + w1*S2 + b*csum; emb = gc + alpha*(relu(LN(gc)@W1+b1)@W2+b2)
__global__ __launch_bounds__(256) void reduce_ced(
    const float* __restrict__ Cpart, P3 wca, P3 bca,
    const float* __restrict__ csum, P3 ga, P3 bea, P3 W1a, P3 b1a,
    P3 W2a, P3 b2a, P3 ala, float* __restrict__ emb_out,
    I6 nsp, const int KScap)
{
    __shared__ float ln_s[4][64];
    __shared__ float h_s[4][32];
    const int z = blockIdx.y;
    const int w = threadIdx.x >> 6, l = threadIdx.x & 63;
    const int row = blockIdx.x * 4 + w;
    const float* b1p = Cpart + (size_t)z * KScap * (NR * 64);
    const float* b2p = Cpart + (size_t)(3 + z) * KScap * (NR * 64);
    const int n1 = nsp.v[z], n2 = nsp.v[3 + z];
    float s1 = 0.f, s2 = 0.f;
    for (int sp = 0; sp < n1; ++sp)
        s1 += b1p[(size_t)sp * (NR * 64) + (size_t)row * 64 + l];
    for (int sp = 0; sp < n2; ++sp)
        s2 += b2p[(size_t)sp * (NR * 64) + (size_t)row * 64 + l];
    const float w0 = wca.p[z][0], w1 = wca.p[z][1], bb = bca.p[z][0];
    const float x = w0 * s1 + w1 * s2 + bb * csum[z * 64 + l];

    float s = x, s2v = x * x;
    #pragma unroll
    for (int off = 32; off >= 1; off >>= 1) {
        s   += __shfl_xor(s, off);
        s2v += __shfl_xor(s2v, off);
    }
    const float mu  = s * (1.f / 64.f);
    const float var = s2v * (1.f / 64.f) - mu * mu;
    const float ln = (x - mu) * rsqrtf(var + 1e-5f) * ga.p[z][l] + bea.p[z][l];
    ln_s[w][l] = ln;
    __syncthreads();
    if (l < 32) {
        const float* W1 = W1a.p[z];
        float h = b1a.p[z][l];
        #pragma unroll 8
        for (int k = 0; k < 64; ++k) h += ln_s[w][k] * W1[k * 32 + l];
        h_s[w][l] = fmaxf(h, 0.f);
    }
    __syncthreads();
    const float* W2 = W2a.p[z];
    float e = b2a.p[z][l];
    #pragma unroll 8
    for (int j = 0; j < 32; ++j) e += h_s[w][j] * W2[j * 64 + l];
    emb_out[(size_t)z * (NR * 64) + (size_t)row * 64 + l] = x + ala.p[z][0] * e;
}

// fusion MLP: comb = (cat @ Wfc1 + b1) @ Wfc2 + b2; emits f32 + combT bf16
__global__ __launch_bounds__(256) void fusion_kernel(
    const float* __restrict__ emb_base, const float* __restrict__ Wfc1,
    const float* __restrict__ bfc1, const float* __restrict__ Wfc2,
    const float* __restrict__ bfc2, float* __restrict__ comb,
    unsigned short* __restrict__ combT)
{
    __shared__ float cat_s[4][192];
    __shared__ float h_s[4][64];
    const int w = threadIdx.x >> 6, l = threadIdx.x & 63;
    const int row = blockIdx.x * 4 + w;
    cat_s[w][l]       = emb_base[(size_t)row * 64 + l];
    cat_s[w][64 + l]  = emb_base[(size_t)(NR * 64) + (size_t)row * 64 + l];
    cat_s[w][128 + l] = emb_base[(size_t)(2 * NR * 64) + (size_t)row * 64 + l];
    __syncthreads();
    float h = bfc1[l];
    #pragma unroll 8
    for (int k = 0; k < 192; ++k) h += cat_s[w][k] * Wfc1[k * 64 + l];
    h_s[w][l] = h;
    __syncthreads();
    float c = bfc2[l];
    #pragma unroll 8
    for (int j = 0; j < 64; ++j) c += h_s[w][j] * Wfc2[j * 64 + l];
    comb[(size_t)row * 64 + l] = c;
    combT[(size_t)l * NR + row] = f2bf(c);      // B^T for step-4
}

// generic f32 [R][C] -> bf16 [Cp][Rp] transpose with zero-pad (weights prep)
__global__ __launch_bounds__(256) void prep_t(P6 src, U6 dst, I6 Rv6, I6 Cv6,
                                              I6 Rp6, I6 Cp6)
{
    const int z = blockIdx.y;
    const int Rp = Rp6.v[z], Cp = Cp6.v[z];
    const int rtiles = Rp >> 6, ctiles = Cp >> 6;
    const int tid = blockIdx.x;
    if (tid >= rtiles * ctiles) return;
    const int ci = tid / rtiles, ri = tid % rtiles;
    __shared__ float ld[64][65];
    const int t = threadIdx.x;
    const float* s = src.p[z];
    const int Rv = Rv6.v[z], Cv = Cv6.v[z];
    {
        const int rr = t >> 2;
        const int gr = ri * 64 + rr;
        #pragma unroll
        for (int q = 0; q < 4; ++q) {
            const int cc = (t & 3) * 16 + q * 4;
            const int gc = ci * 64 + cc;
            f32x4 x;
            if (gr < Rv && gc + 3 < Cv) {
                x = *(const f32x4*)(s + (size_t)gr * Cv + gc);
            } else {
                #pragma unroll
                for (int e = 0; e < 4; ++e)
                    x[e] = (gr < Rv && gc + e < Cv) ? s[(size_t)gr * Cv + gc + e] : 0.f;
            }
            #pragma unroll
            for (int e = 0; e < 4; ++e) ld[rr][cc + e] = x[e];
        }
    }
    __syncthreads();
    {
        unsigned short* d = dst.p[z];
        const int cl = t >> 2;
        const int r4 = (t & 3) * 16;
        unsigned short vv[16] __attribute__((aligned(16)));
        #pragma unroll
        for (int e = 0; e < 16; ++e) vv[e] = f2bf(ld[r4 + e][cl]);
        const size_t bpos = (size_t)(ci * 64 + cl) * Rp + ri * 64 + r4;
        *(bf16x8*)&d[bpos]     = *(bf16x8*)&vv[0];
        *(bf16x8*)&d[bpos + 8] = *(bf16x8*)&vv[8];
    }
}

// rec[M,Dz] = Tb[M,64](bf16) @ WdecT_z^T ; B staged from WdecT[Dp][64] bf16.
__global__ __launch_bounds__(256) void gemm_rec(
    const unsigned short* __restrict__ Tbase, V3 WdTa, O3 outa, I3 Dz)
{
    const int z = blockIdx.z;
    const int Nw = Dz.v[z];
    const int mt = blockIdx.x, nt = blockIdx.y;
    if (nt * 64 >= Nw) return;                  // uniform early-exit
    __shared__ unsigned short As[64 * 64];
    __shared__ unsigned short Bs[64 * 64];
    const int t = threadIdx.x;
    const unsigned short* Tb = Tbase + (size_t)z * (NR * 64);
    const unsigned short* Wt = (const unsigned short*)WdTa.p[z];
    float* C = outa.p[z];

    const int sr = t >> 3, sc = t & 7;
    const int l = t & 63, w = t >> 6;
    const int wm = (w >> 1) << 5, wn = (w & 1) << 5;
    const int lr = l & 15, lk = l >> 4;
    const int aw0 = sr * 64 + ((sc ^ (sr & 7)) << 3);

    #pragma unroll
    for (int j = 0; j < 2; ++j) {
        const int m = j * 32 + sr;
        *(bf16x8*)&As[aw0 + j * 2048] = *(const bf16x8*)&Tb[(size_t)(mt * 64 + m) * 64 + sc * 8];
        *(bf16x8*)&Bs[aw0 + j * 2048] = *(const bf16x8*)&Wt[(size_t)(nt * 64 + m) * 64 + sc * 8];
    }
    __syncthreads();

    f32x4 acc[2][2];
    #pragma unroll
    for (int i = 0; i < 2; ++i)
        #pragma unroll
        for (int j = 0; j < 2; ++j)
            #pragma unroll
            for (int r = 0; r < 4; ++r) acc[i][j][r] = 0.f;

    #pragma unroll
    for (int ks = 0; ks < 2; ++ks) {
        bf16x8 af[2], bfv[2];
        #pragma unroll
        for (int i = 0; i < 2; ++i) {
            const int row = wm + (i << 4) + lr;
            af[i]  = *(const bf16x8*)&As[row * 64 + ((((ks << 2) + lk) ^ (row & 7)) << 3)];
            const int col = wn + (i << 4) + lr;
            bfv[i] = *(const bf16x8*)&Bs[col * 64 + ((((ks << 2) + lk) ^ (col & 7)) << 3)];
        }
        #pragma unroll
        for (int i = 0; i < 2; ++i)
            #pragma unroll
            for (int j = 0; j < 2; ++j)
                acc[i][j] = __builtin_amdgcn_mfma_f32_16x16x32_bf16(af[i], bfv[j], acc[i][j], 0, 0, 0);
    }

    #pragma unroll
    for (int i = 0; i < 2; ++i)
        #pragma unroll
        for (int j = 0; j < 2; ++j)
            #pragma unroll
            for (int r = 0; r < 4; ++r) {
                const int row = mt * 64 + wm + (i << 4) + (lk << 2) + r;
                const int col = nt * 64 + wn + (j << 4) + lr;
                if (col < Nw) C[(size_t)row * Nw + col] = acc[i][j][r];
            }
}

extern "C" void kernel_launch(void* const* d_in, const int* in_sizes, int n_in,
                              void* d_out, int out_size, void* d_ws, size_t ws_size,
                              hipStream_t stream)
{
    const int Din[3] = {3000, 1000, 500};
    const int DinP[3] = {3072, 1024, 512};      // padded to 128-multiples (BK)
    const float* feat[3]   = {(const float*)d_in[0], (const float*)d_in[1], (const float*)d_in[2]};
    const float* adj_sp[3] = {(const float*)d_in[3], (const float*)d_in[5], (const float*)d_in[7]};
    const float* adj_ft[3] = {(const float*)d_in[4], (const float*)d_in[6], (const float*)d_in[8]};
    const int base[3] = {9, 20, 31};
    const float *wconv[3], *bconv[3], *Wenc[3], *g[3], *be[3], *W1[3], *b1[3],
                *W2[3], *b2[3], *alpha[3], *Wdec[3];
    for (int i = 0; i < 3; ++i) {
        wconv[i] = (const float*)d_in[base[i] + 0];
        bconv[i] = (const float*)d_in[base[i] + 1];
        Wenc[i]  = (const float*)d_in[base[i] + 2];
        g[i]     = (const float*)d_in[base[i] + 3];
        be[i]    = (const float*)d_in[base[i] + 4];
        W1[i]    = (const float*)d_in[base[i] + 5];
        b1[i]    = (const float*)d_in[base[i] + 6];
        W2[i]    = (const float*)d_in[base[i] + 7];
        b2[i]    = (const float*)d_in[base[i] + 8];
        alpha[i] = (const float*)d_in[base[i] + 9];
        Wdec[i]  = (const float*)d_in[base[i] + 10];
    }
    const float* Wfc1 = (const float*)d_in[42];
    const float* bfc1 = (const float*)d_in[43];
    const float* Wfc2 = (const float*)d_in[44];
    const float* bfc2 = (const float*)d_in[45];

    // workspace: febT[3] | combT | Tb[3] (bf16), WencT[3], WdecT[3], csum, Cpart
    char* wsb = (char*)d_ws;
    const size_t SZ_BF = (size_t)NR * 64 * 2;   // 512 KB
    const size_t SZ_F  = (size_t)NR * 64 * 4;   // 1 MB
    unsigned short* febT  = (unsigned short*)wsb;                    // 3x
    unsigned short* combT = (unsigned short*)(wsb + 3 * SZ_BF);
    unsigned short* Tb    = (unsigned short*)(wsb + 4 * SZ_BF);      // 3x
    size_t off = 7 * SZ_BF;
    unsigned short* WencT[3]; unsigned short* WdecT[3];
    for (int i = 0; i < 3; ++i) { WencT[i] = (unsigned short*)(wsb + off); off += (size_t)DinP[i] * 64 * 2; }
    for (int i = 0; i < 3; ++i) { WdecT[i] = (unsigned short*)(wsb + off); off += (size_t)DinP[i] * 64 * 2; }
    float* csum = (float*)(wsb + ((off + 255) & ~(size_t)255));
    off = ((off + 255) & ~(size_t)255) + 3 * 64 * sizeof(float);
    const size_t cpart_off = ((off + 255) & ~(size_t)255);
    float* Cpart = (float*)(wsb + cpart_off);

    int KScap = (int)((ws_size - cpart_off) / (6 * SZ_F));
    if (KScap > 8) KScap = 8;
    if (KScap < 1) KScap = 1;

    float* out = (float*)d_out;
    float* emb_out  = out;
    float* comb_out = out + 3 * (size_t)NR * 64;
    O3 rec_out;
    rec_out.p[0] = out + 4 * (size_t)NR * 64;
    rec_out.p[1] = rec_out.p[0] + (size_t)NR * Din[0];
    rec_out.p[2] = rec_out.p[1] + (size_t)NR * Din[1];

    auto plan = [&](const int* kts, int cnt, I6& kt, I6& tps, I6& nsp, int& maxnsp) {
        maxnsp = 1;
        for (int i = 0; i < 6; ++i) {
            const int k = kts[(i < cnt) ? i : (cnt - 1)];
            const int tp = (k + KScap - 1) / KScap;
            kt.v[i] = k; tps.v[i] = tp;
            nsp.v[i] = (k + tp - 1) / tp;
            if (i < cnt && nsp.v[i] > maxnsp) maxnsp = nsp.v[i];
        }
    };

    P3 wcA, bcA, gA, beA, W1A, b1A, W2A, b2A, alA;
    for (int i = 0; i < 3; ++i) {
        wcA.p[i] = wconv[i]; bcA.p[i] = bconv[i];
        gA.p[i] = g[i]; beA.p[i] = be[i]; W1A.p[i] = W1[i]; b1A.p[i] = b1[i];
        W2A.p[i] = W2[i]; b2A.p[i] = b2[i]; alA.p[i] = alpha[i];
    }

    // step-1 (3 slices): feat @ WencT
    P6 A1; V6 B1;
    for (int i = 0; i < 3; ++i) { A1.p[i] = feat[i]; A1.p[3 + i] = feat[i];
                                  B1.p[i] = WencT[i]; B1.p[3 + i] = WencT[i]; }
    // step-2 (6 slices): adj_sp x3 then adj_ft x3; B = febT[z%3]
    P6 A2; V6 B2;
    for (int i = 0; i < 3; ++i) {
        A2.p[i]     = adj_sp[i];
        A2.p[3 + i] = adj_ft[i];
        B2.p[i]     = febT + (size_t)i * NR * 64;
        B2.p[3 + i] = febT + (size_t)i * NR * 64;
    }
    // step-4 (3 slices): adj_sp; B = combT
    P6 A4; V6 B4;
    for (int i = 0; i < 3; ++i) { A4.p[i] = adj_sp[i]; A4.p[3 + i] = adj_sp[i];
                                  B4.p[i] = combT;     B4.p[3 + i] = combT; }

    I6 K1 = {Din[0], Din[1], Din[2], Din[0], Din[1], Din[2]};
    I6 Kp1 = {DinP[0], DinP[1], DinP[2], DinP[0], DinP[1], DinP[2]};
    I6 Kadj; for (int i = 0; i < 6; ++i) Kadj.v[i] = NR;

    // BK=128 tiles
    const int kt1_[3] = {DinP[0] / 128, DinP[1] / 128, DinP[2] / 128};  // 24,8,4
    const int ktA_[1] = {NR / 128};                                      // 32
    I6 ktF, tpsF, nspF; int mF; plan(kt1_, 3, ktF, tpsF, nspF, mF);
    I6 ktA, tpsA, nspA; int mA; plan(ktA_, 1, ktA, tpsA, nspA, mA);

    I3 nspF3 = {nspF.v[0], nspF.v[1], nspF.v[2]};
    I3 nspA3 = {nspA.v[0], nspA.v[1], nspA.v[2]};

    // 0) weight prep: WencT [64][DinP], WdecT [DinP][64] (bf16, zero-padded)
    {
        P6 s6; U6 d6; I6 R6, C6, Rp6, Cp6;
        int maxtiles = 1;
        for (int i = 0; i < 3; ++i) {
            s6.p[i] = Wenc[i]; d6.p[i] = WencT[i];
            R6.v[i] = Din[i]; C6.v[i] = 64; Rp6.v[i] = DinP[i]; Cp6.v[i] = 64;
            s6.p[3 + i] = Wdec[i]; d6.p[3 + i] = WdecT[i];
            R6.v[3 + i] = 64; C6.v[3 + i] = Din[i]; Rp6.v[3 + i] = 64; Cp6.v[3 + i] = DinP[i];
            const int tls = DinP[i] / 64;
            if (tls > maxtiles) maxtiles = tls;
        }
        prep_t<<<dim3(maxtiles, 6), 256, 0, stream>>>(s6, d6, R6, C6, Rp6, Cp6);
    }

    // 1) fe_i = feat_i @ W_enc_i  -> transposed partials -> febT [64][NR]
    gemm_stream<true><<<dim3(64, mF, 3), 256, 0, stream>>>(
        A1, B1, Cpart, K1, Kp1, ktF, tpsF, KScap);
    reduce_many<<<dim3(256, 3), 256, 0, stream>>>(Cpart, febT, nspF3, KScap);

    // 1b) csum_z[c] = sum_r fe_z[r][c]  (conv bias term)
    colsum_kernel<<<3, 256, 0, stream>>>(febT, csum);

    // 2) S1_z = adj_sp_z @ fe_z, S2_z = adj_ft_z @ fe_z  (6 slices);
    //    reduce_ced: gc = w0*S1 + w1*S2 + b*csum, fused CED -> emb
    gemm_stream<false><<<dim3(64, mA, 6), 256, 0, stream>>>(
        A2, B2, Cpart, Kadj, Kadj, ktA, tpsA, KScap);
    reduce_ced<<<dim3(NR / 4, 3), 256, 0, stream>>>(
        Cpart, wcA, bcA, csum, gA, beA, W1A, b1A, W2A, b2A, alA,
        emb_out, nspA, KScap);

    // 3) fusion MLP -> comb (f32 out) + combT (bf16 B^T scratch)
    fusion_kernel<<<NR / 4, 256, 0, stream>>>(emb_out, Wfc1, bfc1, Wfc2, bfc2,
                                              comb_out, combT);

    // 4) T_i = adj_sp_i @ comb -> Tb [NR][64] bf16
    gemm_stream<false><<<dim3(64, mA, 3), 256, 0, stream>>>(
        A4, B4, Cpart, Kadj, Kadj, ktA, tpsA, KScap);
    reduce_many<<<dim3(256, 3), 256, 0, stream>>>(Cpart, Tb, nspA3, KScap);

    // 5) rec_i = T_i @ W_dec_i
    V3 WdTV; I3 Dz3 = {Din[0], Din[1], Din[2]};
    for (int i = 0; i < 3; ++i) WdTV.p[i] = WdecT[i];
    const int NTmax = DinP[0] / 64;
    gemm_rec<<<dim3(64, NTmax, 3), 256, 0, stream>>>(Tb, WdTV, rec_out, Dz3);
}

// Round 11
// 302.148 us; speedup vs baseline: 1.7877x; 1.0004x over previous
//
#include <hip/hip_runtime.h>

#define NR 4096

typedef __attribute__((ext_vector_type(8))) short bf16x8;
typedef __attribute__((ext_vector_type(4))) float f32x4;
typedef __attribute__((ext_vector_type(4))) unsigned short u16x4;

struct P3 { const float* p[3]; };
struct V3 { const void* p[3]; };
struct O3 { float* p[3]; };
struct I3 { int v[3]; };
struct P6 { const float* p[6]; };
struct V6 { const void* p[6]; };
struct U6 { unsigned short* p[6]; };
struct I6 { int v[6]; };

__device__ __forceinline__ unsigned short f2bf(float f) {
    union { float f; unsigned u; } v; v.f = f;
    unsigned r = v.u + 0x7fffu + ((v.u >> 16) & 1u);
    return (unsigned short)(r >> 16);
}
__device__ __forceinline__ float bf2f(unsigned short b) {
    union { unsigned u; float f; } v; v.u = ((unsigned)b) << 16;
    return v.f;
}

// ---------------------------------------------------------------------------
// C[M,64] = A[M,K] @ B[K,64], BK=128, pipelined staging.
// R10 diagnostic: occupancy 39->58% with zero speedup -> TLP saturated; the
// per-iteration SERIAL chain (A-load wait ~900cy -> ~128 VALU f2bf ->
// ds_write -> barrier -> MFMA w/ exposed B-loads) is the limiter.
// R11 changes (only two):
//  1) T14 async split: convert(i) from regs, RE-ISSUE same reg bank with
//     tile i+1's loads, then write/barrier/MFMA.  i+1's latency hides under
//     write+barrier+MFMA (~500cy).  Conversion of i+1 happens next iteration
//     -> compiler's vmcnt wait lands late (R5's bug was conv-at-issue).
//  2) v_cvt_pk_bf16_f32 (inline asm): 16 pack instrs replace ~128 manual
//     RNE bit-twiddle VALU ops per iteration.
// Rest identical to R10 (LDS [64][128] chunk-swizzled, B direct from L2,
// 4 waves 2x2, split-K partials, CT writes C^T).
// ---------------------------------------------------------------------------
template<bool CT>
__global__ __launch_bounds__(256, 2) void gemm_stream(
    P6 Aa, V6 Ba, float* __restrict__ Cpart,
    I6 Kz, I6 Kpz, I6 ktz, I6 tpsz, const int KScap)
{
    const int z = blockIdx.z;
    const int K = Kz.v[z], Kp = Kpz.v[z], ktiles = ktz.v[z], tps = tpsz.v[z];
    const int mt = blockIdx.x, sp = blockIdx.y;
    const int kt0 = sp * tps;
    int kt1 = kt0 + tps; if (kt1 > ktiles) kt1 = ktiles;
    if (kt0 >= kt1) return;                     // uniform early-exit

    __shared__ unsigned short As[64 * 128];     // 16 KB

    const int t = threadIdx.x;
    const int l = t & 63, w = t >> 6;
    const int lr = l & 15, lk = l >> 4;
    const int wm = (w >> 1) << 5, wn = (w & 1) << 5;

    const float* __restrict__ A = Aa.p[z];
    const unsigned short* __restrict__ Bt = (const unsigned short*)Ba.p[z];

    const unsigned short* BpA = Bt + (size_t)(wn + lr) * Kp + lk * 8;
    const unsigned short* BpB = Bt + (size_t)(wn + 16 + lr) * Kp + lk * 8;

    f32x4 acc00, acc01, acc10, acc11;
    #pragma unroll
    for (int r = 0; r < 4; ++r) { acc00[r] = 0.f; acc01[r] = 0.f; acc10[r] = 0.f; acc11[r] = 0.f; }

    // staging: wave w covers rows [w*16, w*16+16); instr j -> rows w*16+2j
    // and w*16+2j+1; lane l -> row +(l>>5), col floats (l&31)*4
    const int srow0 = w * 16 + (l >> 5);
    const int scol  = (l & 31) * 4;
    const float* Sbase = A + (size_t)(mt * 64 + srow0) * K + scol;

    const int wc  = (l & 31) >> 1;              // 16B chunk within row
    const int whb = (l & 1) << 3;               // 8B half of the chunk

    f32x4 v[8];                                 // single raw bank (reused)
    auto issueA = [&](int kt) {
        const int kk = kt * 128 + scol;
        #pragma unroll
        for (int j = 0; j < 8; ++j) {
            const float* p = Sbase + (size_t)(2 * j) * K + kt * 128;
            if (kk + 3 < K) {
                v[j] = *(const f32x4*)p;
            } else {
                #pragma unroll
                for (int e = 0; e < 4; ++e) v[j][e] = (kk + e < K) ? p[e] : 0.f;
            }
        }
    };

    issueA(kt0);

    for (int kt = kt0; kt < kt1; ++kt) {
        // 1) pack current tile (waits its loads), 2 cvt_pk per j
        unsigned pk0[8], pk1[8];
        #pragma unroll
        for (int j = 0; j < 8; ++j) {
            asm("v_cvt_pk_bf16_f32 %0, %1, %2"
                : "=v"(pk0[j]) : "v"(v[j][0]), "v"(v[j][1]));
            asm("v_cvt_pk_bf16_f32 %0, %1, %2"
                : "=v"(pk1[j]) : "v"(v[j][2]), "v"(v[j][3]));
        }
        // 2) re-issue the bank with next tile (latency hides under 3..5)
        if (kt + 1 < kt1) issueA(kt + 1);
        // 3) LDS write (swizzled)
        #pragma unroll
        for (int j = 0; j < 8; ++j) {
            const int row = w * 16 + 2 * j + (l >> 5);
            uint2 o; o.x = pk0[j]; o.y = pk1[j];
            *(uint2*)((char*)As + row * 256 + ((wc ^ (row & 15)) << 4) + whb) = o;
        }
        __syncthreads();
        // 4) MFMA phase (B direct from L2)
        const int rowA0 = wm + lr, rowA1 = wm + 16 + lr;
        const char* pa0 = (const char*)As + rowA0 * 256;
        const char* pa1 = (const char*)As + rowA1 * 256;
        const int sw0 = rowA0 & 15, sw1 = rowA1 & 15;
        #pragma unroll
        for (int ks = 0; ks < 4; ++ks) {
            const int c = ks * 4 + lk;
            const bf16x8 a0 = *(const bf16x8*)(pa0 + ((c ^ sw0) << 4));
            const bf16x8 a1 = *(const bf16x8*)(pa1 + ((c ^ sw1) << 4));
            const bf16x8 b0 = *(const bf16x8*)(BpA + kt * 128 + ks * 32);
            const bf16x8 b1 = *(const bf16x8*)(BpB + kt * 128 + ks * 32);
            acc00 = __builtin_amdgcn_mfma_f32_16x16x32_bf16(a0, b0, acc00, 0, 0, 0);
            acc01 = __builtin_amdgcn_mfma_f32_16x16x32_bf16(a0, b1, acc01, 0, 0, 0);
            acc10 = __builtin_amdgcn_mfma_f32_16x16x32_bf16(a1, b0, acc10, 0, 0, 0);
            acc11 = __builtin_amdgcn_mfma_f32_16x16x32_bf16(a1, b1, acc11, 0, 0, 0);
        }
        __syncthreads();
    }

    float* Cp = Cpart + (size_t)(z * KScap + sp) * (NR * 64);
    if (CT) {
        const int r0 = mt * 64 + wm + lk * 4;
        *(f32x4*)&Cp[(size_t)(wn + lr     ) * NR + r0     ] = acc00;
        *(f32x4*)&Cp[(size_t)(wn + 16 + lr) * NR + r0     ] = acc01;
        *(f32x4*)&Cp[(size_t)(wn + lr     ) * NR + r0 + 16] = acc10;
        *(f32x4*)&Cp[(size_t)(wn + 16 + lr) * NR + r0 + 16] = acc11;
    } else {
        #pragma unroll
        for (int r = 0; r < 4; ++r) {
            const int row = mt * 64 + wm + lk * 4 + r;
            Cp[(size_t)row * 64 + wn + lr     ] = acc00[r];
            Cp[(size_t)row * 64 + wn + 16 + lr] = acc01[r];
            Cp[(size_t)(row + 16) * 64 + wn + lr     ] = acc10[r];
            Cp[(size_t)(row + 16) * 64 + wn + 16 + lr] = acc11[r];
        }
    }
}

// sum per-z split partials -> bf16 (layout-agnostic), z-merged
__global__ __launch_bounds__(256) void reduce_many(
    const float* __restrict__ Cpart, unsigned short* __restrict__ out,
    I3 nsp, const int KScap)
{
    const int z = blockIdx.y;
    const int idx = (blockIdx.x * 256 + threadIdx.x) * 4;
    const float* base = Cpart + (size_t)z * KScap * (NR * 64);
    const int n = nsp.v[z];
    f32x4 s; s[0] = s[1] = s[2] = s[3] = 0.f;
    for (int sp = 0; sp < n; ++sp)
        s += *(const f32x4*)(base + (size_t)sp * (NR * 64) + idx);
    unsigned short* o = out + (size_t)z * (NR * 64);
    #pragma unroll
    for (int e = 0; e < 4; ++e) o[idx + e] = f2bf(s[e]);
}

// column sums of fe (from febT [64][NR]): csum[z][c] = sum_r fe[r][c]
__global__ __launch_bounds__(256) void colsum_kernel(
    const unsigned short* __restrict__ febT, float* __restrict__ csum)
{
    const int z = blockIdx.x;
    const int t = threadIdx.x, w = t >> 6, l = t & 63;
    for (int row = w; row < 64; row += 4) {
        const unsigned short* src = febT + ((size_t)z * 64 + row) * NR;
        float s = 0.f;
        for (int i = l * 8; i < NR; i += 512) {
            const bf16x8 v = *(const bf16x8*)(src + i);
            #pragma unroll
            for (int e = 0; e < 8; ++e) s += bf2f((unsigned short)v[e]);
        }
        #pragma unroll
        for (int off = 32; off >= 1; off >>= 1) s += __shfl_xor(s, off);
        if (l == 0) csum[z * 64 + row] = s;
    }
}

// gc = w0*S1 + w1*S2 + b*csum; emb = gc + alpha*(relu(LN(gc)@W1+b1)@W2+b2)
__global__ __launch_bounds__(256) void reduce_ced(
    const float* __restrict__ Cpart, P3 wca, P3 bca,
    const float* __restrict__ csum, P3 ga, P3 bea, P3 W1a, P3 b1a,
    P3 W2a, P3 b2a, P3 ala, float* __restrict__ emb_out,
    I6 nsp, const int KScap)
{
    __shared__ float ln_s[4][64];
    __shared__ float h_s[4][32];
    const int z = blockIdx.y;
    const int w = threadIdx.x >> 6, l = threadIdx.x & 63;
    const int row = blockIdx.x * 4 + w;
    const float* b1p = Cpart + (size_t)z * KScap * (NR * 64);
    const float* b2p = Cpart + (size_t)(3 + z) * KScap * (NR * 64);
    const int n1 = nsp.v[z], n2 = nsp.v[3 + z];
    float s1 = 0.f, s2 = 0.f;
    for (int sp = 0; sp < n1; ++sp)
        s1 += b1p[(size_t)sp * (NR * 64) + (size_t)row * 64 + l];
    for (int sp = 0; sp < n2; ++sp)
        s2 += b2p[(size_t)sp * (NR * 64) + (size_t)row * 64 + l];
    const float w0 = wca.p[z][0], w1 = wca.p[z][1], bb = bca.p[z][0];
    const float x = w0 * s1 + w1 * s2 + bb * csum[z * 64 + l];

    float s = x, s2v = x * x;
    #pragma unroll
    for (int off = 32; off >= 1; off >>= 1) {
        s   += __shfl_xor(s, off);
        s2v += __shfl_xor(s2v, off);
    }
    const float mu  = s * (1.f / 64.f);
    const float var = s2v * (1.f / 64.f) - mu * mu;
    const float ln = (x - mu) * rsqrtf(var + 1e-5f) * ga.p[z][l] + bea.p[z][l];
    ln_s[w][l] = ln;
    __syncthreads();
    if (l < 32) {
        const float* W1 = W1a.p[z];
        float h = b1a.p[z][l];
        #pragma unroll 8
        for (int k = 0; k < 64; ++k) h += ln_s[w][k] * W1[k * 32 + l];
        h_s[w][l] = fmaxf(h, 0.f);
    }
    __syncthreads();
    const float* W2 = W2a.p[z];
    float e = b2a.p[z][l];
    #pragma unroll 8
    for (int j = 0; j < 32; ++j) e += h_s[w][j] * W2[j * 64 + l];
    emb_out[(size_t)z * (NR * 64) + (size_t)row * 64 + l] = x + ala.p[z][0] * e;
}

// fusion MLP: comb = (cat @ Wfc1 + b1) @ Wfc2 + b2; emits f32 + combT bf16
__global__ __launch_bounds__(256) void fusion_kernel(
    const float* __restrict__ emb_base, const float* __restrict__ Wfc1,
    const float* __restrict__ bfc1, const float* __restrict__ Wfc2,
    const float* __restrict__ bfc2, float* __restrict__ comb,
    unsigned short* __restrict__ combT)
{
    __shared__ float cat_s[4][192];
    __shared__ float h_s[4][64];
    const int w = threadIdx.x >> 6, l = threadIdx.x & 63;
    const int row = blockIdx.x * 4 + w;
    cat_s[w][l]       = emb_base[(size_t)row * 64 + l];
    cat_s[w][64 + l]  = emb_base[(size_t)(NR * 64) + (size_t)row * 64 + l];
    cat_s[w][128 + l] = emb_base[(size_t)(2 * NR * 64) + (size_t)row * 64 + l];
    __syncthreads();
    float h = bfc1[l];
    #pragma unroll 8
    for (int k = 0; k < 192; ++k) h += cat_s[w][k] * Wfc1[k * 64 + l];
    h_s[w][l] = h;
    __syncthreads();
    float c = bfc2[l];
    #pragma unroll 8
    for (int j = 0; j < 64; ++j) c += h_s[w][j] * Wfc2[j * 64 + l];
    comb[(size_t)row * 64 + l] = c;
    combT[(size_t)l * NR + row] = f2bf(c);      // B^T for step-4
}

// generic f32 [R][C] -> bf16 [Cp][Rp] transpose with zero-pad (weights prep)
__global__ __launch_bounds__(256) void prep_t(P6 src, U6 dst, I6 Rv6, I6 Cv6,
                                              I6 Rp6, I6 Cp6)
{
    const int z = blockIdx.y;
    const int Rp = Rp6.v[z], Cp = Cp6.v[z];
    const int rtiles = Rp >> 6, ctiles = Cp >> 6;
    const int tid = blockIdx.x;
    if (tid >= rtiles * ctiles) return;
    const int ci = tid / rtiles, ri = tid % rtiles;
    __shared__ float ld[64][65];
    const int t = threadIdx.x;
    const float* s = src.p[z];
    const int Rv = Rv6.v[z], Cv = Cv6.v[z];
    {
        const int rr = t >> 2;
        const int gr = ri * 64 + rr;
        #pragma unroll
        for (int q = 0; q < 4; ++q) {
            const int cc = (t & 3) * 16 + q * 4;
            const int gc = ci * 64 + cc;
            f32x4 x;
            if (gr < Rv && gc + 3 < Cv) {
                x = *(const f32x4*)(s + (size_t)gr * Cv + gc);
            } else {
                #pragma unroll
                for (int e = 0; e < 4; ++e)
                    x[e] = (gr < Rv && gc + e < Cv) ? s[(size_t)gr * Cv + gc + e] : 0.f;
            }
            #pragma unroll
            for (int e = 0; e < 4; ++e) ld[rr][cc + e] = x[e];
        }
    }
    __syncthreads();
    {
        unsigned short* d = dst.p[z];
        const int cl = t >> 2;
        const int r4 = (t & 3) * 16;
        unsigned short vv[16] __attribute__((aligned(16)));
        #pragma unroll
        for (int e = 0; e < 16; ++e) vv[e] = f2bf(ld[r4 + e][cl]);
        const size_t bpos = (size_t)(ci * 64 + cl) * Rp + ri * 64 + r4;
        *(bf16x8*)&d[bpos]     = *(bf16x8*)&vv[0];
        *(bf16x8*)&d[bpos + 8] = *(bf16x8*)&vv[8];
    }
}

// rec[M,Dz] = Tb[M,64](bf16) @ WdecT_z^T ; B staged from WdecT[Dp][64] bf16.
__global__ __launch_bounds__(256) void gemm_rec(
    const unsigned short* __restrict__ Tbase, V3 WdTa, O3 outa, I3 Dz)
{
    const int z = blockIdx.z;
    const int Nw = Dz.v[z];
    const int mt = blockIdx.x, nt = blockIdx.y;
    if (nt * 64 >= Nw) return;                  // uniform early-exit
    __shared__ unsigned short As[64 * 64];
    __shared__ unsigned short Bs[64 * 64];
    const int t = threadIdx.x;
    const unsigned short* Tb = Tbase + (size_t)z * (NR * 64);
    const unsigned short* Wt = (const unsigned short*)WdTa.p[z];
    float* C = outa.p[z];

    const int sr = t >> 3, sc = t & 7;
    const int l = t & 63, w = t >> 6;
    const int wm = (w >> 1) << 5, wn = (w & 1) << 5;
    const int lr = l & 15, lk = l >> 4;
    const int aw0 = sr * 64 + ((sc ^ (sr & 7)) << 3);

    #pragma unroll
    for (int j = 0; j < 2; ++j) {
        const int m = j * 32 + sr;
        *(bf16x8*)&As[aw0 + j * 2048] = *(const bf16x8*)&Tb[(size_t)(mt * 64 + m) * 64 + sc * 8];
        *(bf16x8*)&Bs[aw0 + j * 2048] = *(const bf16x8*)&Wt[(size_t)(nt * 64 + m) * 64 + sc * 8];
    }
    __syncthreads();

    f32x4 acc[2][2];
    #pragma unroll
    for (int i = 0; i < 2; ++i)
        #pragma unroll
        for (int j = 0; j < 2; ++j)
            #pragma unroll
            for (int r = 0; r < 4; ++r) acc[i][j][r] = 0.f;

    #pragma unroll
    for (int ks = 0; ks < 2; ++ks) {
        bf16x8 af[2], bfv[2];
        #pragma unroll
        for (int i = 0; i < 2; ++i) {
            const int row = wm + (i << 4) + lr;
            af[i]  = *(const bf16x8*)&As[row * 64 + ((((ks << 2) + lk) ^ (row & 7)) << 3)];
            const int col = wn + (i << 4) + lr;
            bfv[i] = *(const bf16x8*)&Bs[col * 64 + ((((ks << 2) + lk) ^ (col & 7)) << 3)];
        }
        #pragma unroll
        for (int i = 0; i < 2; ++i)
            #pragma unroll
            for (int j = 0; j < 2; ++j)
                acc[i][j] = __builtin_amdgcn_mfma_f32_16x16x32_bf16(af[i], bfv[j], acc[i][j], 0, 0, 0);
    }

    #pragma unroll
    for (int i = 0; i < 2; ++i)
        #pragma unroll
        for (int j = 0; j < 2; ++j)
            #pragma unroll
            for (int r = 0; r < 4; ++r) {
                const int row = mt * 64 + wm + (i << 4) + (lk << 2) + r;
                const int col = nt * 64 + wn + (j << 4) + lr;
                if (col < Nw) C[(size_t)row * Nw + col] = acc[i][j][r];
            }
}

extern "C" void kernel_launch(void* const* d_in, const int* in_sizes, int n_in,
                              void* d_out, int out_size, void* d_ws, size_t ws_size,
                              hipStream_t stream)
{
    const int Din[3] = {3000, 1000, 500};
    const int DinP[3] = {3072, 1024, 512};      // padded to 128-multiples (BK)
    const float* feat[3]   = {(const float*)d_in[0], (const float*)d_in[1], (const float*)d_in[2]};
    const float* adj_sp[3] = {(const float*)d_in[3], (const float*)d_in[5], (const float*)d_in[7]};
    const float* adj_ft[3] = {(const float*)d_in[4], (const float*)d_in[6], (const float*)d_in[8]};
    const int base[3] = {9, 20, 31};
    const float *wconv[3], *bconv[3], *Wenc[3], *g[3], *be[3], *W1[3], *b1[3],
                *W2[3], *b2[3], *alpha[3], *Wdec[3];
    for (int i = 0; i < 3; ++i) {
        wconv[i] = (const float*)d_in[base[i] + 0];
        bconv[i] = (const float*)d_in[base[i] + 1];
        Wenc[i]  = (const float*)d_in[base[i] + 2];
        g[i]     = (const float*)d_in[base[i] + 3];
        be[i]    = (const float*)d_in[base[i] + 4];
        W1[i]    = (const float*)d_in[base[i] + 5];
        b1[i]    = (const float*)d_in[base[i] + 6];
        W2[i]    = (const float*)d_in[base[i] + 7];
        b2[i]    = (const float*)d_in[base[i] + 8];
        alpha[i] = (const float*)d_in[base[i] + 9];
        Wdec[i]  = (const float*)d_in[base[i] + 10];
    }
    const float* Wfc1 = (const float*)d_in[42];
    const float* bfc1 = (const float*)d_in[43];
    const float* Wfc2 = (const float*)d_in[44];
    const float* bfc2 = (const float*)d_in[45];

    // workspace: febT[3] | combT | Tb[3] (bf16), WencT[3], WdecT[3], csum, Cpart
    char* wsb = (char*)d_ws;
    const size_t SZ_BF = (size_t)NR * 64 * 2;   // 512 KB
    const size_t SZ_F  = (size_t)NR * 64 * 4;   // 1 MB
    unsigned short* febT  = (unsigned short*)wsb;                    // 3x
    unsigned short* combT = (unsigned short*)(wsb + 3 * SZ_BF);
    unsigned short* Tb    = (unsigned short*)(wsb + 4 * SZ_BF);      // 3x
    size_t off = 7 * SZ_BF;
    unsigned short* WencT[3]; unsigned short* WdecT[3];
    for (int i = 0; i < 3; ++i) { WencT[i] = (unsigned short*)(wsb + off); off += (size_t)DinP[i] * 64 * 2; }
    for (int i = 0; i < 3; ++i) { WdecT[i] = (unsigned short*)(wsb + off); off += (size_t)DinP[i] * 64 * 2; }
    float* csum = (float*)(wsb + ((off + 255) & ~(size_t)255));
    off = ((off + 255) & ~(size_t)255) + 3 * 64 * sizeof(float);
    const size_t cpart_off = ((off + 255) & ~(size_t)255);
    float* Cpart = (float*)(wsb + cpart_off);

    int KScap = (int)((ws_size - cpart_off) / (6 * SZ_F));
    if (KScap > 8) KScap = 8;
    if (KScap < 1) KScap = 1;

    float* out = (float*)d_out;
    float* emb_out  = out;
    float* comb_out = out + 3 * (size_t)NR * 64;
    O3 rec_out;
    rec_out.p[0] = out + 4 * (size_t)NR * 64;
    rec_out.p[1] = rec_out.p[0] + (size_t)NR * Din[0];
    rec_out.p[2] = rec_out.p[1] + (size_t)NR * Din[1];

    auto plan = [&](const int* kts, int cnt, I6& kt, I6& tps, I6& nsp, int& maxnsp) {
        maxnsp = 1;
        for (int i = 0; i < 6; ++i) {
            const int k = kts[(i < cnt) ? i : (cnt - 1)];
            const int tp = (k + KScap - 1) / KScap;
            kt.v[i] = k; tps.v[i] = tp;
            nsp.v[i] = (k + tp - 1) / tp;
            if (i < cnt && nsp.v[i] > maxnsp) maxnsp = nsp.v[i];
        }
    };

    P3 wcA, bcA, gA, beA, W1A, b1A, W2A, b2A, alA;
    for (int i = 0; i < 3; ++i) {
        wcA.p[i] = wconv[i]; bcA.p[i] = bconv[i];
        gA.p[i] = g[i]; beA.p[i] = be[i]; W1A.p[i] = W1[i]; b1A.p[i] = b1[i];
        W2A.p[i] = W2[i]; b2A.p[i] = b2[i]; alA.p[i] = alpha[i];
    }

    // step-1 (3 slices): feat @ WencT
    P6 A1; V6 B1;
    for (int i = 0; i < 3; ++i) { A1.p[i] = feat[i]; A1.p[3 + i] = feat[i];
                                  B1.p[i] = WencT[i]; B1.p[3 + i] = WencT[i]; }
    // step-2 (6 slices): adj_sp x3 then adj_ft x3; B = febT[z%3]
    P6 A2; V6 B2;
    for (int i = 0; i < 3; ++i) {
        A2.p[i]     = adj_sp[i];
        A2.p[3 + i] = adj_ft[i];
        B2.p[i]     = febT + (size_t)i * NR * 64;
        B2.p[3 + i] = febT + (size_t)i * NR * 64;
    }
    // step-4 (3 slices): adj_sp; B = combT
    P6 A4; V6 B4;
    for (int i = 0; i < 3; ++i) { A4.p[i] = adj_sp[i]; A4.p[3 + i] = adj_sp[i];
                                  B4.p[i] = combT;     B4.p[3 + i] = combT; }

    I6 K1 = {Din[0], Din[1], Din[2], Din[0], Din[1], Din[2]};
    I6 Kp1 = {DinP[0], DinP[1], DinP[2], DinP[0], DinP[1], DinP[2]};
    I6 Kadj; for (int i = 0; i < 6; ++i) Kadj.v[i] = NR;

    // BK=128 tiles
    const int kt1_[3] = {DinP[0] / 128, DinP[1] / 128, DinP[2] / 128};  // 24,8,4
    const int ktA_[1] = {NR / 128};                                      // 32
    I6 ktF, tpsF, nspF; int mF; plan(kt1_, 3, ktF, tpsF, nspF, mF);
    I6 ktA, tpsA, nspA; int mA; plan(ktA_, 1, ktA, tpsA, nspA, mA);

    I3 nspF3 = {nspF.v[0], nspF.v[1], nspF.v[2]};
    I3 nspA3 = {nspA.v[0], nspA.v[1], nspA.v[2]};

    // 0) weight prep: WencT [64][DinP], WdecT [DinP][64] (bf16, zero-padded)
    {
        P6 s6; U6 d6; I6 R6, C6, Rp6, Cp6;
        int maxtiles = 1;
        for (int i = 0; i < 3; ++i) {
            s6.p[i] = Wenc[i]; d6.p[i] = WencT[i];
            R6.v[i] = Din[i]; C6.v[i] = 64; Rp6.v[i] = DinP[i]; Cp6.v[i] = 64;
            s6.p[3 + i] = Wdec[i]; d6.p[3 + i] = WdecT[i];
            R6.v[3 + i] = 64; C6.v[3 + i] = Din[i]; Rp6.v[3 + i] = 64; Cp6.v[3 + i] = DinP[i];
            const int tls = DinP[i] / 64;
            if (tls > maxtiles) maxtiles = tls;
        }
        prep_t<<<dim3(maxtiles, 6), 256, 0, stream>>>(s6, d6, R6, C6, Rp6, Cp6);
    }

    // 1) fe_i = feat_i @ W_enc_i  -> transposed partials -> febT [64][NR]
    gemm_stream<true><<<dim3(64, mF, 3), 256, 0, stream>>>(
        A1, B1, Cpart, K1, Kp1, ktF, tpsF, KScap);
    reduce_many<<<dim3(256, 3), 256, 0, stream>>>(Cpart, febT, nspF3, KScap);

    // 1b) csum_z[c] = sum_r fe_z[r][c]  (conv bias term)
    colsum_kernel<<<3, 256, 0, stream>>>(febT, csum);

    // 2) S1_z = adj_sp_z @ fe_z, S2_z = adj_ft_z @ fe_z  (6 slices);
    //    reduce_ced: gc = w0*S1 + w1*S2 + b*csum, fused CED -> emb
    gemm_stream<false><<<dim3(64, mA, 6), 256, 0, stream>>>(
        A2, B2, Cpart, Kadj, Kadj, ktA, tpsA, KScap);
    reduce_ced<<<dim3(NR / 4, 3), 256, 0, stream>>>(
        Cpart, wcA, bcA, csum, gA, beA, W1A, b1A, W2A, b2A, alA,
        emb_out, nspA, KScap);

    // 3) fusion MLP -> comb (f32 out) + combT (bf16 B^T scratch)
    fusion_kernel<<<NR / 4, 256, 0, stream>>>(emb_out, Wfc1, bfc1, Wfc2, bfc2,
                                              comb_out, combT);

    // 4) T_i = adj_sp_i @ comb -> Tb [NR][64] bf16
    gemm_stream<false><<<dim3(64, mA, 3), 256, 0, stream>>>(
        A4, B4, Cpart, Kadj, Kadj, ktA, tpsA, KScap);
    reduce_many<<<dim3(256, 3), 256, 0, stream>>>(Cpart, Tb, nspA3, KScap);

    // 5) rec_i = T_i @ W_dec_i
    V3 WdTV; I3 Dz3 = {Din[0], Din[1], Din[2]};
    for (int i = 0; i < 3; ++i) WdTV.p[i] = WdecT[i];
    const int NTmax = DinP[0] / 64;
    gemm_rec<<<dim3(64, NTmax, 3), 256, 0, stream>>>(Tb, WdTV, rec_out, Dz3);
}

// Round 12
// 296.769 us; speedup vs baseline: 1.8201x; 1.0181x over previous
//
#include <hip/hip_runtime.h>

#define NR 4096

typedef __attribute__((ext_vector_type(8))) short bf16x8;
typedef __attribute__((ext_vector_type(4))) float f32x4;
typedef __attribute__((ext_vector_type(4))) unsigned short u16x4;

struct P3 { const float* p[3]; };
struct V3 { const void* p[3]; };
struct O3 { float* p[3]; };
struct I3 { int v[3]; };
struct P6 { const float* p[6]; };
struct V6 { const void* p[6]; };
struct U6 { unsigned short* p[6]; };
struct I6 { int v[6]; };

__device__ __forceinline__ unsigned short f2bf(float f) {
    union { float f; unsigned u; } v; v.f = f;
    unsigned r = v.u + 0x7fffu + ((v.u >> 16) & 1u);
    return (unsigned short)(r >> 16);
}
__device__ __forceinline__ float bf2f(unsigned short b) {
    union { unsigned u; float f; } v; v.u = ((unsigned)b) << 16;
    return v.f;
}

// ---------------------------------------------------------------------------
// C[M,64] = A[M,K] @ B[K,64], BK=128.  R12 changes (structure unchanged):
//  1) A-loads NON-TEMPORAL (adjacency is read once; avoid L1 allocate/fill
//     serialization — R11 showed data mostly L3-resident yet goodput capped
//     at ~5.5 B/cy/CU) and Cpart stores non-temporal (don't evict the
//     L3-resident adjacency).  B/febT stay cached (reused).
//  2) deeper split-K for small-grid launches (step-4/step-1): R9/R10 showed
//     throughput ~ block count in this regime.
// ---------------------------------------------------------------------------
template<bool CT>
__global__ __launch_bounds__(256, 2) void gemm_stream(
    P6 Aa, V6 Ba, float* __restrict__ Cpart,
    I6 Kz, I6 Kpz, I6 ktz, I6 tpsz, const int KScap)
{
    const int z = blockIdx.z;
    const int K = Kz.v[z], Kp = Kpz.v[z], ktiles = ktz.v[z], tps = tpsz.v[z];
    const int mt = blockIdx.x, sp = blockIdx.y;
    const int kt0 = sp * tps;
    int kt1 = kt0 + tps; if (kt1 > ktiles) kt1 = ktiles;
    if (kt0 >= kt1) return;                     // uniform early-exit

    __shared__ unsigned short As[64 * 128];     // 16 KB

    const int t = threadIdx.x;
    const int l = t & 63, w = t >> 6;
    const int lr = l & 15, lk = l >> 4;
    const int wm = (w >> 1) << 5, wn = (w & 1) << 5;

    const float* __restrict__ A = Aa.p[z];
    const unsigned short* __restrict__ Bt = (const unsigned short*)Ba.p[z];

    const unsigned short* BpA = Bt + (size_t)(wn + lr) * Kp + lk * 8;
    const unsigned short* BpB = Bt + (size_t)(wn + 16 + lr) * Kp + lk * 8;

    f32x4 acc00, acc01, acc10, acc11;
    #pragma unroll
    for (int r = 0; r < 4; ++r) { acc00[r] = 0.f; acc01[r] = 0.f; acc10[r] = 0.f; acc11[r] = 0.f; }

    const int srow0 = w * 16 + (l >> 5);
    const int scol  = (l & 31) * 4;
    const float* Sbase = A + (size_t)(mt * 64 + srow0) * K + scol;

    const int wc  = (l & 31) >> 1;              // 16B chunk within row
    const int whb = (l & 1) << 3;               // 8B half of the chunk

    f32x4 v[8];                                 // single raw bank (reused)
    auto issueA = [&](int kt) {
        const int kk = kt * 128 + scol;
        #pragma unroll
        for (int j = 0; j < 8; ++j) {
            const float* p = Sbase + (size_t)(2 * j) * K + kt * 128;
            if (kk + 3 < K) {
                v[j] = __builtin_nontemporal_load((const f32x4*)p);
            } else {
                #pragma unroll
                for (int e = 0; e < 4; ++e) v[j][e] = (kk + e < K) ? p[e] : 0.f;
            }
        }
    };

    issueA(kt0);

    for (int kt = kt0; kt < kt1; ++kt) {
        unsigned pk0[8], pk1[8];
        #pragma unroll
        for (int j = 0; j < 8; ++j) {
            asm("v_cvt_pk_bf16_f32 %0, %1, %2"
                : "=v"(pk0[j]) : "v"(v[j][0]), "v"(v[j][1]));
            asm("v_cvt_pk_bf16_f32 %0, %1, %2"
                : "=v"(pk1[j]) : "v"(v[j][2]), "v"(v[j][3]));
        }
        if (kt + 1 < kt1) issueA(kt + 1);       // next tile in flight
        #pragma unroll
        for (int j = 0; j < 8; ++j) {
            const int row = w * 16 + 2 * j + (l >> 5);
            uint2 o; o.x = pk0[j]; o.y = pk1[j];
            *(uint2*)((char*)As + row * 256 + ((wc ^ (row & 15)) << 4) + whb) = o;
        }
        __syncthreads();
        const int rowA0 = wm + lr, rowA1 = wm + 16 + lr;
        const char* pa0 = (const char*)As + rowA0 * 256;
        const char* pa1 = (const char*)As + rowA1 * 256;
        const int sw0 = rowA0 & 15, sw1 = rowA1 & 15;
        #pragma unroll
        for (int ks = 0; ks < 4; ++ks) {
            const int c = ks * 4 + lk;
            const bf16x8 a0 = *(const bf16x8*)(pa0 + ((c ^ sw0) << 4));
            const bf16x8 a1 = *(const bf16x8*)(pa1 + ((c ^ sw1) << 4));
            const bf16x8 b0 = *(const bf16x8*)(BpA + kt * 128 + ks * 32);
            const bf16x8 b1 = *(const bf16x8*)(BpB + kt * 128 + ks * 32);
            acc00 = __builtin_amdgcn_mfma_f32_16x16x32_bf16(a0, b0, acc00, 0, 0, 0);
            acc01 = __builtin_amdgcn_mfma_f32_16x16x32_bf16(a0, b1, acc01, 0, 0, 0);
            acc10 = __builtin_amdgcn_mfma_f32_16x16x32_bf16(a1, b0, acc10, 0, 0, 0);
            acc11 = __builtin_amdgcn_mfma_f32_16x16x32_bf16(a1, b1, acc11, 0, 0, 0);
        }
        __syncthreads();
    }

    float* Cp = Cpart + (size_t)(z * KScap + sp) * (NR * 64);
    if (CT) {
        const int r0 = mt * 64 + wm + lk * 4;
        __builtin_nontemporal_store(acc00, (f32x4*)&Cp[(size_t)(wn + lr     ) * NR + r0     ]);
        __builtin_nontemporal_store(acc01, (f32x4*)&Cp[(size_t)(wn + 16 + lr) * NR + r0     ]);
        __builtin_nontemporal_store(acc10, (f32x4*)&Cp[(size_t)(wn + lr     ) * NR + r0 + 16]);
        __builtin_nontemporal_store(acc11, (f32x4*)&Cp[(size_t)(wn + 16 + lr) * NR + r0 + 16]);
    } else {
        #pragma unroll
        for (int r = 0; r < 4; ++r) {
            const int row = mt * 64 + wm + lk * 4 + r;
            __builtin_nontemporal_store(acc00[r], &Cp[(size_t)row * 64 + wn + lr     ]);
            __builtin_nontemporal_store(acc01[r], &Cp[(size_t)row * 64 + wn + 16 + lr]);
            __builtin_nontemporal_store(acc10[r], &Cp[(size_t)(row + 16) * 64 + wn + lr     ]);
            __builtin_nontemporal_store(acc11[r], &Cp[(size_t)(row + 16) * 64 + wn + 16 + lr]);
        }
    }
}

// sum per-z split partials -> bf16 (layout-agnostic), z-merged
__global__ __launch_bounds__(256) void reduce_many(
    const float* __restrict__ Cpart, unsigned short* __restrict__ out,
    I3 nsp, const int KScap)
{
    const int z = blockIdx.y;
    const int idx = (blockIdx.x * 256 + threadIdx.x) * 4;
    const float* base = Cpart + (size_t)z * KScap * (NR * 64);
    const int n = nsp.v[z];
    f32x4 s; s[0] = s[1] = s[2] = s[3] = 0.f;
    for (int sp = 0; sp < n; ++sp)
        s += __builtin_nontemporal_load((const f32x4*)(base + (size_t)sp * (NR * 64) + idx));
    unsigned short* o = out + (size_t)z * (NR * 64);
    #pragma unroll
    for (int e = 0; e < 4; ++e) o[idx + e] = f2bf(s[e]);
}

// column sums of fe (from febT [64][NR]): csum[z][c] = sum_r fe[r][c]
__global__ __launch_bounds__(256) void colsum_kernel(
    const unsigned short* __restrict__ febT, float* __restrict__ csum)
{
    const int z = blockIdx.x;
    const int t = threadIdx.x, w = t >> 6, l = t & 63;
    for (int row = w; row < 64; row += 4) {
        const unsigned short* src = febT + ((size_t)z * 64 + row) * NR;
        float s = 0.f;
        for (int i = l * 8; i < NR; i += 512) {
            const bf16x8 v = *(const bf16x8*)(src + i);
            #pragma unroll
            for (int e = 0; e < 8; ++e) s += bf2f((unsigned short)v[e]);
        }
        #pragma unroll
        for (int off = 32; off >= 1; off >>= 1) s += __shfl_xor(s, off);
        if (l == 0) csum[z * 64 + row] = s;
    }
}

// gc = w0*S1 + w1*S2 + b*csum; emb = gc + alpha*(relu(LN(gc)@W1+b1)@W2+b2)
__global__ __launch_bounds__(256) void reduce_ced(
    const float* __restrict__ Cpart, P3 wca, P3 bca,
    const float* __restrict__ csum, P3 ga, P3 bea, P3 W1a, P3 b1a,
    P3 W2a, P3 b2a, P3 ala, float* __restrict__ emb_out,
    I6 nsp, const int KScap)
{
    __shared__ float ln_s[4][64];
    __shared__ float h_s[4][32];
    const int z = blockIdx.y;
    const int w = threadIdx.x >> 6, l = threadIdx.x & 63;
    const int row = blockIdx.x * 4 + w;
    const float* b1p = Cpart + (size_t)z * KScap * (NR * 64);
    const float* b2p = Cpart + (size_t)(3 + z) * KScap * (NR * 64);
    const int n1 = nsp.v[z], n2 = nsp.v[3 + z];
    float s1 = 0.f, s2 = 0.f;
    for (int sp = 0; sp < n1; ++sp)
        s1 += __builtin_nontemporal_load(&b1p[(size_t)sp * (NR * 64) + (size_t)row * 64 + l]);
    for (int sp = 0; sp < n2; ++sp)
        s2 += __builtin_nontemporal_load(&b2p[(size_t)sp * (NR * 64) + (size_t)row * 64 + l]);
    const float w0 = wca.p[z][0], w1 = wca.p[z][1], bb = bca.p[z][0];
    const float x = w0 * s1 + w1 * s2 + bb * csum[z * 64 + l];

    float s = x, s2v = x * x;
    #pragma unroll
    for (int off = 32; off >= 1; off >>= 1) {
        s   += __shfl_xor(s, off);
        s2v += __shfl_xor(s2v, off);
    }
    const float mu  = s * (1.f / 64.f);
    const float var = s2v * (1.f / 64.f) - mu * mu;
    const float ln = (x - mu) * rsqrtf(var + 1e-5f) * ga.p[z][l] + bea.p[z][l];
    ln_s[w][l] = ln;
    __syncthreads();
    if (l < 32) {
        const float* W1 = W1a.p[z];
        float h = b1a.p[z][l];
        #pragma unroll 8
        for (int k = 0; k < 64; ++k) h += ln_s[w][k] * W1[k * 32 + l];
        h_s[w][l] = fmaxf(h, 0.f);
    }
    __syncthreads();
    const float* W2 = W2a.p[z];
    float e = b2a.p[z][l];
    #pragma unroll 8
    for (int j = 0; j < 32; ++j) e += h_s[w][j] * W2[j * 64 + l];
    emb_out[(size_t)z * (NR * 64) + (size_t)row * 64 + l] = x + ala.p[z][0] * e;
}

// fusion MLP: comb = (cat @ Wfc1 + b1) @ Wfc2 + b2; emits f32 + combT bf16
__global__ __launch_bounds__(256) void fusion_kernel(
    const float* __restrict__ emb_base, const float* __restrict__ Wfc1,
    const float* __restrict__ bfc1, const float* __restrict__ Wfc2,
    const float* __restrict__ bfc2, float* __restrict__ comb,
    unsigned short* __restrict__ combT)
{
    __shared__ float cat_s[4][192];
    __shared__ float h_s[4][64];
    const int w = threadIdx.x >> 6, l = threadIdx.x & 63;
    const int row = blockIdx.x * 4 + w;
    cat_s[w][l]       = emb_base[(size_t)row * 64 + l];
    cat_s[w][64 + l]  = emb_base[(size_t)(NR * 64) + (size_t)row * 64 + l];
    cat_s[w][128 + l] = emb_base[(size_t)(2 * NR * 64) + (size_t)row * 64 + l];
    __syncthreads();
    float h = bfc1[l];
    #pragma unroll 8
    for (int k = 0; k < 192; ++k) h += cat_s[w][k] * Wfc1[k * 64 + l];
    h_s[w][l] = h;
    __syncthreads();
    float c = bfc2[l];
    #pragma unroll 8
    for (int j = 0; j < 64; ++j) c += h_s[w][j] * Wfc2[j * 64 + l];
    comb[(size_t)row * 64 + l] = c;
    combT[(size_t)l * NR + row] = f2bf(c);      // B^T for step-4
}

// generic f32 [R][C] -> bf16 [Cp][Rp] transpose with zero-pad (weights prep)
__global__ __launch_bounds__(256) void prep_t(P6 src, U6 dst, I6 Rv6, I6 Cv6,
                                              I6 Rp6, I6 Cp6)
{
    const int z = blockIdx.y;
    const int Rp = Rp6.v[z], Cp = Cp6.v[z];
    const int rtiles = Rp >> 6, ctiles = Cp >> 6;
    const int tid = blockIdx.x;
    if (tid >= rtiles * ctiles) return;
    const int ci = tid / rtiles, ri = tid % rtiles;
    __shared__ float ld[64][65];
    const int t = threadIdx.x;
    const float* s = src.p[z];
    const int Rv = Rv6.v[z], Cv = Cv6.v[z];
    {
        const int rr = t >> 2;
        const int gr = ri * 64 + rr;
        #pragma unroll
        for (int q = 0; q < 4; ++q) {
            const int cc = (t & 3) * 16 + q * 4;
            const int gc = ci * 64 + cc;
            f32x4 x;
            if (gr < Rv && gc + 3 < Cv) {
                x = *(const f32x4*)(s + (size_t)gr * Cv + gc);
            } else {
                #pragma unroll
                for (int e = 0; e < 4; ++e)
                    x[e] = (gr < Rv && gc + e < Cv) ? s[(size_t)gr * Cv + gc + e] : 0.f;
            }
            #pragma unroll
            for (int e = 0; e < 4; ++e) ld[rr][cc + e] = x[e];
        }
    }
    __syncthreads();
    {
        unsigned short* d = dst.p[z];
        const int cl = t >> 2;
        const int r4 = (t & 3) * 16;
        unsigned short vv[16] __attribute__((aligned(16)));
        #pragma unroll
        for (int e = 0; e < 16; ++e) vv[e] = f2bf(ld[r4 + e][cl]);
        const size_t bpos = (size_t)(ci * 64 + cl) * Rp + ri * 64 + r4;
        *(bf16x8*)&d[bpos]     = *(bf16x8*)&vv[0];
        *(bf16x8*)&d[bpos + 8] = *(bf16x8*)&vv[8];
    }
}

// rec[M,Dz] = Tb[M,64](bf16) @ WdecT_z^T ; B staged from WdecT[Dp][64] bf16.
__global__ __launch_bounds__(256) void gemm_rec(
    const unsigned short* __restrict__ Tbase, V3 WdTa, O3 outa, I3 Dz)
{
    const int z = blockIdx.z;
    const int Nw = Dz.v[z];
    const int mt = blockIdx.x, nt = blockIdx.y;
    if (nt * 64 >= Nw) return;                  // uniform early-exit
    __shared__ unsigned short As[64 * 64];
    __shared__ unsigned short Bs[64 * 64];
    const int t = threadIdx.x;
    const unsigned short* Tb = Tbase + (size_t)z * (NR * 64);
    const unsigned short* Wt = (const unsigned short*)WdTa.p[z];
    float* C = outa.p[z];

    const int sr = t >> 3, sc = t & 7;
    const int l = t & 63, w = t >> 6;
    const int wm = (w >> 1) << 5, wn = (w & 1) << 5;
    const int lr = l & 15, lk = l >> 4;
    const int aw0 = sr * 64 + ((sc ^ (sr & 7)) << 3);

    #pragma unroll
    for (int j = 0; j < 2; ++j) {
        const int m = j * 32 + sr;
        *(bf16x8*)&As[aw0 + j * 2048] = *(const bf16x8*)&Tb[(size_t)(mt * 64 + m) * 64 + sc * 8];
        *(bf16x8*)&Bs[aw0 + j * 2048] = *(const bf16x8*)&Wt[(size_t)(nt * 64 + m) * 64 + sc * 8];
    }
    __syncthreads();

    f32x4 acc[2][2];
    #pragma unroll
    for (int i = 0; i < 2; ++i)
        #pragma unroll
        for (int j = 0; j < 2; ++j)
            #pragma unroll
            for (int r = 0; r < 4; ++r) acc[i][j][r] = 0.f;

    #pragma unroll
    for (int ks = 0; ks < 2; ++ks) {
        bf16x8 af[2], bfv[2];
        #pragma unroll
        for (int i = 0; i < 2; ++i) {
            const int row = wm + (i << 4) + lr;
            af[i]  = *(const bf16x8*)&As[row * 64 + ((((ks << 2) + lk) ^ (row & 7)) << 3)];
            const int col = wn + (i << 4) + lr;
            bfv[i] = *(const bf16x8*)&Bs[col * 64 + ((((ks << 2) + lk) ^ (col & 7)) << 3)];
        }
        #pragma unroll
        for (int i = 0; i < 2; ++i)
            #pragma unroll
            for (int j = 0; j < 2; ++j)
                acc[i][j] = __builtin_amdgcn_mfma_f32_16x16x32_bf16(af[i], bfv[j], acc[i][j], 0, 0, 0);
    }

    #pragma unroll
    for (int i = 0; i < 2; ++i)
        #pragma unroll
        for (int j = 0; j < 2; ++j)
            #pragma unroll
            for (int r = 0; r < 4; ++r) {
                const int row = mt * 64 + wm + (i << 4) + (lk << 2) + r;
                const int col = nt * 64 + wn + (j << 4) + lr;
                if (col < Nw) C[(size_t)row * Nw + col] = acc[i][j][r];
            }
}

extern "C" void kernel_launch(void* const* d_in, const int* in_sizes, int n_in,
                              void* d_out, int out_size, void* d_ws, size_t ws_size,
                              hipStream_t stream)
{
    const int Din[3] = {3000, 1000, 500};
    const int DinP[3] = {3072, 1024, 512};      // padded to 128-multiples (BK)
    const float* feat[3]   = {(const float*)d_in[0], (const float*)d_in[1], (const float*)d_in[2]};
    const float* adj_sp[3] = {(const float*)d_in[3], (const float*)d_in[5], (const float*)d_in[7]};
    const float* adj_ft[3] = {(const float*)d_in[4], (const float*)d_in[6], (const float*)d_in[8]};
    const int base[3] = {9, 20, 31};
    const float *wconv[3], *bconv[3], *Wenc[3], *g[3], *be[3], *W1[3], *b1[3],
                *W2[3], *b2[3], *alpha[3], *Wdec[3];
    for (int i = 0; i < 3; ++i) {
        wconv[i] = (const float*)d_in[base[i] + 0];
        bconv[i] = (const float*)d_in[base[i] + 1];
        Wenc[i]  = (const float*)d_in[base[i] + 2];
        g[i]     = (const float*)d_in[base[i] + 3];
        be[i]    = (const float*)d_in[base[i] + 4];
        W1[i]    = (const float*)d_in[base[i] + 5];
        b1[i]    = (const float*)d_in[base[i] + 6];
        W2[i]    = (const float*)d_in[base[i] + 7];
        b2[i]    = (const float*)d_in[base[i] + 8];
        alpha[i] = (const float*)d_in[base[i] + 9];
        Wdec[i]  = (const float*)d_in[base[i] + 10];
    }
    const float* Wfc1 = (const float*)d_in[42];
    const float* bfc1 = (const float*)d_in[43];
    const float* Wfc2 = (const float*)d_in[44];
    const float* bfc2 = (const float*)d_in[45];

    // workspace: febT[3] | combT | Tb[3] (bf16), WencT[3], WdecT[3], csum, Cpart
    char* wsb = (char*)d_ws;
    const size_t SZ_BF = (size_t)NR * 64 * 2;   // 512 KB
    const size_t SZ_F  = (size_t)NR * 64 * 4;   // 1 MB
    unsigned short* febT  = (unsigned short*)wsb;                    // 3x
    unsigned short* combT = (unsigned short*)(wsb + 3 * SZ_BF);
    unsigned short* Tb    = (unsigned short*)(wsb + 4 * SZ_BF);      // 3x
    size_t off = 7 * SZ_BF;
    unsigned short* WencT[3]; unsigned short* WdecT[3];
    for (int i = 0; i < 3; ++i) { WencT[i] = (unsigned short*)(wsb + off); off += (size_t)DinP[i] * 64 * 2; }
    for (int i = 0; i < 3; ++i) { WdecT[i] = (unsigned short*)(wsb + off); off += (size_t)DinP[i] * 64 * 2; }
    float* csum = (float*)(wsb + ((off + 255) & ~(size_t)255));
    off = ((off + 255) & ~(size_t)255) + 3 * 64 * sizeof(float);
    const size_t cpart_off = ((off + 255) & ~(size_t)255);
    float* Cpart = (float*)(wsb + cpart_off);
    const size_t cregion = (ws_size > cpart_off) ? (ws_size - cpart_off) : 0;

    // step-2 uses 6 slice groups; steps 1/4 use 3 -> deeper split possible
    int KScapA = (int)(cregion / (6 * SZ_F));
    if (KScapA > 8)  KScapA = 8;
    if (KScapA < 1)  KScapA = 1;
    int KScapD = (int)(cregion / (3 * SZ_F));
    if (KScapD > 16) KScapD = 16;
    if (KScapD < 1)  KScapD = 1;

    float* out = (float*)d_out;
    float* emb_out  = out;
    float* comb_out = out + 3 * (size_t)NR * 64;
    O3 rec_out;
    rec_out.p[0] = out + 4 * (size_t)NR * 64;
    rec_out.p[1] = rec_out.p[0] + (size_t)NR * Din[0];
    rec_out.p[2] = rec_out.p[1] + (size_t)NR * Din[1];

    auto plan = [&](const int* kts, int cnt, int cap, I6& kt, I6& tps, I6& nsp,
                    int& maxnsp) {
        maxnsp = 1;
        for (int i = 0; i < 6; ++i) {
            const int k = kts[(i < cnt) ? i : (cnt - 1)];
            const int tp = (k + cap - 1) / cap;
            kt.v[i] = k; tps.v[i] = tp;
            nsp.v[i] = (k + tp - 1) / tp;
            if (i < cnt && nsp.v[i] > maxnsp) maxnsp = nsp.v[i];
        }
    };

    P3 wcA, bcA, gA, beA, W1A, b1A, W2A, b2A, alA;
    for (int i = 0; i < 3; ++i) {
        wcA.p[i] = wconv[i]; bcA.p[i] = bconv[i];
        gA.p[i] = g[i]; beA.p[i] = be[i]; W1A.p[i] = W1[i]; b1A.p[i] = b1[i];
        W2A.p[i] = W2[i]; b2A.p[i] = b2[i]; alA.p[i] = alpha[i];
    }

    // step-1 (3 slices): feat @ WencT
    P6 A1; V6 B1;
    for (int i = 0; i < 3; ++i) { A1.p[i] = feat[i]; A1.p[3 + i] = feat[i];
                                  B1.p[i] = WencT[i]; B1.p[3 + i] = WencT[i]; }
    // step-2 (6 slices): adj_sp x3 then adj_ft x3; B = febT[z%3]
    P6 A2; V6 B2;
    for (int i = 0; i < 3; ++i) {
        A2.p[i]     = adj_sp[i];
        A2.p[3 + i] = adj_ft[i];
        B2.p[i]     = febT + (size_t)i * NR * 64;
        B2.p[3 + i] = febT + (size_t)i * NR * 64;
    }
    // step-4 (3 slices): adj_sp; B = combT
    P6 A4; V6 B4;
    for (int i = 0; i < 3; ++i) { A4.p[i] = adj_sp[i]; A4.p[3 + i] = adj_sp[i];
                                  B4.p[i] = combT;     B4.p[3 + i] = combT; }

    I6 K1 = {Din[0], Din[1], Din[2], Din[0], Din[1], Din[2]};
    I6 Kp1 = {DinP[0], DinP[1], DinP[2], DinP[0], DinP[1], DinP[2]};
    I6 Kadj; for (int i = 0; i < 6; ++i) Kadj.v[i] = NR;

    // BK=128 tiles
    const int kt1_[3] = {DinP[0] / 128, DinP[1] / 128, DinP[2] / 128};  // 24,8,4
    const int ktA_[1] = {NR / 128};                                      // 32
    I6 ktF, tpsF, nspF; int mF; plan(kt1_, 3, KScapD, ktF, tpsF, nspF, mF);
    I6 ktA2, tpsA2, nspA2; int mA2; plan(ktA_, 1, KScapA, ktA2, tpsA2, nspA2, mA2);
    I6 ktA4, tpsA4, nspA4; int mA4; plan(ktA_, 1, KScapD, ktA4, tpsA4, nspA4, mA4);

    I3 nspF3  = {nspF.v[0],  nspF.v[1],  nspF.v[2]};
    I3 nspA43 = {nspA4.v[0], nspA4.v[1], nspA4.v[2]};

    // 0) weight prep: WencT [64][DinP], WdecT [DinP][64] (bf16, zero-padded)
    {
        P6 s6; U6 d6; I6 R6, C6, Rp6, Cp6;
        int maxtiles = 1;
        for (int i = 0; i < 3; ++i) {
            s6.p[i] = Wenc[i]; d6.p[i] = WencT[i];
            R6.v[i] = Din[i]; C6.v[i] = 64; Rp6.v[i] = DinP[i]; Cp6.v[i] = 64;
            s6.p[3 + i] = Wdec[i]; d6.p[3 + i] = WdecT[i];
            R6.v[3 + i] = 64; C6.v[3 + i] = Din[i]; Rp6.v[3 + i] = 64; Cp6.v[3 + i] = DinP[i];
            const int tls = DinP[i] / 64;
            if (tls > maxtiles) maxtiles = tls;
        }
        prep_t<<<dim3(maxtiles, 6), 256, 0, stream>>>(s6, d6, R6, C6, Rp6, Cp6);
    }

    // 1) fe_i = feat_i @ W_enc_i  -> transposed partials -> febT [64][NR]
    gemm_stream<true><<<dim3(64, mF, 3), 256, 0, stream>>>(
        A1, B1, Cpart, K1, Kp1, ktF, tpsF, KScapD);
    reduce_many<<<dim3(256, 3), 256, 0, stream>>>(Cpart, febT, nspF3, KScapD);

    // 1b) csum_z[c] = sum_r fe_z[r][c]  (conv bias term)
    colsum_kernel<<<3, 256, 0, stream>>>(febT, csum);

    // 2) S1_z = adj_sp_z @ fe_z, S2_z = adj_ft_z @ fe_z  (6 slices);
    //    reduce_ced: gc = w0*S1 + w1*S2 + b*csum, fused CED -> emb
    gemm_stream<false><<<dim3(64, mA2, 6), 256, 0, stream>>>(
        A2, B2, Cpart, Kadj, Kadj, ktA2, tpsA2, KScapA);
    reduce_ced<<<dim3(NR / 4, 3), 256, 0, stream>>>(
        Cpart, wcA, bcA, csum, gA, beA, W1A, b1A, W2A, b2A, alA,
        emb_out, nspA2, KScapA);

    // 3) fusion MLP -> comb (f32 out) + combT (bf16 B^T scratch)
    fusion_kernel<<<NR / 4, 256, 0, stream>>>(emb_out, Wfc1, bfc1, Wfc2, bfc2,
                                              comb_out, combT);

    // 4) T_i = adj_sp_i @ comb -> Tb [NR][64] bf16   (deep split: KScapD)
    gemm_stream<false><<<dim3(64, mA4, 3), 256, 0, stream>>>(
        A4, B4, Cpart, Kadj, Kadj, ktA4, tpsA4, KScapD);
    reduce_many<<<dim3(256, 3), 256, 0, stream>>>(Cpart, Tb, nspA43, KScapD);

    // 5) rec_i = T_i @ W_dec_i
    V3 WdTV; I3 Dz3 = {Din[0], Din[1], Din[2]};
    for (int i = 0; i < 3; ++i) WdTV.p[i] = WdecT[i];
    const int NTmax = DinP[0] / 64;
    gemm_rec<<<dim3(64, NTmax, 3), 256, 0, stream>>>(Tb, WdTV, rec_out, Dz3);
}

// Round 13
// 289.592 us; speedup vs baseline: 1.8652x; 1.0248x over previous
//
#include <hip/hip_runtime.h>

#define NR 4096

typedef __attribute__((ext_vector_type(8))) short bf16x8;
typedef __attribute__((ext_vector_type(4))) float f32x4;
typedef __attribute__((ext_vector_type(4))) unsigned short u16x4;

struct P3 { const float* p[3]; };
struct V3 { const void* p[3]; };
struct O3 { float* p[3]; };
struct I3 { int v[3]; };
struct P6 { const float* p[6]; };
struct V6 { const void* p[6]; };
struct U6 { unsigned short* p[6]; };
struct I6 { int v[6]; };

__device__ __forceinline__ unsigned short f2bf(float f) {
    union { float f; unsigned u; } v; v.f = f;
    unsigned r = v.u + 0x7fffu + ((v.u >> 16) & 1u);
    return (unsigned short)(r >> 16);
}
__device__ __forceinline__ float bf2f(unsigned short b) {
    union { unsigned u; float f; } v; v.u = ((unsigned)b) << 16;
    return v.f;
}

// ---------------------------------------------------------------------------
// C[M,64] = A[M,K] @ B[K,64], BK=128.
// R12 lesson: nt is traffic-class-specific.  A-loads (stream-once adjacency)
// nt = +27% (118->93us big GEMMs, 4.3 TB/s ~ 70% of per-CU ceiling).  But nt
// on Cpart stores/reduce loads pushed producer-consumer partials (~240 MB)
// out of L2/L3 to HBM, costing ~48us elsewhere.  R13: keep nt ONLY on
// A-loads; partials go back through cache.  launch_bounds(256,4) hint.
// ---------------------------------------------------------------------------
template<bool CT>
__global__ __launch_bounds__(256, 4) void gemm_stream(
    P6 Aa, V6 Ba, float* __restrict__ Cpart,
    I6 Kz, I6 Kpz, I6 ktz, I6 tpsz, const int KScap)
{
    const int z = blockIdx.z;
    const int K = Kz.v[z], Kp = Kpz.v[z], ktiles = ktz.v[z], tps = tpsz.v[z];
    const int mt = blockIdx.x, sp = blockIdx.y;
    const int kt0 = sp * tps;
    int kt1 = kt0 + tps; if (kt1 > ktiles) kt1 = ktiles;
    if (kt0 >= kt1) return;                     // uniform early-exit

    __shared__ unsigned short As[64 * 128];     // 16 KB

    const int t = threadIdx.x;
    const int l = t & 63, w = t >> 6;
    const int lr = l & 15, lk = l >> 4;
    const int wm = (w >> 1) << 5, wn = (w & 1) << 5;

    const float* __restrict__ A = Aa.p[z];
    const unsigned short* __restrict__ Bt = (const unsigned short*)Ba.p[z];

    const unsigned short* BpA = Bt + (size_t)(wn + lr) * Kp + lk * 8;
    const unsigned short* BpB = Bt + (size_t)(wn + 16 + lr) * Kp + lk * 8;

    f32x4 acc00, acc01, acc10, acc11;
    #pragma unroll
    for (int r = 0; r < 4; ++r) { acc00[r] = 0.f; acc01[r] = 0.f; acc10[r] = 0.f; acc11[r] = 0.f; }

    const int srow0 = w * 16 + (l >> 5);
    const int scol  = (l & 31) * 4;
    const float* Sbase = A + (size_t)(mt * 64 + srow0) * K + scol;

    const int wc  = (l & 31) >> 1;              // 16B chunk within row
    const int whb = (l & 1) << 3;               // 8B half of the chunk

    f32x4 v[8];                                 // single raw bank (reused)
    auto issueA = [&](int kt) {
        const int kk = kt * 128 + scol;
        #pragma unroll
        for (int j = 0; j < 8; ++j) {
            const float* p = Sbase + (size_t)(2 * j) * K + kt * 128;
            if (kk + 3 < K) {
                v[j] = __builtin_nontemporal_load((const f32x4*)p);
            } else {
                #pragma unroll
                for (int e = 0; e < 4; ++e) v[j][e] = (kk + e < K) ? p[e] : 0.f;
            }
        }
    };

    issueA(kt0);

    for (int kt = kt0; kt < kt1; ++kt) {
        unsigned pk0[8], pk1[8];
        #pragma unroll
        for (int j = 0; j < 8; ++j) {
            asm("v_cvt_pk_bf16_f32 %0, %1, %2"
                : "=v"(pk0[j]) : "v"(v[j][0]), "v"(v[j][1]));
            asm("v_cvt_pk_bf16_f32 %0, %1, %2"
                : "=v"(pk1[j]) : "v"(v[j][2]), "v"(v[j][3]));
        }
        if (kt + 1 < kt1) issueA(kt + 1);       // next tile in flight
        #pragma unroll
        for (int j = 0; j < 8; ++j) {
            const int row = w * 16 + 2 * j + (l >> 5);
            uint2 o; o.x = pk0[j]; o.y = pk1[j];
            *(uint2*)((char*)As + row * 256 + ((wc ^ (row & 15)) << 4) + whb) = o;
        }
        __syncthreads();
        const int rowA0 = wm + lr, rowA1 = wm + 16 + lr;
        const char* pa0 = (const char*)As + rowA0 * 256;
        const char* pa1 = (const char*)As + rowA1 * 256;
        const int sw0 = rowA0 & 15, sw1 = rowA1 & 15;
        #pragma unroll
        for (int ks = 0; ks < 4; ++ks) {
            const int c = ks * 4 + lk;
            const bf16x8 a0 = *(const bf16x8*)(pa0 + ((c ^ sw0) << 4));
            const bf16x8 a1 = *(const bf16x8*)(pa1 + ((c ^ sw1) << 4));
            const bf16x8 b0 = *(const bf16x8*)(BpA + kt * 128 + ks * 32);
            const bf16x8 b1 = *(const bf16x8*)(BpB + kt * 128 + ks * 32);
            acc00 = __builtin_amdgcn_mfma_f32_16x16x32_bf16(a0, b0, acc00, 0, 0, 0);
            acc01 = __builtin_amdgcn_mfma_f32_16x16x32_bf16(a0, b1, acc01, 0, 0, 0);
            acc10 = __builtin_amdgcn_mfma_f32_16x16x32_bf16(a1, b0, acc10, 0, 0, 0);
            acc11 = __builtin_amdgcn_mfma_f32_16x16x32_bf16(a1, b1, acc11, 0, 0, 0);
        }
        __syncthreads();
    }

    float* Cp = Cpart + (size_t)(z * KScap + sp) * (NR * 64);
    if (CT) {
        const int r0 = mt * 64 + wm + lk * 4;
        *(f32x4*)&Cp[(size_t)(wn + lr     ) * NR + r0     ] = acc00;
        *(f32x4*)&Cp[(size_t)(wn + 16 + lr) * NR + r0     ] = acc01;
        *(f32x4*)&Cp[(size_t)(wn + lr     ) * NR + r0 + 16] = acc10;
        *(f32x4*)&Cp[(size_t)(wn + 16 + lr) * NR + r0 + 16] = acc11;
    } else {
        #pragma unroll
        for (int r = 0; r < 4; ++r) {
            const int row = mt * 64 + wm + lk * 4 + r;
            Cp[(size_t)row * 64 + wn + lr     ] = acc00[r];
            Cp[(size_t)row * 64 + wn + 16 + lr] = acc01[r];
            Cp[(size_t)(row + 16) * 64 + wn + lr     ] = acc10[r];
            Cp[(size_t)(row + 16) * 64 + wn + 16 + lr] = acc11[r];
        }
    }
}

// sum per-z split partials -> bf16 (layout-agnostic), z-merged
__global__ __launch_bounds__(256) void reduce_many(
    const float* __restrict__ Cpart, unsigned short* __restrict__ out,
    I3 nsp, const int KScap)
{
    const int z = blockIdx.y;
    const int idx = (blockIdx.x * 256 + threadIdx.x) * 4;
    const float* base = Cpart + (size_t)z * KScap * (NR * 64);
    const int n = nsp.v[z];
    f32x4 s; s[0] = s[1] = s[2] = s[3] = 0.f;
    for (int sp = 0; sp < n; ++sp)
        s += *(const f32x4*)(base + (size_t)sp * (NR * 64) + idx);
    unsigned short* o = out + (size_t)z * (NR * 64);
    #pragma unroll
    for (int e = 0; e < 4; ++e) o[idx + e] = f2bf(s[e]);
}

// column sums of fe (from febT [64][NR]): csum[z][c] = sum_r fe[r][c]
__global__ __launch_bounds__(256) void colsum_kernel(
    const unsigned short* __restrict__ febT, float* __restrict__ csum)
{
    const int z = blockIdx.x;
    const int t = threadIdx.x, w = t >> 6, l = t & 63;
    for (int row = w; row < 64; row += 4) {
        const unsigned short* src = febT + ((size_t)z * 64 + row) * NR;
        float s = 0.f;
        for (int i = l * 8; i < NR; i += 512) {
            const bf16x8 v = *(const bf16x8*)(src + i);
            #pragma unroll
            for (int e = 0; e < 8; ++e) s += bf2f((unsigned short)v[e]);
        }
        #pragma unroll
        for (int off = 32; off >= 1; off >>= 1) s += __shfl_xor(s, off);
        if (l == 0) csum[z * 64 + row] = s;
    }
}

// gc = w0*S1 + w1*S2 + b*csum; emb = gc + alpha*(relu(LN(gc)@W1+b1)@W2+b2)
__global__ __launch_bounds__(256) void reduce_ced(
    const float* __restrict__ Cpart, P3 wca, P3 bca,
    const float* __restrict__ csum, P3 ga, P3 bea, P3 W1a, P3 b1a,
    P3 W2a, P3 b2a, P3 ala, float* __restrict__ emb_out,
    I6 nsp, const int KScap)
{
    __shared__ float ln_s[4][64];
    __shared__ float h_s[4][32];
    const int z = blockIdx.y;
    const int w = threadIdx.x >> 6, l = threadIdx.x & 63;
    const int row = blockIdx.x * 4 + w;
    const float* b1p = Cpart + (size_t)z * KScap * (NR * 64);
    const float* b2p = Cpart + (size_t)(3 + z) * KScap * (NR * 64);
    const int n1 = nsp.v[z], n2 = nsp.v[3 + z];
    float s1 = 0.f, s2 = 0.f;
    for (int sp = 0; sp < n1; ++sp)
        s1 += b1p[(size_t)sp * (NR * 64) + (size_t)row * 64 + l];
    for (int sp = 0; sp < n2; ++sp)
        s2 += b2p[(size_t)sp * (NR * 64) + (size_t)row * 64 + l];
    const float w0 = wca.p[z][0], w1 = wca.p[z][1], bb = bca.p[z][0];
    const float x = w0 * s1 + w1 * s2 + bb * csum[z * 64 + l];

    float s = x, s2v = x * x;
    #pragma unroll
    for (int off = 32; off >= 1; off >>= 1) {
        s   += __shfl_xor(s, off);
        s2v += __shfl_xor(s2v, off);
    }
    const float mu  = s * (1.f / 64.f);
    const float var = s2v * (1.f / 64.f) - mu * mu;
    const float ln = (x - mu) * rsqrtf(var + 1e-5f) * ga.p[z][l] + bea.p[z][l];
    ln_s[w][l] = ln;
    __syncthreads();
    if (l < 32) {
        const float* W1 = W1a.p[z];
        float h = b1a.p[z][l];
        #pragma unroll 8
        for (int k = 0; k < 64; ++k) h += ln_s[w][k] * W1[k * 32 + l];
        h_s[w][l] = fmaxf(h, 0.f);
    }
    __syncthreads();
    const float* W2 = W2a.p[z];
    float e = b2a.p[z][l];
    #pragma unroll 8
    for (int j = 0; j < 32; ++j) e += h_s[w][j] * W2[j * 64 + l];
    emb_out[(size_t)z * (NR * 64) + (size_t)row * 64 + l] = x + ala.p[z][0] * e;
}

// fusion MLP: comb = (cat @ Wfc1 + b1) @ Wfc2 + b2; emits f32 + combT bf16
__global__ __launch_bounds__(256) void fusion_kernel(
    const float* __restrict__ emb_base, const float* __restrict__ Wfc1,
    const float* __restrict__ bfc1, const float* __restrict__ Wfc2,
    const float* __restrict__ bfc2, float* __restrict__ comb,
    unsigned short* __restrict__ combT)
{
    __shared__ float cat_s[4][192];
    __shared__ float h_s[4][64];
    const int w = threadIdx.x >> 6, l = threadIdx.x & 63;
    const int row = blockIdx.x * 4 + w;
    cat_s[w][l]       = emb_base[(size_t)row * 64 + l];
    cat_s[w][64 + l]  = emb_base[(size_t)(NR * 64) + (size_t)row * 64 + l];
    cat_s[w][128 + l] = emb_base[(size_t)(2 * NR * 64) + (size_t)row * 64 + l];
    __syncthreads();
    float h = bfc1[l];
    #pragma unroll 8
    for (int k = 0; k < 192; ++k) h += cat_s[w][k] * Wfc1[k * 64 + l];
    h_s[w][l] = h;
    __syncthreads();
    float c = bfc2[l];
    #pragma unroll 8
    for (int j = 0; j < 64; ++j) c += h_s[w][j] * Wfc2[j * 64 + l];
    comb[(size_t)row * 64 + l] = c;
    combT[(size_t)l * NR + row] = f2bf(c);      // B^T for step-4
}

// generic f32 [R][C] -> bf16 [Cp][Rp] transpose with zero-pad (weights prep)
__global__ __launch_bounds__(256) void prep_t(P6 src, U6 dst, I6 Rv6, I6 Cv6,
                                              I6 Rp6, I6 Cp6)
{
    const int z = blockIdx.y;
    const int Rp = Rp6.v[z], Cp = Cp6.v[z];
    const int rtiles = Rp >> 6, ctiles = Cp >> 6;
    const int tid = blockIdx.x;
    if (tid >= rtiles * ctiles) return;
    const int ci = tid / rtiles, ri = tid % rtiles;
    __shared__ float ld[64][65];
    const int t = threadIdx.x;
    const float* s = src.p[z];
    const int Rv = Rv6.v[z], Cv = Cv6.v[z];
    {
        const int rr = t >> 2;
        const int gr = ri * 64 + rr;
        #pragma unroll
        for (int q = 0; q < 4; ++q) {
            const int cc = (t & 3) * 16 + q * 4;
            const int gc = ci * 64 + cc;
            f32x4 x;
            if (gr < Rv && gc + 3 < Cv) {
                x = *(const f32x4*)(s + (size_t)gr * Cv + gc);
            } else {
                #pragma unroll
                for (int e = 0; e < 4; ++e)
                    x[e] = (gr < Rv && gc + e < Cv) ? s[(size_t)gr * Cv + gc + e] : 0.f;
            }
            #pragma unroll
            for (int e = 0; e < 4; ++e) ld[rr][cc + e] = x[e];
        }
    }
    __syncthreads();
    {
        unsigned short* d = dst.p[z];
        const int cl = t >> 2;
        const int r4 = (t & 3) * 16;
        unsigned short vv[16] __attribute__((aligned(16)));
        #pragma unroll
        for (int e = 0; e < 16; ++e) vv[e] = f2bf(ld[r4 + e][cl]);
        const size_t bpos = (size_t)(ci * 64 + cl) * Rp + ri * 64 + r4;
        *(bf16x8*)&d[bpos]     = *(bf16x8*)&vv[0];
        *(bf16x8*)&d[bpos + 8] = *(bf16x8*)&vv[8];
    }
}

// rec[M,Dz] = Tb[M,64](bf16) @ WdecT_z^T ; B staged from WdecT[Dp][64] bf16.
__global__ __launch_bounds__(256) void gemm_rec(
    const unsigned short* __restrict__ Tbase, V3 WdTa, O3 outa, I3 Dz)
{
    const int z = blockIdx.z;
    const int Nw = Dz.v[z];
    const int mt = blockIdx.x, nt = blockIdx.y;
    if (nt * 64 >= Nw) return;                  // uniform early-exit
    __shared__ unsigned short As[64 * 64];
    __shared__ unsigned short Bs[64 * 64];
    const int t = threadIdx.x;
    const unsigned short* Tb = Tbase + (size_t)z * (NR * 64);
    const unsigned short* Wt = (const unsigned short*)WdTa.p[z];
    float* C = outa.p[z];

    const int sr = t >> 3, sc = t & 7;
    const int l = t & 63, w = t >> 6;
    const int wm = (w >> 1) << 5, wn = (w & 1) << 5;
    const int lr = l & 15, lk = l >> 4;
    const int aw0 = sr * 64 + ((sc ^ (sr & 7)) << 3);

    #pragma unroll
    for (int j = 0; j < 2; ++j) {
        const int m = j * 32 + sr;
        *(bf16x8*)&As[aw0 + j * 2048] = *(const bf16x8*)&Tb[(size_t)(mt * 64 + m) * 64 + sc * 8];
        *(bf16x8*)&Bs[aw0 + j * 2048] = *(const bf16x8*)&Wt[(size_t)(nt * 64 + m) * 64 + sc * 8];
    }
    __syncthreads();

    f32x4 acc[2][2];
    #pragma unroll
    for (int i = 0; i < 2; ++i)
        #pragma unroll
        for (int j = 0; j < 2; ++j)
            #pragma unroll
            for (int r = 0; r < 4; ++r) acc[i][j][r] = 0.f;

    #pragma unroll
    for (int ks = 0; ks < 2; ++ks) {
        bf16x8 af[2], bfv[2];
        #pragma unroll
        for (int i = 0; i < 2; ++i) {
            const int row = wm + (i << 4) + lr;
            af[i]  = *(const bf16x8*)&As[row * 64 + ((((ks << 2) + lk) ^ (row & 7)) << 3)];
            const int col = wn + (i << 4) + lr;
            bfv[i] = *(const bf16x8*)&Bs[col * 64 + ((((ks << 2) + lk) ^ (col & 7)) << 3)];
        }
        #pragma unroll
        for (int i = 0; i < 2; ++i)
            #pragma unroll
            for (int j = 0; j < 2; ++j)
                acc[i][j] = __builtin_amdgcn_mfma_f32_16x16x32_bf16(af[i], bfv[j], acc[i][j], 0, 0, 0);
    }

    #pragma unroll
    for (int i = 0; i < 2; ++i)
        #pragma unroll
        for (int j = 0; j < 2; ++j)
            #pragma unroll
            for (int r = 0; r < 4; ++r) {
                const int row = mt * 64 + wm + (i << 4) + (lk << 2) + r;
                const int col = nt * 64 + wn + (j << 4) + lr;
                if (col < Nw) C[(size_t)row * Nw + col] = acc[i][j][r];
            }
}

extern "C" void kernel_launch(void* const* d_in, const int* in_sizes, int n_in,
                              void* d_out, int out_size, void* d_ws, size_t ws_size,
                              hipStream_t stream)
{
    const int Din[3] = {3000, 1000, 500};
    const int DinP[3] = {3072, 1024, 512};      // padded to 128-multiples (BK)
    const float* feat[3]   = {(const float*)d_in[0], (const float*)d_in[1], (const float*)d_in[2]};
    const float* adj_sp[3] = {(const float*)d_in[3], (const float*)d_in[5], (const float*)d_in[7]};
    const float* adj_ft[3] = {(const float*)d_in[4], (const float*)d_in[6], (const float*)d_in[8]};
    const int base[3] = {9, 20, 31};
    const float *wconv[3], *bconv[3], *Wenc[3], *g[3], *be[3], *W1[3], *b1[3],
                *W2[3], *b2[3], *alpha[3], *Wdec[3];
    for (int i = 0; i < 3; ++i) {
        wconv[i] = (const float*)d_in[base[i] + 0];
        bconv[i] = (const float*)d_in[base[i] + 1];
        Wenc[i]  = (const float*)d_in[base[i] + 2];
        g[i]     = (const float*)d_in[base[i] + 3];
        be[i]    = (const float*)d_in[base[i] + 4];
        W1[i]    = (const float*)d_in[base[i] + 5];
        b1[i]    = (const float*)d_in[base[i] + 6];
        W2[i]    = (const float*)d_in[base[i] + 7];
        b2[i]    = (const float*)d_in[base[i] + 8];
        alpha[i] = (const float*)d_in[base[i] + 9];
        Wdec[i]  = (const float*)d_in[base[i] + 10];
    }
    const float* Wfc1 = (const float*)d_in[42];
    const float* bfc1 = (const float*)d_in[43];
    const float* Wfc2 = (const float*)d_in[44];
    const float* bfc2 = (const float*)d_in[45];

    // workspace: febT[3] | combT | Tb[3] (bf16), WencT[3], WdecT[3], csum, Cpart
    char* wsb = (char*)d_ws;
    const size_t SZ_BF = (size_t)NR * 64 * 2;   // 512 KB
    const size_t SZ_F  = (size_t)NR * 64 * 4;   // 1 MB
    unsigned short* febT  = (unsigned short*)wsb;                    // 3x
    unsigned short* combT = (unsigned short*)(wsb + 3 * SZ_BF);
    unsigned short* Tb    = (unsigned short*)(wsb + 4 * SZ_BF);      // 3x
    size_t off = 7 * SZ_BF;
    unsigned short* WencT[3]; unsigned short* WdecT[3];
    for (int i = 0; i < 3; ++i) { WencT[i] = (unsigned short*)(wsb + off); off += (size_t)DinP[i] * 64 * 2; }
    for (int i = 0; i < 3; ++i) { WdecT[i] = (unsigned short*)(wsb + off); off += (size_t)DinP[i] * 64 * 2; }
    float* csum = (float*)(wsb + ((off + 255) & ~(size_t)255));
    off = ((off + 255) & ~(size_t)255) + 3 * 64 * sizeof(float);
    const size_t cpart_off = ((off + 255) & ~(size_t)255);
    float* Cpart = (float*)(wsb + cpart_off);
    const size_t cregion = (ws_size > cpart_off) ? (ws_size - cpart_off) : 0;

    // step-2 uses 6 slice groups; steps 1/4 use 3 -> deeper split possible
    int KScapA = (int)(cregion / (6 * SZ_F));
    if (KScapA > 8)  KScapA = 8;
    if (KScapA < 1)  KScapA = 1;
    int KScapD = (int)(cregion / (3 * SZ_F));
    if (KScapD > 16) KScapD = 16;
    if (KScapD < 1)  KScapD = 1;

    float* out = (float*)d_out;
    float* emb_out  = out;
    float* comb_out = out + 3 * (size_t)NR * 64;
    O3 rec_out;
    rec_out.p[0] = out + 4 * (size_t)NR * 64;
    rec_out.p[1] = rec_out.p[0] + (size_t)NR * Din[0];
    rec_out.p[2] = rec_out.p[1] + (size_t)NR * Din[1];

    auto plan = [&](const int* kts, int cnt, int cap, I6& kt, I6& tps, I6& nsp,
                    int& maxnsp) {
        maxnsp = 1;
        for (int i = 0; i < 6; ++i) {
            const int k = kts[(i < cnt) ? i : (cnt - 1)];
            const int tp = (k + cap - 1) / cap;
            kt.v[i] = k; tps.v[i] = tp;
            nsp.v[i] = (k + tp - 1) / tp;
            if (i < cnt && nsp.v[i] > maxnsp) maxnsp = nsp.v[i];
        }
    };

    P3 wcA, bcA, gA, beA, W1A, b1A, W2A, b2A, alA;
    for (int i = 0; i < 3; ++i) {
        wcA.p[i] = wconv[i]; bcA.p[i] = bconv[i];
        gA.p[i] = g[i]; beA.p[i] = be[i]; W1A.p[i] = W1[i]; b1A.p[i] = b1[i];
        W2A.p[i] = W2[i]; b2A.p[i] = b2[i]; alA.p[i] = alpha[i];
    }

    // step-1 (3 slices): feat @ WencT
    P6 A1; V6 B1;
    for (int i = 0; i < 3; ++i) { A1.p[i] = feat[i]; A1.p[3 + i] = feat[i];
                                  B1.p[i] = WencT[i]; B1.p[3 + i] = WencT[i]; }
    // step-2 (6 slices): adj_sp x3 then adj_ft x3; B = febT[z%3]
    P6 A2; V6 B2;
    for (int i = 0; i < 3; ++i) {
        A2.p[i]     = adj_sp[i];
        A2.p[3 + i] = adj_ft[i];
        B2.p[i]     = febT + (size_t)i * NR * 64;
        B2.p[3 + i] = febT + (size_t)i * NR * 64;
    }
    // step-4 (3 slices): adj_sp; B = combT
    P6 A4; V6 B4;
    for (int i = 0; i < 3; ++i) { A4.p[i] = adj_sp[i]; A4.p[3 + i] = adj_sp[i];
                                  B4.p[i] = combT;     B4.p[3 + i] = combT; }

    I6 K1 = {Din[0], Din[1], Din[2], Din[0], Din[1], Din[2]};
    I6 Kp1 = {DinP[0], DinP[1], DinP[2], DinP[0], DinP[1], DinP[2]};
    I6 Kadj; for (int i = 0; i < 6; ++i) Kadj.v[i] = NR;

    // BK=128 tiles
    const int kt1_[3] = {DinP[0] / 128, DinP[1] / 128, DinP[2] / 128};  // 24,8,4
    const int ktA_[1] = {NR / 128};                                      // 32
    I6 ktF, tpsF, nspF; int mF; plan(kt1_, 3, KScapD, ktF, tpsF, nspF, mF);
    I6 ktA2, tpsA2, nspA2; int mA2; plan(ktA_, 1, KScapA, ktA2, tpsA2, nspA2, mA2);
    I6 ktA4, tpsA4, nspA4; int mA4; plan(ktA_, 1, KScapD, ktA4, tpsA4, nspA4, mA4);

    I3 nspF3  = {nspF.v[0],  nspF.v[1],  nspF.v[2]};
    I3 nspA43 = {nspA4.v[0], nspA4.v[1], nspA4.v[2]};

    // 0) weight prep: WencT [64][DinP], WdecT [DinP][64] (bf16, zero-padded)
    {
        P6 s6; U6 d6; I6 R6, C6, Rp6, Cp6;
        int maxtiles = 1;
        for (int i = 0; i < 3; ++i) {
            s6.p[i] = Wenc[i]; d6.p[i] = WencT[i];
            R6.v[i] = Din[i]; C6.v[i] = 64; Rp6.v[i] = DinP[i]; Cp6.v[i] = 64;
            s6.p[3 + i] = Wdec[i]; d6.p[3 + i] = WdecT[i];
            R6.v[3 + i] = 64; C6.v[3 + i] = Din[i]; Rp6.v[3 + i] = 64; Cp6.v[3 + i] = DinP[i];
            const int tls = DinP[i] / 64;
            if (tls > maxtiles) maxtiles = tls;
        }
        prep_t<<<dim3(maxtiles, 6), 256, 0, stream>>>(s6, d6, R6, C6, Rp6, Cp6);
    }

    // 1) fe_i = feat_i @ W_enc_i  -> transposed partials -> febT [64][NR]
    gemm_stream<true><<<dim3(64, mF, 3), 256, 0, stream>>>(
        A1, B1, Cpart, K1, Kp1, ktF, tpsF, KScapD);
    reduce_many<<<dim3(256, 3), 256, 0, stream>>>(Cpart, febT, nspF3, KScapD);

    // 1b) csum_z[c] = sum_r fe_z[r][c]  (conv bias term)
    colsum_kernel<<<3, 256, 0, stream>>>(febT, csum);

    // 2) S1_z = adj_sp_z @ fe_z, S2_z = adj_ft_z @ fe_z  (6 slices);
    //    reduce_ced: gc = w0*S1 + w1*S2 + b*csum, fused CED -> emb
    gemm_stream<false><<<dim3(64, mA2, 6), 256, 0, stream>>>(
        A2, B2, Cpart, Kadj, Kadj, ktA2, tpsA2, KScapA);
    reduce_ced<<<dim3(NR / 4, 3), 256, 0, stream>>>(
        Cpart, wcA, bcA, csum, gA, beA, W1A, b1A, W2A, b2A, alA,
        emb_out, nspA2, KScapA);

    // 3) fusion MLP -> comb (f32 out) + combT (bf16 B^T scratch)
    fusion_kernel<<<NR / 4, 256, 0, stream>>>(emb_out, Wfc1, bfc1, Wfc2, bfc2,
                                              comb_out, combT);

    // 4) T_i = adj_sp_i @ comb -> Tb [NR][64] bf16   (deep split: KScapD)
    gemm_stream<false><<<dim3(64, mA4, 3), 256, 0, stream>>>(
        A4, B4, Cpart, Kadj, Kadj, ktA4, tpsA4, KScapD);
    reduce_many<<<dim3(256, 3), 256, 0, stream>>>(Cpart, Tb, nspA43, KScapD);

    // 5) rec_i = T_i @ W_dec_i
    V3 WdTV; I3 Dz3 = {Din[0], Din[1], Din[2]};
    for (int i = 0; i < 3; ++i) WdTV.p[i] = WdecT[i];
    const int NTmax = DinP[0] / 64;
    gemm_rec<<<dim3(64, NTmax, 3), 256, 0, stream>>>(Tb, WdTV, rec_out, Dz3);
}